// Round 1
// baseline (242.796 us; speedup 1.0000x reference)
//
#include <hip/hip_runtime.h>

#define DIM 1024
#define HEADS 16
#define BB 2
#define NN 2048
#define HD 64
#define M_ROWS (BB*NN)  // 4096

typedef __bf16 bf16x8 __attribute__((ext_vector_type(8)));
typedef float f32x4 __attribute__((ext_vector_type(4)));
typedef short s16x4 __attribute__((ext_vector_type(4)));

__device__ inline unsigned short f2bf(float f) {
    unsigned int u = __builtin_bit_cast(unsigned int, f);
    u += 0x7fffu + ((u >> 16) & 1u);
    return (unsigned short)(u >> 16);
}
__device__ inline float bf2f(unsigned short u) {
    return __builtin_bit_cast(float, (unsigned int)u << 16);
}
__device__ inline bf16x8 as_bf16x8(uint4 v) {
    return __builtin_bit_cast(bf16x8, v);
}
// async global->LDS, 16B per lane: LDS dest = base + lane*16 (wave-uniform
// base); global source address is per-lane (gather allowed).
__device__ __forceinline__ void gl_lds16(const unsigned short* g, unsigned short* l) {
    __builtin_amdgcn_global_load_lds(
        (const __attribute__((address_space(1))) unsigned int*)g,
        (__attribute__((address_space(3))) unsigned int*)l, 16, 0, 0);
}

// 16x16x16 bf16 MFMA (K=16): A/B = 4 bf16 (2 VGPRs), C/D = 4 f32.
__device__ __forceinline__ f32x4 mfma16x16x16bf16(s16x4 a, s16x4 b, f32x4 c) {
#if __has_builtin(__builtin_amdgcn_mfma_f32_16x16x16bf16_1k)
    return __builtin_amdgcn_mfma_f32_16x16x16bf16_1k(a, b, c, 0, 0, 0);
#else
    asm volatile("v_mfma_f32_16x16x16_bf16 %0, %1, %2, %0"
                 : "+v"(c) : "v"(a), "v"(b));
    return c;
#endif
}

// ---------------------------------------------------------------------------
// Weight prep: Wt[m][n][k] = W_m[k][n], f32 -> bf16.  grid (32,32,4), 256 thr.
// ---------------------------------------------------------------------------
__global__ __launch_bounds__(256) void prep_w(
    const float* __restrict__ Wq, const float* __restrict__ Wk,
    const float* __restrict__ Wv, const float* __restrict__ Wo,
    unsigned short* __restrict__ Wt_all)
{
    __shared__ float tile[32][33];
    const int m = blockIdx.z;
    const float* W = (m == 0) ? Wq : (m == 1) ? Wk : (m == 2) ? Wv : Wo;
    const int bk = blockIdx.x, bn = blockIdx.y;
    const int tx = threadIdx.x & 31, ty = threadIdx.x >> 5;  // 32 x 8

    #pragma unroll
    for (int i = 0; i < 32; i += 8)
        tile[ty + i][tx] = W[(size_t)(bk*32 + ty + i)*DIM + bn*32 + tx];
    __syncthreads();
    unsigned short* dst = Wt_all + (size_t)m * DIM * DIM;
    #pragma unroll
    for (int i = 0; i < 32; i += 8)
        dst[(size_t)(bn*32 + ty + i)*DIM + bk*32 + tx] = f2bf(tile[tx][ty + i]);
}

// ---------------------------------------------------------------------------
// Activation prep: Af=bf16(y2f), Ab=bf16(y2b), As=bf16(y2f+y2b). 8 el/thread.
// ---------------------------------------------------------------------------
__global__ __launch_bounds__(256) void prep_act(
    const float* __restrict__ y2f, const float* __restrict__ y2b,
    unsigned short* __restrict__ Af, unsigned short* __restrict__ Ab,
    unsigned short* __restrict__ As)
{
    const size_t idx = ((size_t)blockIdx.x*256 + threadIdx.x) * 8;
    #pragma unroll
    for (int half = 0; half < 2; half++) {
        float4 f = *(const float4*)(y2f + idx + half*4);
        float4 b = *(const float4*)(y2b + idx + half*4);
        ushort4 of, ob, os;
        of.x = f2bf(f.x); of.y = f2bf(f.y); of.z = f2bf(f.z); of.w = f2bf(f.w);
        ob.x = f2bf(b.x); ob.y = f2bf(b.y); ob.z = f2bf(b.z); ob.w = f2bf(b.w);
        os.x = f2bf(f.x + b.x); os.y = f2bf(f.y + b.y);
        os.z = f2bf(f.z + b.z); os.w = f2bf(f.w + b.w);
        *(ushort4*)(Af + idx + half*4) = of;
        *(ushort4*)(Ab + idx + half*4) = ob;
        *(ushort4*)(As + idx + half*4) = os;
    }
}

// ---------------------------------------------------------------------------
// Uniform QKV GEMM: grid (32, 24). bn>>3 selects mode (0=Q,1=K,2=V);
// every block: 128x128 tile, 32 K-iters over DIM=1024. m97 staging.
// Q -> Qh (head layout, pre-scaled 0.125*log2e); K -> Kh; V -> Vt [b,h,d,n].
// V epilogue: coalesced transposed store via LDS (was: 2B scatter @ 4KB
// lane stride = 64 transactions/wave-store; now 16B coalesced rows).
// ---------------------------------------------------------------------------
__global__ __launch_bounds__(256) void gemm_qkv(
    const unsigned short* __restrict__ Af, const unsigned short* __restrict__ Ab,
    const unsigned short* __restrict__ As,
    const unsigned short* __restrict__ Wt_all,
    const float* __restrict__ bq, const float* __restrict__ bk,
    const float* __restrict__ bv,
    unsigned short* __restrict__ Qh, unsigned short* __restrict__ Kh,
    unsigned short* __restrict__ Vt)
{
    const int bm = blockIdx.x;
    const int mode = blockIdx.y >> 3;       // 0=Q, 1=K, 2=V
    const int bn = blockIdx.y & 7;
    __shared__ __align__(16) unsigned short smem[8192];   // 16 KB
    unsigned short* sA = smem;              // [128][32]
    unsigned short* sB = smem + 4096;       // [128][32]
    const int t = threadIdx.x;
    const int w = t >> 6, lane = t & 63, ln = lane & 15, quad = lane >> 4;
    const int wm = w >> 1, wn = w & 1;
    const unsigned short* Wt = Wt_all + (size_t)mode * (DIM*DIM);
    const unsigned short* A0 = (mode == 0) ? Af : (mode == 1) ? Ab : As;

    const int srow = lane >> 2;
    const int scol = (lane & 3) * 8;

    f32x4 acc[4][4];
    #pragma unroll
    for (int mi = 0; mi < 4; mi++)
        #pragma unroll
        for (int ni = 0; ni < 4; ni++)
            acc[mi][ni] = (f32x4){0.f, 0.f, 0.f, 0.f};

    for (int kt = 0; kt < 32; kt++) {
        __syncthreads();
        #pragma unroll
        for (int j = 0; j < 2; j++) {
            int row = w*32 + j*16;
            gl_lds16(A0 + (size_t)(bm*128 + row + srow)*DIM + kt*32 + scol,
                     &sA[row*32]);
            gl_lds16(Wt + (size_t)(bn*128 + row + srow)*DIM + kt*32 + scol,
                     &sB[row*32]);
        }
        __syncthreads();

        bf16x8 af[4], bfr[4];
        #pragma unroll
        for (int mi = 0; mi < 4; mi++)
            af[mi] = as_bf16x8(*(const uint4*)(&sA[(wm*64 + mi*16 + ln)*32 + quad*8]));
        #pragma unroll
        for (int ni = 0; ni < 4; ni++)
            bfr[ni] = as_bf16x8(*(const uint4*)(&sB[(wn*64 + ni*16 + ln)*32 + quad*8]));
        #pragma unroll
        for (int mi = 0; mi < 4; mi++)
            #pragma unroll
            for (int ni = 0; ni < 4; ni++)
                acc[mi][ni] = __builtin_amdgcn_mfma_f32_16x16x32_bf16(af[mi], bfr[ni], acc[mi][ni], 0, 0, 0);
    }

    const float* bias = (mode == 0) ? bq : (mode == 1) ? bk : bv;
    unsigned short* dst = (mode == 0) ? Qh : (mode == 1) ? Kh : Vt;
    if (mode < 2) {
        const float sc = (mode == 0) ? 0.125f * 1.4426950408889634f : 1.0f;
        #pragma unroll
        for (int mi = 0; mi < 4; mi++) {
            #pragma unroll
            for (int r = 0; r < 4; r++) {
                int grow = bm*128 + wm*64 + mi*16 + quad*4 + r;
                int b_ = grow >> 11, n = grow & (NN - 1);
                #pragma unroll
                for (int ni = 0; ni < 4; ni++) {
                    int gcol = bn*128 + wn*64 + ni*16 + ln;
                    int hh = gcol >> 6, dd = gcol & 63;
                    float val = (acc[mi][ni][r] + bias[gcol]) * sc;
                    dst[(((size_t)(b_*HEADS + hh))*NN + n)*HD + dd] = f2bf(val);
                }
            }
        }
    } else {
        // V: transpose through LDS. Two passes of 64 d-cols (one head each);
        // smem reused as sT[64 dd][128 n] bf16 = 16 KB (exact fit).
        #pragma unroll
        for (int p = 0; p < 2; p++) {
            __syncthreads();
            if (wn == p) {
                #pragma unroll
                for (int mi = 0; mi < 4; mi++)
                    #pragma unroll
                    for (int ni = 0; ni < 4; ni++) {
                        float bsv = bias[bn*128 + wn*64 + ni*16 + ln];
                        ushort4 pk;
                        pk.x = f2bf(acc[mi][ni][0] + bsv);
                        pk.y = f2bf(acc[mi][ni][1] + bsv);
                        pk.z = f2bf(acc[mi][ni][2] + bsv);
                        pk.w = f2bf(acc[mi][ni][3] + bsv);
                        *(ushort4*)(&smem[(ni*16 + ln)*128 + wm*64 + mi*16 + quad*4]) = pk;
                    }
            }
            __syncthreads();
            const int hh = bn*2 + p, b_ = bm >> 4;
            unsigned short* vrow = dst + (((size_t)(b_*HEADS + hh))*HD)*NN
                                       + (size_t)(bm & 15)*128;
            #pragma unroll
            for (int i = 0; i < 4; i++) {
                int idx = i*256 + t;              // 0..1023 chunk ids
                int dd = idx >> 4, ch = (idx & 15)*8;
                *(uint4*)(vrow + (size_t)dd*NN + ch) = *(const uint4*)(&smem[dd*128 + ch]);
            }
        }
    }
}

// ---------------------------------------------------------------------------
// Out projection: out[4096,1024] = attp @ Wo^T + bo (f32).
// 64x128 tile, grid (64, 8) = 512 blocks (2/CU).
// ---------------------------------------------------------------------------
__global__ __launch_bounds__(256) void gemm_out(
    const unsigned short* __restrict__ attp,
    const unsigned short* __restrict__ Wt_all,
    const float* __restrict__ bo, float* __restrict__ out)
{
    const int bm = blockIdx.x, bn = blockIdx.y;
    __shared__ __align__(16) unsigned short sA[64*32];
    __shared__ __align__(16) unsigned short sB[128*32];
    const int t = threadIdx.x;
    const int w = t >> 6, lane = t & 63, ln = lane & 15, quad = lane >> 4;
    const int wm = w >> 1, wn = w & 1;
    const unsigned short* Wt = Wt_all + (size_t)3 * (DIM*DIM);

    const int srow = lane >> 2;
    const int scol = (lane & 3) * 8;

    f32x4 acc[2][4];
    #pragma unroll
    for (int mi = 0; mi < 2; mi++)
        #pragma unroll
        for (int ni = 0; ni < 4; ni++)
            acc[mi][ni] = (f32x4){0.f, 0.f, 0.f, 0.f};

    for (int kt = 0; kt < 32; kt++) {
        __syncthreads();
        gl_lds16(attp + (size_t)(bm*64 + w*16 + srow)*DIM + kt*32 + scol,
                 &sA[(w*16)*32]);
        #pragma unroll
        for (int j = 0; j < 2; j++) {
            int row = w*32 + j*16;
            gl_lds16(Wt + (size_t)(bn*128 + row + srow)*DIM + kt*32 + scol,
                     &sB[row*32]);
        }
        __syncthreads();

        bf16x8 af[2], bfr[4];
        #pragma unroll
        for (int mi = 0; mi < 2; mi++)
            af[mi] = as_bf16x8(*(const uint4*)(&sA[(wm*32 + mi*16 + ln)*32 + quad*8]));
        #pragma unroll
        for (int ni = 0; ni < 4; ni++)
            bfr[ni] = as_bf16x8(*(const uint4*)(&sB[(wn*64 + ni*16 + ln)*32 + quad*8]));
        #pragma unroll
        for (int mi = 0; mi < 2; mi++)
            #pragma unroll
            for (int ni = 0; ni < 4; ni++)
                acc[mi][ni] = __builtin_amdgcn_mfma_f32_16x16x32_bf16(af[mi], bfr[ni], acc[mi][ni], 0, 0, 0);
    }

    #pragma unroll
    for (int mi = 0; mi < 2; mi++) {
        #pragma unroll
        for (int r = 0; r < 4; r++) {
            int grow = bm*64 + wm*32 + mi*16 + quad*4 + r;
            #pragma unroll
            for (int ni = 0; ni < 4; ni++) {
                int gcol = bn*128 + wn*64 + ni*16 + ln;
                out[(size_t)grow*DIM + gcol] = acc[mi][ni][r] + bo[gcol];
            }
        }
    }
}

// ---------------------------------------------------------------------------
// Flash attention v5 = v4 + double-buffered K/V staging (T3-lite 2-phase):
//   - raw s_barrier + counted s_waitcnt vmcnt(4) (never 0 in main loop) so
//     next-tile global_load_lds stays in flight across the barrier
//   - Q fragments loaded directly from global (no LDS, no startup barrier)
//   - EBIAS folded into the MFMA accumulator init (kills 16 v_sub/jt)
//   - s_setprio(1) around MFMA clusters (T5; phase diversity from dbuf)
//   - #pragma unroll 2 makes buffer index compile-time (LDS addrs fold)
// LDS 32 KB -> 5 blocks/CU (grid gives 4/CU, all resident).
// 64 q-rows/block, grid (32 bh, 32 qt) = 1024 blocks.
// ---------------------------------------------------------------------------
__global__ __launch_bounds__(256) void attn_kernel(
    const unsigned short* __restrict__ Qh, const unsigned short* __restrict__ Kh,
    const unsigned short* __restrict__ Vt, const unsigned short* __restrict__ As,
    unsigned short* __restrict__ attp)
{
    const int bh = blockIdx.x;      // b*16 + h
    const int qt = blockIdx.y;      // 0..31 (64-row q tiles)
    const int b = bh >> 4, h = bh & 15;
    const int t = threadIdx.x;
    const int w = t >> 6, lane = t & 63, ln = lane & 15, quad = lane >> 4;
    const int sw = ln & 7;          // fragment rows are == ln (mod 8)
    const float EBIAS = 17.312340490667562f;   // 12 * log2(e)

    __shared__ __align__(16) unsigned short sK[2][64*64];    // 16 KB [n][k]
    __shared__ __align__(16) unsigned short sVt[2][64*64];   // 16 KB [d][n]

    const unsigned short* Qb  = Qh + (size_t)bh * NN * HD + (size_t)qt * 64 * HD;
    const unsigned short* Kb  = Kh + (size_t)bh * NN * HD;
    const unsigned short* Vtb = Vt + (size_t)bh * HD * NN;   // [d][n]

    const int rl = lane >> 3, cb = lane & 7;

    // ---- Q fragments straight from global (per-lane 16B, L2-resident) ----
    bf16x8 aq[2];
    #pragma unroll
    for (int k = 0; k < 2; k++)
        aq[k] = as_bf16x8(*(const uint4*)(Qb + (size_t)(w*16 + ln)*HD + (k*4 + quad)*8));

    // stage tile jt into buffer bb (4 gl_lds16 per wave; XOR-swizzled cols)
#define STAGE_KV(JT, BBUF) do { \
        _Pragma("unroll") \
        for (int j = 0; j < 2; j++) { \
            int row = w*16 + j*8 + rl; \
            gl_lds16(Kb + (size_t)((JT)*64 + row)*HD + ((cb ^ (row & 7))*8), \
                     &sK[BBUF][(w*16 + j*8)*64]); \
            gl_lds16(Vtb + (size_t)row*NN + (JT)*64 + ((cb ^ (row & 7))*8), \
                     &sVt[BBUF][(w*16 + j*8)*64]); \
        } } while (0)

    const s16x4 ones = { (short)0x3F80, (short)0x3F80, (short)0x3F80, (short)0x3F80 };
    f32x4 accO[4], accL;
    accL = (f32x4){0.f, 0.f, 0.f, 0.f};
    #pragma unroll
    for (int di = 0; di < 4; di++) accO[di] = (f32x4){0.f, 0.f, 0.f, 0.f};

    STAGE_KV(0, 0);                       // prologue: tile 0 -> buf 0

    #pragma unroll 2
    for (int jt = 0; jt < 32; jt++) {
        const int cur = jt & 1;
        if (jt < 31) {
            STAGE_KV(jt + 1, cur ^ 1);    // issue next tile, then counted wait:
            asm volatile("s_waitcnt vmcnt(4)" ::: "memory");   // buf[cur] done
        } else {
            asm volatile("s_waitcnt vmcnt(0)" ::: "memory");   // drain last
        }
        __builtin_amdgcn_s_barrier();     // raw: no compiler vmcnt(0) drain
        __builtin_amdgcn_sched_barrier(0);

        const unsigned short* sKc = sK[cur];
        const unsigned short* sVc = sVt[cur];

        // S^T: accS[ni] — lane: q-col = w*16+ln, kv = ni*16+quad*4+r.
        // Accumulator pre-loaded with -EBIAS: exp2 input needs no subtract.
        f32x4 accS[4];
        #pragma unroll
        for (int ni = 0; ni < 4; ni++)
            accS[ni] = (f32x4){-EBIAS, -EBIAS, -EBIAS, -EBIAS};
        __builtin_amdgcn_s_setprio(1);
        #pragma unroll
        for (int ni = 0; ni < 4; ni++)
            #pragma unroll
            for (int k = 0; k < 2; k++) {
                bf16x8 bkf = as_bf16x8(*(const uint4*)(
                    &sKc[(ni*16 + ln)*64 + (((k*4 + quad) ^ sw)*8)]));
                accS[ni] = __builtin_amdgcn_mfma_f32_16x16x32_bf16(bkf, aq[k], accS[ni], 0, 0, 0);
            }
        __builtin_amdgcn_s_setprio(0);

        // p = exp2(s-EBIAS); pack via v_perm (trunc); L via ones-MFMA
        s16x4 pf[4];
        #pragma unroll
        for (int ni = 0; ni < 4; ni++) {
            unsigned int e0 = __builtin_bit_cast(unsigned int, __builtin_amdgcn_exp2f(accS[ni][0]));
            unsigned int e1 = __builtin_bit_cast(unsigned int, __builtin_amdgcn_exp2f(accS[ni][1]));
            unsigned int e2 = __builtin_bit_cast(unsigned int, __builtin_amdgcn_exp2f(accS[ni][2]));
            unsigned int e3 = __builtin_bit_cast(unsigned int, __builtin_amdgcn_exp2f(accS[ni][3]));
            unsigned int lo = __builtin_amdgcn_perm(e1, e0, 0x07060302u);
            unsigned int hi = __builtin_amdgcn_perm(e3, e2, 0x07060302u);
            pf[ni] = __builtin_bit_cast(s16x4, uint2{lo, hi});
            accL = mfma16x16x16bf16(pf[ni], ones, accL);
        }

        // O += P V: B-frag = V^T[d=di*16+ln][kv=ni*16+quad*4+j], 8-B read
        __builtin_amdgcn_s_setprio(1);
        #pragma unroll
        for (int ni = 0; ni < 4; ni++) {
            int blkv = 2*ni + (quad >> 1);
            int off = (quad & 1) * 4;
            #pragma unroll
            for (int di = 0; di < 4; di++) {
                s16x4 bv = __builtin_bit_cast(s16x4,
                    *(const uint2*)(&sVc[(di*16 + ln)*64 + ((blkv ^ sw)*8) + off]));
                accO[di] = mfma16x16x16bf16(pf[ni], bv, accO[di]);
            }
        }
        __builtin_amdgcn_s_setprio(0);

        __builtin_amdgcn_sched_barrier(0);
        __builtin_amdgcn_s_barrier();     // all waves done reading buf[cur]
    }
#undef STAGE_KV

    // accL[r] = row-sum L for q-row w*16+quad*4+r (uniform over ln)
    #pragma unroll
    for (int r = 0; r < 4; r++) {
        float inv = 1.f / accL[r];
        int n = qt*64 + w*16 + quad*4 + r;
        #pragma unroll
        for (int di = 0; di < 4; di++) {
            int c = h*64 + di*16 + ln;
            size_t gi = ((size_t)b*NN + n)*DIM + c;
            float o = accO[di][r]*inv + bf2f(As[gi]);
            attp[gi] = f2bf(o);
        }
    }
}

// ---------------------------------------------------------------------------
extern "C" void kernel_launch(void* const* d_in, const int* in_sizes, int n_in,
                              void* d_out, int out_size, void* d_ws, size_t ws_size,
                              hipStream_t stream) {
    const float* y2f = (const float*)d_in[0];
    const float* y2b = (const float*)d_in[1];
    const float* Wq  = (const float*)d_in[2];
    const float* bq  = (const float*)d_in[3];
    const float* Wk  = (const float*)d_in[4];
    const float* bk  = (const float*)d_in[5];
    const float* Wv  = (const float*)d_in[6];
    const float* bv  = (const float*)d_in[7];
    const float* Wo  = (const float*)d_in[8];
    const float* bo  = (const float*)d_in[9];
    float* out = (float*)d_out;

    const size_t NACT = (size_t)M_ROWS * DIM;  // 4,194,304 (8 MB as ushort)
    unsigned short* ws   = (unsigned short*)d_ws;
    unsigned short* Af   = ws;
    unsigned short* Ab   = ws + NACT;
    unsigned short* As   = ws + 2*NACT;
    unsigned short* Qh   = ws + 3*NACT;
    unsigned short* Kh   = ws + 4*NACT;
    unsigned short* Vt   = ws + 5*NACT;   // V written pre-transposed [b,h,d,n]
    unsigned short* Wt   = ws + 6*NACT;   // 4 x 1024 x 1024 bf16
    unsigned short* attp = Ab;            // overlay (Ab dead after QKV gemm)

    prep_w<<<dim3(32, 32, 4), 256, 0, stream>>>(Wq, Wk, Wv, Wo, Wt);
    prep_act<<<dim3(2048), 256, 0, stream>>>(y2f, y2b, Af, Ab, As);
    gemm_qkv<<<dim3(32, 24), 256, 0, stream>>>(
        Af, Ab, As, Wt, bq, bk, bv, Qh, Kh, Vt);
    attn_kernel<<<dim3(32, 32), 256, 0, stream>>>(Qh, Kh, Vt, As, attp);
    gemm_out<<<dim3(64, 8), 256, 0, stream>>>(attp, Wt, bo, out);
}

// Round 2
// 227.445 us; speedup vs baseline: 1.0675x; 1.0675x over previous
//
#include <hip/hip_runtime.h>

#define DIM 1024
#define HEADS 16
#define BB 2
#define NN 2048
#define HD 64
#define M_ROWS (BB*NN)  // 4096

typedef __bf16 bf16x8 __attribute__((ext_vector_type(8)));
typedef float f32x4 __attribute__((ext_vector_type(4)));
typedef short s16x4 __attribute__((ext_vector_type(4)));

__device__ inline unsigned short f2bf(float f) {
    unsigned int u = __builtin_bit_cast(unsigned int, f);
    u += 0x7fffu + ((u >> 16) & 1u);
    return (unsigned short)(u >> 16);
}
__device__ inline float bf2f(unsigned short u) {
    return __builtin_bit_cast(float, (unsigned int)u << 16);
}
__device__ inline bf16x8 as_bf16x8(uint4 v) {
    return __builtin_bit_cast(bf16x8, v);
}
// async global->LDS, 16B per lane: LDS dest = base + lane*16 (wave-uniform
// base); global source address is per-lane (gather allowed).
__device__ __forceinline__ void gl_lds16(const unsigned short* g, unsigned short* l) {
    __builtin_amdgcn_global_load_lds(
        (const __attribute__((address_space(1))) unsigned int*)g,
        (__attribute__((address_space(3))) unsigned int*)l, 16, 0, 0);
}

// 16x16x16 bf16 MFMA (K=16): A/B = 4 bf16 (2 VGPRs), C/D = 4 f32.
__device__ __forceinline__ f32x4 mfma16x16x16bf16(s16x4 a, s16x4 b, f32x4 c) {
#if __has_builtin(__builtin_amdgcn_mfma_f32_16x16x16bf16_1k)
    return __builtin_amdgcn_mfma_f32_16x16x16bf16_1k(a, b, c, 0, 0, 0);
#else
    asm volatile("v_mfma_f32_16x16x16_bf16 %0, %1, %2, %0"
                 : "+v"(c) : "v"(a), "v"(b));
    return c;
#endif
}

// ---------------------------------------------------------------------------
// Weight prep: Wt[m][n][k] = W_m[k][n], f32 -> bf16.  grid (32,32,4), 256 thr.
// ---------------------------------------------------------------------------
__global__ __launch_bounds__(256) void prep_w(
    const float* __restrict__ Wq, const float* __restrict__ Wk,
    const float* __restrict__ Wv, const float* __restrict__ Wo,
    unsigned short* __restrict__ Wt_all)
{
    __shared__ float tile[32][33];
    const int m = blockIdx.z;
    const float* W = (m == 0) ? Wq : (m == 1) ? Wk : (m == 2) ? Wv : Wo;
    const int bk = blockIdx.x, bn = blockIdx.y;
    const int tx = threadIdx.x & 31, ty = threadIdx.x >> 5;  // 32 x 8

    #pragma unroll
    for (int i = 0; i < 32; i += 8)
        tile[ty + i][tx] = W[(size_t)(bk*32 + ty + i)*DIM + bn*32 + tx];
    __syncthreads();
    unsigned short* dst = Wt_all + (size_t)m * DIM * DIM;
    #pragma unroll
    for (int i = 0; i < 32; i += 8)
        dst[(size_t)(bn*32 + ty + i)*DIM + bk*32 + tx] = f2bf(tile[tx][ty + i]);
}

// ---------------------------------------------------------------------------
// Activation prep: Af=bf16(y2f), Ab=bf16(y2b), As=bf16(y2f+y2b). 8 el/thread.
// ---------------------------------------------------------------------------
__global__ __launch_bounds__(256) void prep_act(
    const float* __restrict__ y2f, const float* __restrict__ y2b,
    unsigned short* __restrict__ Af, unsigned short* __restrict__ Ab,
    unsigned short* __restrict__ As)
{
    const size_t idx = ((size_t)blockIdx.x*256 + threadIdx.x) * 8;
    #pragma unroll
    for (int half = 0; half < 2; half++) {
        float4 f = *(const float4*)(y2f + idx + half*4);
        float4 b = *(const float4*)(y2b + idx + half*4);
        ushort4 of, ob, os;
        of.x = f2bf(f.x); of.y = f2bf(f.y); of.z = f2bf(f.z); of.w = f2bf(f.w);
        ob.x = f2bf(b.x); ob.y = f2bf(b.y); ob.z = f2bf(b.z); ob.w = f2bf(b.w);
        os.x = f2bf(f.x + b.x); os.y = f2bf(f.y + b.y);
        os.z = f2bf(f.z + b.z); os.w = f2bf(f.w + b.w);
        *(ushort4*)(Af + idx + half*4) = of;
        *(ushort4*)(Ab + idx + half*4) = ob;
        *(ushort4*)(As + idx + half*4) = os;
    }
}

// ---------------------------------------------------------------------------
// Uniform QKV GEMM: grid (32, 24). bn>>3 selects mode (0=Q,1=K,2=V);
// 128x128 tile, 32 K-iters. NOW: 2-phase double-buffered staging (T3-lite)
//   prologue STAGE(0); per iter: STAGE(next) -> ds_read+MFMA cur ->
//   vmcnt(0)+raw barrier. One barrier per K-step, loads overlap MFMA.
// V epilogue: single-pass transpose via swizzled sT[128][128] overlaying the
// (dead) 32KB staging LDS; XOR swizzle (u ^= (row&7)<<1) kills the 16-way
// ds_write conflicts seen in R1 (4.1M SQ_LDS_BANK_CONFLICT).
// ---------------------------------------------------------------------------
__global__ __launch_bounds__(256) void gemm_qkv(
    const unsigned short* __restrict__ Af, const unsigned short* __restrict__ Ab,
    const unsigned short* __restrict__ As,
    const unsigned short* __restrict__ Wt_all,
    const float* __restrict__ bq, const float* __restrict__ bk,
    const float* __restrict__ bv,
    unsigned short* __restrict__ Qh, unsigned short* __restrict__ Kh,
    unsigned short* __restrict__ Vt)
{
    const int bm = blockIdx.x;
    const int mode = blockIdx.y >> 3;       // 0=Q, 1=K, 2=V
    const int bn = blockIdx.y & 7;
    // dbuf: buf b at smem + b*8192 (sA = +0 [128][32], sB = +4096 [128][32])
    __shared__ __align__(16) unsigned short smem[16384];   // 32 KB
    const int t = threadIdx.x;
    const int w = t >> 6, lane = t & 63, ln = lane & 15, quad = lane >> 4;
    const int wm = w >> 1, wn = w & 1;
    const unsigned short* Wt = Wt_all + (size_t)mode * (DIM*DIM);
    const unsigned short* A0 = (mode == 0) ? Af : (mode == 1) ? Ab : As;

    const int srow = lane >> 2;
    const int scol = (lane & 3) * 8;

    f32x4 acc[4][4];
    #pragma unroll
    for (int mi = 0; mi < 4; mi++)
        #pragma unroll
        for (int ni = 0; ni < 4; ni++)
            acc[mi][ni] = (f32x4){0.f, 0.f, 0.f, 0.f};

#define STAGE_G(KT, BUF) do { \
        unsigned short* sa_ = smem + (BUF)*8192; \
        _Pragma("unroll") \
        for (int j = 0; j < 2; j++) { \
            int row = w*32 + j*16; \
            gl_lds16(A0 + (size_t)(bm*128 + row + srow)*DIM + (KT)*32 + scol, \
                     &sa_[row*32]); \
            gl_lds16(Wt + (size_t)(bn*128 + row + srow)*DIM + (KT)*32 + scol, \
                     &sa_[4096 + row*32]); \
        } } while (0)

    STAGE_G(0, 0);
    asm volatile("s_waitcnt vmcnt(0)" ::: "memory");
    __builtin_amdgcn_s_barrier();
    __builtin_amdgcn_sched_barrier(0);

    #pragma unroll 2
    for (int kt = 0; kt < 32; kt++) {
        const int cur = kt & 1;
        if (kt < 31) STAGE_G(kt + 1, cur ^ 1);   // issue next tile first

        const unsigned short* sa = smem + cur*8192;
        const unsigned short* sb = sa + 4096;
        bf16x8 af[4], bfr[4];
        #pragma unroll
        for (int mi = 0; mi < 4; mi++)
            af[mi] = as_bf16x8(*(const uint4*)(&sa[(wm*64 + mi*16 + ln)*32 + quad*8]));
        #pragma unroll
        for (int ni = 0; ni < 4; ni++)
            bfr[ni] = as_bf16x8(*(const uint4*)(&sb[(wn*64 + ni*16 + ln)*32 + quad*8]));
        #pragma unroll
        for (int mi = 0; mi < 4; mi++)
            #pragma unroll
            for (int ni = 0; ni < 4; ni++)
                acc[mi][ni] = __builtin_amdgcn_mfma_f32_16x16x32_bf16(af[mi], bfr[ni], acc[mi][ni], 0, 0, 0);

        __builtin_amdgcn_sched_barrier(0);
        if (kt < 31) {
            asm volatile("s_waitcnt vmcnt(0)" ::: "memory");  // next tile landed
            __builtin_amdgcn_s_barrier();                     // cur fully read
            __builtin_amdgcn_sched_barrier(0);
        }
    }
#undef STAGE_G

    const float* bias = (mode == 0) ? bq : (mode == 1) ? bk : bv;
    unsigned short* dst = (mode == 0) ? Qh : (mode == 1) ? Kh : Vt;
    if (mode < 2) {
        const float sc = (mode == 0) ? 0.125f * 1.4426950408889634f : 1.0f;
        #pragma unroll
        for (int mi = 0; mi < 4; mi++) {
            #pragma unroll
            for (int r = 0; r < 4; r++) {
                int grow = bm*128 + wm*64 + mi*16 + quad*4 + r;
                int b_ = grow >> 11, n = grow & (NN - 1);
                #pragma unroll
                for (int ni = 0; ni < 4; ni++) {
                    int gcol = bn*128 + wn*64 + ni*16 + ln;
                    int hh = gcol >> 6, dd = gcol & 63;
                    float val = (acc[mi][ni][r] + bias[gcol]) * sc;
                    dst[(((size_t)(b_*HEADS + hh))*NN + n)*HD + dd] = f2bf(val);
                }
            }
        }
    } else {
        // V: single-pass transpose through swizzled sT[128 dd][128 nn]
        // overlaying the full 32KB staging LDS (dead after K-loop).
        __syncthreads();
        #pragma unroll
        for (int ni = 0; ni < 4; ni++) {
            int row_s = wn*64 + ni*16 + ln;            // local feature col dd
            float bsv = bias[bn*128 + row_s];
            int sxor = (row_s & 7) << 1;               // 8B-unit XOR swizzle
            #pragma unroll
            for (int mi = 0; mi < 4; mi++) {
                int u = wm*16 + mi*4 + quad;           // 8B unit along nn
                ushort4 pk;
                pk.x = f2bf(acc[mi][ni][0] + bsv);
                pk.y = f2bf(acc[mi][ni][1] + bsv);
                pk.z = f2bf(acc[mi][ni][2] + bsv);
                pk.w = f2bf(acc[mi][ni][3] + bsv);
                *(ushort4*)(&smem[row_s*128 + ((u ^ sxor) << 2)]) = pk;
            }
        }
        __syncthreads();
        const int b_ = bm >> 4;
        #pragma unroll
        for (int i = 0; i < 8; i++) {
            int idx = i*256 + t;                        // 0..2047 16B chunks
            int dd = idx >> 4, jc = idx & 15;
            int u = (jc*2) ^ ((dd & 7) << 1);
            int hh = bn*2 + (dd >> 6), d_ = dd & 63;
            *(uint4*)(dst + (((size_t)(b_*HEADS + hh))*HD + d_)*NN
                          + (size_t)(bm & 15)*128 + jc*8)
                = *(const uint4*)(&smem[dd*128 + (u << 2)]);
        }
    }
}

// ---------------------------------------------------------------------------
// Out projection: out[4096,1024] = attp @ Wo^T + bo (f32).
// 64x128 tile, grid (64, 8). Same 2-phase dbuf staging as gemm_qkv.
// ---------------------------------------------------------------------------
__global__ __launch_bounds__(256) void gemm_out(
    const unsigned short* __restrict__ attp,
    const unsigned short* __restrict__ Wt_all,
    const float* __restrict__ bo, float* __restrict__ out)
{
    const int bm = blockIdx.x, bn = blockIdx.y;
    // buf b at smem + b*6144 (sA = +0 [64][32], sB = +2048 [128][32])
    __shared__ __align__(16) unsigned short smem[12288];   // 24 KB
    const int t = threadIdx.x;
    const int w = t >> 6, lane = t & 63, ln = lane & 15, quad = lane >> 4;
    const int wm = w >> 1, wn = w & 1;
    const unsigned short* Wt = Wt_all + (size_t)3 * (DIM*DIM);

    const int srow = lane >> 2;
    const int scol = (lane & 3) * 8;

    f32x4 acc[2][4];
    #pragma unroll
    for (int mi = 0; mi < 2; mi++)
        #pragma unroll
        for (int ni = 0; ni < 4; ni++)
            acc[mi][ni] = (f32x4){0.f, 0.f, 0.f, 0.f};

#define STAGE_O(KT, BUF) do { \
        unsigned short* sa_ = smem + (BUF)*6144; \
        gl_lds16(attp + (size_t)(bm*64 + w*16 + srow)*DIM + (KT)*32 + scol, \
                 &sa_[(w*16)*32]); \
        _Pragma("unroll") \
        for (int j = 0; j < 2; j++) { \
            int row = w*32 + j*16; \
            gl_lds16(Wt + (size_t)(bn*128 + row + srow)*DIM + (KT)*32 + scol, \
                     &sa_[2048 + row*32]); \
        } } while (0)

    STAGE_O(0, 0);
    asm volatile("s_waitcnt vmcnt(0)" ::: "memory");
    __builtin_amdgcn_s_barrier();
    __builtin_amdgcn_sched_barrier(0);

    #pragma unroll 2
    for (int kt = 0; kt < 32; kt++) {
        const int cur = kt & 1;
        if (kt < 31) STAGE_O(kt + 1, cur ^ 1);

        const unsigned short* sa = smem + cur*6144;
        const unsigned short* sb = sa + 2048;
        bf16x8 af[2], bfr[4];
        #pragma unroll
        for (int mi = 0; mi < 2; mi++)
            af[mi] = as_bf16x8(*(const uint4*)(&sa[(wm*32 + mi*16 + ln)*32 + quad*8]));
        #pragma unroll
        for (int ni = 0; ni < 4; ni++)
            bfr[ni] = as_bf16x8(*(const uint4*)(&sb[(wn*64 + ni*16 + ln)*32 + quad*8]));
        #pragma unroll
        for (int mi = 0; mi < 2; mi++)
            #pragma unroll
            for (int ni = 0; ni < 4; ni++)
                acc[mi][ni] = __builtin_amdgcn_mfma_f32_16x16x32_bf16(af[mi], bfr[ni], acc[mi][ni], 0, 0, 0);

        __builtin_amdgcn_sched_barrier(0);
        if (kt < 31) {
            asm volatile("s_waitcnt vmcnt(0)" ::: "memory");
            __builtin_amdgcn_s_barrier();
            __builtin_amdgcn_sched_barrier(0);
        }
    }
#undef STAGE_O

    #pragma unroll
    for (int mi = 0; mi < 2; mi++) {
        #pragma unroll
        for (int r = 0; r < 4; r++) {
            int grow = bm*64 + wm*32 + mi*16 + quad*4 + r;
            #pragma unroll
            for (int ni = 0; ni < 4; ni++) {
                int gcol = bn*128 + wn*64 + ni*16 + ln;
                out[(size_t)grow*DIM + gcol] = acc[mi][ni][r] + bo[gcol];
            }
        }
    }
}

// ---------------------------------------------------------------------------
// Flash attention v6 = v5 with single-barrier 2-phase loop (recipe form):
//   STAGE(next) -> compute(cur) -> vmcnt(0)+raw barrier. The end-of-iter
//   vmcnt(0) is ~free (compute >> load latency); drops one barrier/jt.
// Q fragments straight from global; EBIAS folded into accS init; setprio
// around MFMA clusters. LDS 32 KB, 64 q-rows/block, grid (32, 32).
// ---------------------------------------------------------------------------
__global__ __launch_bounds__(256) void attn_kernel(
    const unsigned short* __restrict__ Qh, const unsigned short* __restrict__ Kh,
    const unsigned short* __restrict__ Vt, const unsigned short* __restrict__ As,
    unsigned short* __restrict__ attp)
{
    const int bh = blockIdx.x;      // b*16 + h
    const int qt = blockIdx.y;      // 0..31 (64-row q tiles)
    const int b = bh >> 4, h = bh & 15;
    const int t = threadIdx.x;
    const int w = t >> 6, lane = t & 63, ln = lane & 15, quad = lane >> 4;
    const int sw = ln & 7;          // fragment rows are == ln (mod 8)
    const float EBIAS = 17.312340490667562f;   // 12 * log2(e)

    __shared__ __align__(16) unsigned short sK[2][64*64];    // 16 KB [n][k]
    __shared__ __align__(16) unsigned short sVt[2][64*64];   // 16 KB [d][n]

    const unsigned short* Qb  = Qh + (size_t)bh * NN * HD + (size_t)qt * 64 * HD;
    const unsigned short* Kb  = Kh + (size_t)bh * NN * HD;
    const unsigned short* Vtb = Vt + (size_t)bh * HD * NN;   // [d][n]

    const int rl = lane >> 3, cb = lane & 7;

    // ---- Q fragments straight from global (per-lane 16B, L2-resident) ----
    bf16x8 aq[2];
    #pragma unroll
    for (int k = 0; k < 2; k++)
        aq[k] = as_bf16x8(*(const uint4*)(Qb + (size_t)(w*16 + ln)*HD + (k*4 + quad)*8));

    // stage tile jt into buffer bb (4 gl_lds16 per wave; XOR-swizzled cols)
#define STAGE_KV(JT, BBUF) do { \
        _Pragma("unroll") \
        for (int j = 0; j < 2; j++) { \
            int row = w*16 + j*8 + rl; \
            gl_lds16(Kb + (size_t)((JT)*64 + row)*HD + ((cb ^ (row & 7))*8), \
                     &sK[BBUF][(w*16 + j*8)*64]); \
            gl_lds16(Vtb + (size_t)row*NN + (JT)*64 + ((cb ^ (row & 7))*8), \
                     &sVt[BBUF][(w*16 + j*8)*64]); \
        } } while (0)

    const s16x4 ones = { (short)0x3F80, (short)0x3F80, (short)0x3F80, (short)0x3F80 };
    f32x4 accO[4], accL;
    accL = (f32x4){0.f, 0.f, 0.f, 0.f};
    #pragma unroll
    for (int di = 0; di < 4; di++) accO[di] = (f32x4){0.f, 0.f, 0.f, 0.f};

    STAGE_KV(0, 0);                       // prologue: tile 0 -> buf 0
    asm volatile("s_waitcnt vmcnt(0)" ::: "memory");
    __builtin_amdgcn_s_barrier();
    __builtin_amdgcn_sched_barrier(0);

    #pragma unroll 2
    for (int jt = 0; jt < 32; jt++) {
        const int cur = jt & 1;
        if (jt < 31) STAGE_KV(jt + 1, cur ^ 1);   // issue next tile first

        const unsigned short* sKc = sK[cur];
        const unsigned short* sVc = sVt[cur];

        // S^T: accS[ni] — lane: q-col = w*16+ln, kv = ni*16+quad*4+r.
        // Accumulator pre-loaded with -EBIAS: exp2 input needs no subtract.
        f32x4 accS[4];
        #pragma unroll
        for (int ni = 0; ni < 4; ni++)
            accS[ni] = (f32x4){-EBIAS, -EBIAS, -EBIAS, -EBIAS};
        __builtin_amdgcn_s_setprio(1);
        #pragma unroll
        for (int ni = 0; ni < 4; ni++)
            #pragma unroll
            for (int k = 0; k < 2; k++) {
                bf16x8 bkf = as_bf16x8(*(const uint4*)(
                    &sKc[(ni*16 + ln)*64 + (((k*4 + quad) ^ sw)*8)]));
                accS[ni] = __builtin_amdgcn_mfma_f32_16x16x32_bf16(bkf, aq[k], accS[ni], 0, 0, 0);
            }
        __builtin_amdgcn_s_setprio(0);

        // p = exp2(s-EBIAS); pack via v_perm (trunc); L via ones-MFMA
        s16x4 pf[4];
        #pragma unroll
        for (int ni = 0; ni < 4; ni++) {
            unsigned int e0 = __builtin_bit_cast(unsigned int, __builtin_amdgcn_exp2f(accS[ni][0]));
            unsigned int e1 = __builtin_bit_cast(unsigned int, __builtin_amdgcn_exp2f(accS[ni][1]));
            unsigned int e2 = __builtin_bit_cast(unsigned int, __builtin_amdgcn_exp2f(accS[ni][2]));
            unsigned int e3 = __builtin_bit_cast(unsigned int, __builtin_amdgcn_exp2f(accS[ni][3]));
            unsigned int lo = __builtin_amdgcn_perm(e1, e0, 0x07060302u);
            unsigned int hi = __builtin_amdgcn_perm(e3, e2, 0x07060302u);
            pf[ni] = __builtin_bit_cast(s16x4, uint2{lo, hi});
            accL = mfma16x16x16bf16(pf[ni], ones, accL);
        }

        // O += P V: B-frag = V^T[d=di*16+ln][kv=ni*16+quad*4+j], 8-B read
        __builtin_amdgcn_s_setprio(1);
        #pragma unroll
        for (int ni = 0; ni < 4; ni++) {
            int blkv = 2*ni + (quad >> 1);
            int off = (quad & 1) * 4;
            #pragma unroll
            for (int di = 0; di < 4; di++) {
                s16x4 bv = __builtin_bit_cast(s16x4,
                    *(const uint2*)(&sVc[(di*16 + ln)*64 + ((blkv ^ sw)*8) + off]));
                accO[di] = mfma16x16x16bf16(pf[ni], bv, accO[di]);
            }
        }
        __builtin_amdgcn_s_setprio(0);

        __builtin_amdgcn_sched_barrier(0);
        if (jt < 31) {
            asm volatile("s_waitcnt vmcnt(0)" ::: "memory");  // next tile landed
            __builtin_amdgcn_s_barrier();                     // cur fully read
            __builtin_amdgcn_sched_barrier(0);
        }
    }
#undef STAGE_KV

    // accL[r] = row-sum L for q-row w*16+quad*4+r (uniform over ln)
    #pragma unroll
    for (int r = 0; r < 4; r++) {
        float inv = 1.f / accL[r];
        int n = qt*64 + w*16 + quad*4 + r;
        #pragma unroll
        for (int di = 0; di < 4; di++) {
            int c = h*64 + di*16 + ln;
            size_t gi = ((size_t)b*NN + n)*DIM + c;
            float o = accO[di][r]*inv + bf2f(As[gi]);
            attp[gi] = f2bf(o);
        }
    }
}

// ---------------------------------------------------------------------------
extern "C" void kernel_launch(void* const* d_in, const int* in_sizes, int n_in,
                              void* d_out, int out_size, void* d_ws, size_t ws_size,
                              hipStream_t stream) {
    const float* y2f = (const float*)d_in[0];
    const float* y2b = (const float*)d_in[1];
    const float* Wq  = (const float*)d_in[2];
    const float* bq  = (const float*)d_in[3];
    const float* Wk  = (const float*)d_in[4];
    const float* bk  = (const float*)d_in[5];
    const float* Wv  = (const float*)d_in[6];
    const float* bv  = (const float*)d_in[7];
    const float* Wo  = (const float*)d_in[8];
    const float* bo  = (const float*)d_in[9];
    float* out = (float*)d_out;

    const size_t NACT = (size_t)M_ROWS * DIM;  // 4,194,304 (8 MB as ushort)
    unsigned short* ws   = (unsigned short*)d_ws;
    unsigned short* Af   = ws;
    unsigned short* Ab   = ws + NACT;
    unsigned short* As   = ws + 2*NACT;
    unsigned short* Qh   = ws + 3*NACT;
    unsigned short* Kh   = ws + 4*NACT;
    unsigned short* Vt   = ws + 5*NACT;   // V written pre-transposed [b,h,d,n]
    unsigned short* Wt   = ws + 6*NACT;   // 4 x 1024 x 1024 bf16
    unsigned short* attp = Ab;            // overlay (Ab dead after QKV gemm)

    prep_w<<<dim3(32, 32, 4), 256, 0, stream>>>(Wq, Wk, Wv, Wo, Wt);
    prep_act<<<dim3(2048), 256, 0, stream>>>(y2f, y2b, Af, Ab, As);
    gemm_qkv<<<dim3(32, 24), 256, 0, stream>>>(
        Af, Ab, As, Wt, bq, bk, bv, Qh, Kh, Vt);
    attn_kernel<<<dim3(32, 32), 256, 0, stream>>>(Qh, Kh, Vt, As, attp);
    gemm_out<<<dim3(64, 8), 256, 0, stream>>>(attp, Wt, bo, out);
}

// Round 3
// 218.765 us; speedup vs baseline: 1.1098x; 1.0397x over previous
//
#include <hip/hip_runtime.h>

#define DIM 1024
#define HEADS 16
#define BB 2
#define NN 2048
#define HD 64
#define M_ROWS (BB*NN)  // 4096

typedef __bf16 bf16x8 __attribute__((ext_vector_type(8)));
typedef float f32x4 __attribute__((ext_vector_type(4)));
typedef short s16x4 __attribute__((ext_vector_type(4)));

__device__ inline unsigned short f2bf(float f) {
    unsigned int u = __builtin_bit_cast(unsigned int, f);
    u += 0x7fffu + ((u >> 16) & 1u);
    return (unsigned short)(u >> 16);
}
__device__ inline float bf2f(unsigned short u) {
    return __builtin_bit_cast(float, (unsigned int)u << 16);
}
__device__ inline bf16x8 as_bf16x8(uint4 v) {
    return __builtin_bit_cast(bf16x8, v);
}
// async global->LDS, 16B per lane: LDS dest = base + lane*16 (wave-uniform
// base); global source address is per-lane (gather allowed).
__device__ __forceinline__ void gl_lds16(const unsigned short* g, unsigned short* l) {
    __builtin_amdgcn_global_load_lds(
        (const __attribute__((address_space(1))) unsigned int*)g,
        (__attribute__((address_space(3))) unsigned int*)l, 16, 0, 0);
}

// 16x16x16 bf16 MFMA (K=16): A/B = 4 bf16 (2 VGPRs), C/D = 4 f32.
__device__ __forceinline__ f32x4 mfma16x16x16bf16(s16x4 a, s16x4 b, f32x4 c) {
#if __has_builtin(__builtin_amdgcn_mfma_f32_16x16x16bf16_1k)
    return __builtin_amdgcn_mfma_f32_16x16x16bf16_1k(a, b, c, 0, 0, 0);
#else
    asm volatile("v_mfma_f32_16x16x16_bf16 %0, %1, %2, %0"
                 : "+v"(c) : "v"(a), "v"(b));
    return c;
#endif
}

// ---------------------------------------------------------------------------
// Merged prep: blocks 0..4095 = weight transpose (Wt[m][n][k] = W_m[k][n]),
// blocks 4096..6143 = activation bf16 prep. One launch instead of two.
// ---------------------------------------------------------------------------
__global__ __launch_bounds__(256) void prep_all(
    const float* __restrict__ y2f, const float* __restrict__ y2b,
    const float* __restrict__ Wq, const float* __restrict__ Wk,
    const float* __restrict__ Wv, const float* __restrict__ Wo,
    unsigned short* __restrict__ Af, unsigned short* __restrict__ Ab,
    unsigned short* __restrict__ As, unsigned short* __restrict__ Wt_all)
{
    __shared__ float tile[32][33];
    const int blk = blockIdx.x;
    if (blk < 4096) {
        const int m = blk >> 10, r = blk & 1023, bk = r & 31, bn = r >> 5;
        const float* W = (m == 0) ? Wq : (m == 1) ? Wk : (m == 2) ? Wv : Wo;
        const int tx = threadIdx.x & 31, ty = threadIdx.x >> 5;  // 32 x 8
        #pragma unroll
        for (int i = 0; i < 32; i += 8)
            tile[ty + i][tx] = W[(size_t)(bk*32 + ty + i)*DIM + bn*32 + tx];
        __syncthreads();
        unsigned short* dst = Wt_all + (size_t)m * DIM * DIM;
        #pragma unroll
        for (int i = 0; i < 32; i += 8)
            dst[(size_t)(bn*32 + ty + i)*DIM + bk*32 + tx] = f2bf(tile[tx][ty + i]);
    } else {
        const size_t idx = ((size_t)(blk - 4096)*256 + threadIdx.x) * 8;
        #pragma unroll
        for (int half = 0; half < 2; half++) {
            float4 f = *(const float4*)(y2f + idx + half*4);
            float4 b = *(const float4*)(y2b + idx + half*4);
            ushort4 of, ob, os;
            of.x = f2bf(f.x); of.y = f2bf(f.y); of.z = f2bf(f.z); of.w = f2bf(f.w);
            ob.x = f2bf(b.x); ob.y = f2bf(b.y); ob.z = f2bf(b.z); ob.w = f2bf(b.w);
            os.x = f2bf(f.x + b.x); os.y = f2bf(f.y + b.y);
            os.z = f2bf(f.z + b.z); os.w = f2bf(f.w + b.w);
            *(ushort4*)(Af + idx + half*4) = of;
            *(ushort4*)(Ab + idx + half*4) = ob;
            *(ushort4*)(As + idx + half*4) = os;
        }
    }
}

// ---------------------------------------------------------------------------
// Uniform QKV GEMM: grid (32, 24). mode = bn>>3 (0=Q,1=K,2=V); 128x128 tile,
// 32 K-iters. T4 counted-vmcnt pipeline: 3 staging buffers (48 KB = 3
// blocks/CU exactly), per iter: vmcnt(4) -> barrier -> STAGE(kt+2 into the
// buffer the barrier just freed) -> compute(kt). Never drains to 0 in the
// main loop; loads have ~2 iterations to land.
// ---------------------------------------------------------------------------
__global__ __launch_bounds__(256) void gemm_qkv(
    const unsigned short* __restrict__ Af, const unsigned short* __restrict__ Ab,
    const unsigned short* __restrict__ As,
    const unsigned short* __restrict__ Wt_all,
    const float* __restrict__ bq, const float* __restrict__ bk,
    const float* __restrict__ bv,
    unsigned short* __restrict__ Qh, unsigned short* __restrict__ Kh,
    unsigned short* __restrict__ Vt)
{
    const int bm = blockIdx.x;
    const int mode = blockIdx.y >> 3;       // 0=Q, 1=K, 2=V
    const int bn = blockIdx.y & 7;
    // buf b at smem + b*8192 shorts (sA [128][32] + sB [128][32])
    __shared__ __align__(16) unsigned short smem[3*8192];   // 48 KB
    const int t = threadIdx.x;
    const int w = t >> 6, lane = t & 63, ln = lane & 15, quad = lane >> 4;
    const int wm = w >> 1, wn = w & 1;
    const unsigned short* Wt = Wt_all + (size_t)mode * (DIM*DIM);
    const unsigned short* A0 = (mode == 0) ? Af : (mode == 1) ? Ab : As;

    const int srow = lane >> 2;
    const int scol = (lane & 3) * 8;

    // staging source pointers, advance 32 elements per kt
    const unsigned short* gA0 = A0 + (size_t)(bm*128 + w*32 + srow)*DIM + scol;
    const unsigned short* gA1 = gA0 + (size_t)16*DIM;
    const unsigned short* gB0 = Wt + (size_t)(bn*128 + w*32 + srow)*DIM + scol;
    const unsigned short* gB1 = gB0 + (size_t)16*DIM;

    // LDS fragment base offsets (elements), loop-invariant
    const int aoff = (wm*64 + ln)*32 + quad*8;          // + mi*512
    const int boff = 4096 + (wn*64 + ln)*32 + quad*8;   // + ni*512

    f32x4 acc[4][4];
    #pragma unroll
    for (int mi = 0; mi < 4; mi++)
        #pragma unroll
        for (int ni = 0; ni < 4; ni++)
            acc[mi][ni] = (f32x4){0.f, 0.f, 0.f, 0.f};

#define STAGE_Q(BUF) do { \
        unsigned short* s_ = smem + (BUF)*8192; \
        gl_lds16(gA0, &s_[(w*32)*32]); \
        gl_lds16(gA1, &s_[(w*32 + 16)*32]); \
        gl_lds16(gB0, &s_[4096 + (w*32)*32]); \
        gl_lds16(gB1, &s_[4096 + (w*32 + 16)*32]); \
        gA0 += 32; gA1 += 32; gB0 += 32; gB1 += 32; } while (0)

#define COMP_Q(BUF) do { \
        const unsigned short* s_ = smem + (BUF)*8192; \
        bf16x8 af[4], bfr[4]; \
        _Pragma("unroll") \
        for (int mi = 0; mi < 4; mi++) \
            af[mi] = as_bf16x8(*(const uint4*)(s_ + aoff + mi*512)); \
        _Pragma("unroll") \
        for (int ni = 0; ni < 4; ni++) \
            bfr[ni] = as_bf16x8(*(const uint4*)(s_ + boff + ni*512)); \
        _Pragma("unroll") \
        for (int mi = 0; mi < 4; mi++) \
            _Pragma("unroll") \
            for (int ni = 0; ni < 4; ni++) \
                acc[mi][ni] = __builtin_amdgcn_mfma_f32_16x16x32_bf16(af[mi], bfr[ni], acc[mi][ni], 0, 0, 0); \
    } while (0)

#define QITER(B) do { \
        asm volatile("s_waitcnt vmcnt(4)" ::: "memory"); \
        __builtin_amdgcn_s_barrier(); \
        __builtin_amdgcn_sched_barrier(0); \
        STAGE_Q(((B) + 2) % 3); \
        COMP_Q(B); \
        __builtin_amdgcn_sched_barrier(0); \
    } while (0)

    STAGE_Q(0);
    STAGE_Q(1);
    // kt = 0..29 (stage kt+2 each iter); buffer = kt%3
    for (int base = 0; base < 30; base += 3) {
        QITER(0); QITER(1); QITER(2);
    }
    // kt = 30: stage 31 still in flight
    asm volatile("s_waitcnt vmcnt(4)" ::: "memory");
    __builtin_amdgcn_s_barrier();
    __builtin_amdgcn_sched_barrier(0);
    COMP_Q(0);
    __builtin_amdgcn_sched_barrier(0);
    // kt = 31: drain
    asm volatile("s_waitcnt vmcnt(0)" ::: "memory");
    __builtin_amdgcn_s_barrier();
    __builtin_amdgcn_sched_barrier(0);
    COMP_Q(1);
#undef QITER
#undef COMP_Q
#undef STAGE_Q

    const float* bias = (mode == 0) ? bq : (mode == 1) ? bk : bv;
    unsigned short* dst = (mode == 0) ? Qh : (mode == 1) ? Kh : Vt;
    if (mode < 2) {
        const float sc = (mode == 0) ? 0.125f * 1.4426950408889634f : 1.0f;
        #pragma unroll
        for (int mi = 0; mi < 4; mi++) {
            #pragma unroll
            for (int r = 0; r < 4; r++) {
                int grow = bm*128 + wm*64 + mi*16 + quad*4 + r;
                int b_ = grow >> 11, n = grow & (NN - 1);
                #pragma unroll
                for (int ni = 0; ni < 4; ni++) {
                    int gcol = bn*128 + wn*64 + ni*16 + ln;
                    int hh = gcol >> 6, dd = gcol & 63;
                    float val = (acc[mi][ni][r] + bias[gcol]) * sc;
                    dst[(((size_t)(b_*HEADS + hh))*NN + n)*HD + dd] = f2bf(val);
                }
            }
        }
    } else {
        // V: single-pass transpose through swizzled sT[128 dd][128 nn]
        // overlaying the staging LDS (dead after K-loop).
        __syncthreads();
        #pragma unroll
        for (int ni = 0; ni < 4; ni++) {
            int row_s = wn*64 + ni*16 + ln;            // local feature col dd
            float bsv = bias[bn*128 + row_s];
            int sxor = (row_s & 7) << 1;               // 8B-unit XOR swizzle
            #pragma unroll
            for (int mi = 0; mi < 4; mi++) {
                int u = wm*16 + mi*4 + quad;           // 8B unit along nn
                ushort4 pk;
                pk.x = f2bf(acc[mi][ni][0] + bsv);
                pk.y = f2bf(acc[mi][ni][1] + bsv);
                pk.z = f2bf(acc[mi][ni][2] + bsv);
                pk.w = f2bf(acc[mi][ni][3] + bsv);
                *(ushort4*)(&smem[row_s*128 + ((u ^ sxor) << 2)]) = pk;
            }
        }
        __syncthreads();
        const int b_ = bm >> 4;
        #pragma unroll
        for (int i = 0; i < 8; i++) {
            int idx = i*256 + t;                        // 0..2047 16B chunks
            int dd = idx >> 4, jc = idx & 15;
            int u = (jc*2) ^ ((dd & 7) << 1);
            int hh = bn*2 + (dd >> 6), d_ = dd & 63;
            *(uint4*)(dst + (((size_t)(b_*HEADS + hh))*HD + d_)*NN
                          + (size_t)(bm & 15)*128 + jc*8)
                = *(const uint4*)(&smem[dd*128 + (u << 2)]);
        }
    }
}

// ---------------------------------------------------------------------------
// Out projection: out[4096,1024] = attp @ Wo^T + bo (f32). 64x128 tile,
// grid (64, 8). Same T4 counted-vmcnt pipeline (3 loads/stage -> vmcnt(3)).
// LDS 36 KB -> 4 blocks/CU.
// ---------------------------------------------------------------------------
__global__ __launch_bounds__(256) void gemm_out(
    const unsigned short* __restrict__ attp,
    const unsigned short* __restrict__ Wt_all,
    const float* __restrict__ bo, float* __restrict__ out)
{
    const int bm = blockIdx.x, bn = blockIdx.y;
    // buf b at smem + b*6144 shorts (sA [64][32] + sB [128][32])
    __shared__ __align__(16) unsigned short smem[3*6144];   // 36 KB
    const int t = threadIdx.x;
    const int w = t >> 6, lane = t & 63, ln = lane & 15, quad = lane >> 4;
    const int wm = w >> 1, wn = w & 1;
    const unsigned short* Wt = Wt_all + (size_t)3 * (DIM*DIM);

    const int srow = lane >> 2;
    const int scol = (lane & 3) * 8;

    const unsigned short* gA = attp + (size_t)(bm*64 + w*16 + srow)*DIM + scol;
    const unsigned short* gB0 = Wt + (size_t)(bn*128 + w*32 + srow)*DIM + scol;
    const unsigned short* gB1 = gB0 + (size_t)16*DIM;

    const int aoff = (wm*32 + ln)*32 + quad*8;          // + mi*512
    const int boff = 2048 + (wn*64 + ln)*32 + quad*8;   // + ni*512

    f32x4 acc[2][4];
    #pragma unroll
    for (int mi = 0; mi < 2; mi++)
        #pragma unroll
        for (int ni = 0; ni < 4; ni++)
            acc[mi][ni] = (f32x4){0.f, 0.f, 0.f, 0.f};

#define STAGE_T(BUF) do { \
        unsigned short* s_ = smem + (BUF)*6144; \
        gl_lds16(gA, &s_[(w*16)*32]); \
        gl_lds16(gB0, &s_[2048 + (w*32)*32]); \
        gl_lds16(gB1, &s_[2048 + (w*32 + 16)*32]); \
        gA += 32; gB0 += 32; gB1 += 32; } while (0)

#define COMP_T(BUF) do { \
        const unsigned short* s_ = smem + (BUF)*6144; \
        bf16x8 af[2], bfr[4]; \
        _Pragma("unroll") \
        for (int mi = 0; mi < 2; mi++) \
            af[mi] = as_bf16x8(*(const uint4*)(s_ + aoff + mi*512)); \
        _Pragma("unroll") \
        for (int ni = 0; ni < 4; ni++) \
            bfr[ni] = as_bf16x8(*(const uint4*)(s_ + boff + ni*512)); \
        _Pragma("unroll") \
        for (int mi = 0; mi < 2; mi++) \
            _Pragma("unroll") \
            for (int ni = 0; ni < 4; ni++) \
                acc[mi][ni] = __builtin_amdgcn_mfma_f32_16x16x32_bf16(af[mi], bfr[ni], acc[mi][ni], 0, 0, 0); \
    } while (0)

#define TITER(B) do { \
        asm volatile("s_waitcnt vmcnt(3)" ::: "memory"); \
        __builtin_amdgcn_s_barrier(); \
        __builtin_amdgcn_sched_barrier(0); \
        STAGE_T(((B) + 2) % 3); \
        COMP_T(B); \
        __builtin_amdgcn_sched_barrier(0); \
    } while (0)

    STAGE_T(0);
    STAGE_T(1);
    for (int base = 0; base < 30; base += 3) {
        TITER(0); TITER(1); TITER(2);
    }
    asm volatile("s_waitcnt vmcnt(3)" ::: "memory");
    __builtin_amdgcn_s_barrier();
    __builtin_amdgcn_sched_barrier(0);
    COMP_T(0);
    __builtin_amdgcn_sched_barrier(0);
    asm volatile("s_waitcnt vmcnt(0)" ::: "memory");
    __builtin_amdgcn_s_barrier();
    __builtin_amdgcn_sched_barrier(0);
    COMP_T(1);
#undef TITER
#undef COMP_T
#undef STAGE_T

    #pragma unroll
    for (int mi = 0; mi < 2; mi++) {
        #pragma unroll
        for (int r = 0; r < 4; r++) {
            int grow = bm*64 + wm*32 + mi*16 + quad*4 + r;
            #pragma unroll
            for (int ni = 0; ni < 4; ni++) {
                int gcol = bn*128 + wn*64 + ni*16 + ln;
                out[(size_t)grow*DIM + gcol] = acc[mi][ni][r] + bo[gcol];
            }
        }
    }
}

// ---------------------------------------------------------------------------
// Flash attention v7 = v6 + explicit address hoisting (the R2 counters showed
// VALUBusy == MfmaUtil == 43%: compiler recomputed all XOR-swizzled LDS
// fragment addresses and 64-bit staging addresses every jt at VGPR=52).
// Now: 12 precomputed LDS base pointers (ds_read immediates do ni/di/k),
// 4 strength-reduced global staging pointers (+= const per jt).
// Sync structure unchanged from R2 (verified): stage-next -> compute ->
// vmcnt(0) -> barrier, 2 buffers, 32 KB LDS.
// ---------------------------------------------------------------------------
__global__ __launch_bounds__(256) void attn_kernel(
    const unsigned short* __restrict__ Qh, const unsigned short* __restrict__ Kh,
    const unsigned short* __restrict__ Vt, const unsigned short* __restrict__ As,
    unsigned short* __restrict__ attp)
{
    const int bh = blockIdx.x;      // b*16 + h
    const int qt = blockIdx.y;      // 0..31 (64-row q tiles)
    const int b = bh >> 4, h = bh & 15;
    const int t = threadIdx.x;
    const int w = t >> 6, lane = t & 63, ln = lane & 15, quad = lane >> 4;
    const int sw = ln & 7;          // fragment rows are == ln (mod 8)
    const float EBIAS = 17.312340490667562f;   // 12 * log2(e)

    __shared__ __align__(16) unsigned short sK[2][64*64];    // 16 KB [n][k]
    __shared__ __align__(16) unsigned short sVt[2][64*64];   // 16 KB [d][n]

    const unsigned short* Qb  = Qh + (size_t)bh * NN * HD + (size_t)qt * 64 * HD;
    const unsigned short* Kb  = Kh + (size_t)bh * NN * HD;
    const unsigned short* Vtb = Vt + (size_t)bh * HD * NN;   // [d][n]

    const int rl = lane >> 3, cb = lane & 7;

    // ---- Q fragments straight from global (per-lane 16B, L2-resident) ----
    bf16x8 aq[2];
    #pragma unroll
    for (int k = 0; k < 2; k++)
        aq[k] = as_bf16x8(*(const uint4*)(Qb + (size_t)(w*16 + ln)*HD + (k*4 + quad)*8));

    // ---- hoisted staging pointers (advance by constants per jt) ----
    const int r0 = w*16 + rl, r1 = w*16 + 8 + rl;
    const unsigned short* gK0 = Kb + (size_t)r0*HD + (cb ^ (r0 & 7))*8;
    const unsigned short* gK1 = Kb + (size_t)r1*HD + (cb ^ (r1 & 7))*8;
    const unsigned short* gV0 = Vtb + (size_t)r0*NN + (cb ^ (r0 & 7))*8;
    const unsigned short* gV1 = Vtb + (size_t)r1*NN + (cb ^ (r1 & 7))*8;

#define STAGE_KV(BUF) do { \
        gl_lds16(gK0, &sK[BUF][(w*16)*64]); \
        gl_lds16(gK1, &sK[BUF][(w*16 + 8)*64]); \
        gl_lds16(gV0, &sVt[BUF][(w*16)*64]); \
        gl_lds16(gV1, &sVt[BUF][(w*16 + 8)*64]); \
        gK0 += 64*HD; gK1 += 64*HD; gV0 += 64; gV1 += 64; } while (0)

    // ---- hoisted LDS fragment base pointers ----
    // K frag: elem = ni*1024 + ln*64 + col8*8, col8 = (quad^(sw&3)) + 4*(k^(sw>>2))
    const int kc0 = ((quad ^ (sw & 3)) + 4*((sw >> 2) & 1)) * 8;     // k=0
    const unsigned short* bK0a = &sK[0][ln*64 + kc0];
    const unsigned short* bK0b = &sK[0][ln*64 + (kc0 ^ 32)];         // k=1
    const unsigned short* bK1a = &sK[1][ln*64 + kc0];
    const unsigned short* bK1b = &sK[1][ln*64 + (kc0 ^ 32)];
    // V frag: elem = di*1024 + ln*64 + ((quad>>1)^(sw&1))*8 + (quad&1)*4
    //              + (ni^((sw>>1)&3))*16
    const int vb = ln*64 + ((quad >> 1) ^ (sw & 1))*8 + (quad & 1)*4;
    const int sv = (sw >> 1) & 3;
    const unsigned short* bV0_0 = &sVt[0][vb + (0 ^ sv)*16];
    const unsigned short* bV0_1 = &sVt[0][vb + (1 ^ sv)*16];
    const unsigned short* bV0_2 = &sVt[0][vb + (2 ^ sv)*16];
    const unsigned short* bV0_3 = &sVt[0][vb + (3 ^ sv)*16];
    const unsigned short* bV1_0 = &sVt[1][vb + (0 ^ sv)*16];
    const unsigned short* bV1_1 = &sVt[1][vb + (1 ^ sv)*16];
    const unsigned short* bV1_2 = &sVt[1][vb + (2 ^ sv)*16];
    const unsigned short* bV1_3 = &sVt[1][vb + (3 ^ sv)*16];

    const s16x4 ones = { (short)0x3F80, (short)0x3F80, (short)0x3F80, (short)0x3F80 };
    f32x4 accO[4], accL;
    accL = (f32x4){0.f, 0.f, 0.f, 0.f};
    #pragma unroll
    for (int di = 0; di < 4; di++) accO[di] = (f32x4){0.f, 0.f, 0.f, 0.f};

#define ATT_JT(PK0_, PK1_, PV0_, PV1_, PV2_, PV3_) do { \
        f32x4 accS[4]; \
        _Pragma("unroll") \
        for (int ni = 0; ni < 4; ni++) \
            accS[ni] = (f32x4){-EBIAS, -EBIAS, -EBIAS, -EBIAS}; \
        __builtin_amdgcn_s_setprio(1); \
        _Pragma("unroll") \
        for (int ni = 0; ni < 4; ni++) { \
            bf16x8 b0_ = as_bf16x8(*(const uint4*)(PK0_ + ni*1024)); \
            accS[ni] = __builtin_amdgcn_mfma_f32_16x16x32_bf16(b0_, aq[0], accS[ni], 0, 0, 0); \
            bf16x8 b1_ = as_bf16x8(*(const uint4*)(PK1_ + ni*1024)); \
            accS[ni] = __builtin_amdgcn_mfma_f32_16x16x32_bf16(b1_, aq[1], accS[ni], 0, 0, 0); \
        } \
        __builtin_amdgcn_s_setprio(0); \
        s16x4 pf[4]; \
        _Pragma("unroll") \
        for (int ni = 0; ni < 4; ni++) { \
            unsigned int e0 = __builtin_bit_cast(unsigned int, __builtin_amdgcn_exp2f(accS[ni][0])); \
            unsigned int e1 = __builtin_bit_cast(unsigned int, __builtin_amdgcn_exp2f(accS[ni][1])); \
            unsigned int e2 = __builtin_bit_cast(unsigned int, __builtin_amdgcn_exp2f(accS[ni][2])); \
            unsigned int e3 = __builtin_bit_cast(unsigned int, __builtin_amdgcn_exp2f(accS[ni][3])); \
            unsigned int lo = __builtin_amdgcn_perm(e1, e0, 0x07060302u); \
            unsigned int hi = __builtin_amdgcn_perm(e3, e2, 0x07060302u); \
            pf[ni] = __builtin_bit_cast(s16x4, uint2{lo, hi}); \
            accL = mfma16x16x16bf16(pf[ni], ones, accL); \
        } \
        __builtin_amdgcn_s_setprio(1); \
        _Pragma("unroll") \
        for (int ni = 0; ni < 4; ni++) { \
            const unsigned short* pv_ = (ni == 0) ? PV0_ : (ni == 1) ? PV1_ \
                                      : (ni == 2) ? PV2_ : PV3_; \
            _Pragma("unroll") \
            for (int di = 0; di < 4; di++) \
                accO[di] = mfma16x16x16bf16(pf[ni], \
                    __builtin_bit_cast(s16x4, *(const uint2*)(pv_ + di*1024)), accO[di]); \
        } \
        __builtin_amdgcn_s_setprio(0); \
    } while (0)

#define ATT_SYNC() do { \
        __builtin_amdgcn_sched_barrier(0); \
        asm volatile("s_waitcnt vmcnt(0)" ::: "memory"); \
        __builtin_amdgcn_s_barrier(); \
        __builtin_amdgcn_sched_barrier(0); \
    } while (0)

    STAGE_KV(0);                          // jt=0 -> buf0
    ATT_SYNC();
    for (int jt2 = 0; jt2 < 15; jt2++) {  // jt = 0..29
        STAGE_KV(1);                      // jt odd -> buf1
        ATT_JT(bK0a, bK0b, bV0_0, bV0_1, bV0_2, bV0_3);
        ATT_SYNC();
        STAGE_KV(0);                      // jt even -> buf0
        ATT_JT(bK1a, bK1b, bV1_0, bV1_1, bV1_2, bV1_3);
        ATT_SYNC();
    }
    STAGE_KV(1);                          // jt=31 -> buf1
    ATT_JT(bK0a, bK0b, bV0_0, bV0_1, bV0_2, bV0_3);   // jt=30
    ATT_SYNC();
    ATT_JT(bK1a, bK1b, bV1_0, bV1_1, bV1_2, bV1_3);   // jt=31
#undef ATT_SYNC
#undef ATT_JT
#undef STAGE_KV

    // accL[r] = row-sum L for q-row w*16+quad*4+r (uniform over ln)
    #pragma unroll
    for (int r = 0; r < 4; r++) {
        float inv = 1.f / accL[r];
        int n = qt*64 + w*16 + quad*4 + r;
        #pragma unroll
        for (int di = 0; di < 4; di++) {
            int c = h*64 + di*16 + ln;
            size_t gi = ((size_t)b*NN + n)*DIM + c;
            float o = accO[di][r]*inv + bf2f(As[gi]);
            attp[gi] = f2bf(o);
        }
    }
}

// ---------------------------------------------------------------------------
extern "C" void kernel_launch(void* const* d_in, const int* in_sizes, int n_in,
                              void* d_out, int out_size, void* d_ws, size_t ws_size,
                              hipStream_t stream) {
    const float* y2f = (const float*)d_in[0];
    const float* y2b = (const float*)d_in[1];
    const float* Wq  = (const float*)d_in[2];
    const float* bq  = (const float*)d_in[3];
    const float* Wk  = (const float*)d_in[4];
    const float* bk  = (const float*)d_in[5];
    const float* Wv  = (const float*)d_in[6];
    const float* bv  = (const float*)d_in[7];
    const float* Wo  = (const float*)d_in[8];
    const float* bo  = (const float*)d_in[9];
    float* out = (float*)d_out;

    const size_t NACT = (size_t)M_ROWS * DIM;  // 4,194,304 (8 MB as ushort)
    unsigned short* ws   = (unsigned short*)d_ws;
    unsigned short* Af   = ws;
    unsigned short* Ab   = ws + NACT;
    unsigned short* As   = ws + 2*NACT;
    unsigned short* Qh   = ws + 3*NACT;
    unsigned short* Kh   = ws + 4*NACT;
    unsigned short* Vt   = ws + 5*NACT;   // V written pre-transposed [b,h,d,n]
    unsigned short* Wt   = ws + 6*NACT;   // 4 x 1024 x 1024 bf16
    unsigned short* attp = Ab;            // overlay (Ab dead after QKV gemm)

    prep_all<<<dim3(6144), 256, 0, stream>>>(y2f, y2b, Wq, Wk, Wv, Wo,
                                             Af, Ab, As, Wt);
    gemm_qkv<<<dim3(32, 24), 256, 0, stream>>>(
        Af, Ab, As, Wt, bq, bk, bv, Qh, Kh, Vt);
    attn_kernel<<<dim3(32, 32), 256, 0, stream>>>(Qh, Kh, Vt, As, attp);
    gemm_out<<<dim3(64, 8), 256, 0, stream>>>(attp, Wt, bo, out);
}

// Round 4
// 218.698 us; speedup vs baseline: 1.1102x; 1.0003x over previous
//
#include <hip/hip_runtime.h>

#define DIM 1024
#define HEADS 16
#define BB 2
#define NN 2048
#define HD 64
#define M_ROWS (BB*NN)  // 4096

typedef __bf16 bf16x8 __attribute__((ext_vector_type(8)));
typedef float f32x4 __attribute__((ext_vector_type(4)));
typedef short s16x4 __attribute__((ext_vector_type(4)));

__device__ inline unsigned short f2bf(float f) {
    unsigned int u = __builtin_bit_cast(unsigned int, f);
    u += 0x7fffu + ((u >> 16) & 1u);
    return (unsigned short)(u >> 16);
}
__device__ inline float bf2f(unsigned short u) {
    return __builtin_bit_cast(float, (unsigned int)u << 16);
}
__device__ inline bf16x8 as_bf16x8(uint4 v) {
    return __builtin_bit_cast(bf16x8, v);
}
// async global->LDS, 16B per lane: LDS dest = base + lane*16 (wave-uniform
// base); global source address is per-lane (gather allowed).
__device__ __forceinline__ void gl_lds16(const unsigned short* g, unsigned short* l) {
    __builtin_amdgcn_global_load_lds(
        (const __attribute__((address_space(1))) unsigned int*)g,
        (__attribute__((address_space(3))) unsigned int*)l, 16, 0, 0);
}

// 16x16x16 bf16 MFMA (K=16): A/B = 4 bf16 (2 VGPRs), C/D = 4 f32.
__device__ __forceinline__ f32x4 mfma16x16x16bf16(s16x4 a, s16x4 b, f32x4 c) {
#if __has_builtin(__builtin_amdgcn_mfma_f32_16x16x16bf16_1k)
    return __builtin_amdgcn_mfma_f32_16x16x16bf16_1k(a, b, c, 0, 0, 0);
#else
    asm volatile("v_mfma_f32_16x16x16_bf16 %0, %1, %2, %0"
                 : "+v"(c) : "v"(a), "v"(b));
    return c;
#endif
}

// ---------------------------------------------------------------------------
// Merged prep: blocks 0..4095 = weight transpose (Wt[m][n][k] = W_m[k][n]),
// blocks 4096..6143 = activation bf16 prep.
// ---------------------------------------------------------------------------
__global__ __launch_bounds__(256) void prep_all(
    const float* __restrict__ y2f, const float* __restrict__ y2b,
    const float* __restrict__ Wq, const float* __restrict__ Wk,
    const float* __restrict__ Wv, const float* __restrict__ Wo,
    unsigned short* __restrict__ Af, unsigned short* __restrict__ Ab,
    unsigned short* __restrict__ As, unsigned short* __restrict__ Wt_all)
{
    __shared__ float tile[32][33];
    const int blk = blockIdx.x;
    if (blk < 4096) {
        const int m = blk >> 10, r = blk & 1023, bk = r & 31, bn = r >> 5;
        const float* W = (m == 0) ? Wq : (m == 1) ? Wk : (m == 2) ? Wv : Wo;
        const int tx = threadIdx.x & 31, ty = threadIdx.x >> 5;  // 32 x 8
        #pragma unroll
        for (int i = 0; i < 32; i += 8)
            tile[ty + i][tx] = W[(size_t)(bk*32 + ty + i)*DIM + bn*32 + tx];
        __syncthreads();
        unsigned short* dst = Wt_all + (size_t)m * DIM * DIM;
        #pragma unroll
        for (int i = 0; i < 32; i += 8)
            dst[(size_t)(bn*32 + ty + i)*DIM + bk*32 + tx] = f2bf(tile[tx][ty + i]);
    } else {
        const size_t idx = ((size_t)(blk - 4096)*256 + threadIdx.x) * 8;
        #pragma unroll
        for (int half = 0; half < 2; half++) {
            float4 f = *(const float4*)(y2f + idx + half*4);
            float4 b = *(const float4*)(y2b + idx + half*4);
            ushort4 of, ob, os;
            of.x = f2bf(f.x); of.y = f2bf(f.y); of.z = f2bf(f.z); of.w = f2bf(f.w);
            ob.x = f2bf(b.x); ob.y = f2bf(b.y); ob.z = f2bf(b.z); ob.w = f2bf(b.w);
            os.x = f2bf(f.x + b.x); os.y = f2bf(f.y + b.y);
            os.z = f2bf(f.z + b.z); os.w = f2bf(f.w + b.w);
            *(ushort4*)(Af + idx + half*4) = of;
            *(ushort4*)(Ab + idx + half*4) = ob;
            *(ushort4*)(As + idx + half*4) = os;
        }
    }
}

// ---------------------------------------------------------------------------
// Uniform QKV GEMM: grid (32, 24). mode = bn>>3 (0=Q,1=K,2=V); 128x128 tile,
// 32 K-iters. T4 counted-vmcnt pipeline: 3 staging buffers (48 KB),
// per iter: vmcnt(4) -> barrier -> STAGE(kt+2) -> compute(kt).
// ---------------------------------------------------------------------------
__global__ __launch_bounds__(256) void gemm_qkv(
    const unsigned short* __restrict__ Af, const unsigned short* __restrict__ Ab,
    const unsigned short* __restrict__ As,
    const unsigned short* __restrict__ Wt_all,
    const float* __restrict__ bq, const float* __restrict__ bk,
    const float* __restrict__ bv,
    unsigned short* __restrict__ Qh, unsigned short* __restrict__ Kh,
    unsigned short* __restrict__ Vt)
{
    const int bm = blockIdx.x;
    const int mode = blockIdx.y >> 3;       // 0=Q, 1=K, 2=V
    const int bn = blockIdx.y & 7;
    __shared__ __align__(16) unsigned short smem[3*8192];   // 48 KB
    const int t = threadIdx.x;
    const int w = t >> 6, lane = t & 63, ln = lane & 15, quad = lane >> 4;
    const int wm = w >> 1, wn = w & 1;
    const unsigned short* Wt = Wt_all + (size_t)mode * (DIM*DIM);
    const unsigned short* A0 = (mode == 0) ? Af : (mode == 1) ? Ab : As;

    const int srow = lane >> 2;
    const int scol = (lane & 3) * 8;

    const unsigned short* gA0 = A0 + (size_t)(bm*128 + w*32 + srow)*DIM + scol;
    const unsigned short* gA1 = gA0 + (size_t)16*DIM;
    const unsigned short* gB0 = Wt + (size_t)(bn*128 + w*32 + srow)*DIM + scol;
    const unsigned short* gB1 = gB0 + (size_t)16*DIM;

    const int aoff = (wm*64 + ln)*32 + quad*8;          // + mi*512
    const int boff = 4096 + (wn*64 + ln)*32 + quad*8;   // + ni*512

    f32x4 acc[4][4];
    #pragma unroll
    for (int mi = 0; mi < 4; mi++)
        #pragma unroll
        for (int ni = 0; ni < 4; ni++)
            acc[mi][ni] = (f32x4){0.f, 0.f, 0.f, 0.f};

#define STAGE_Q(BUF) do { \
        unsigned short* s_ = smem + (BUF)*8192; \
        gl_lds16(gA0, &s_[(w*32)*32]); \
        gl_lds16(gA1, &s_[(w*32 + 16)*32]); \
        gl_lds16(gB0, &s_[4096 + (w*32)*32]); \
        gl_lds16(gB1, &s_[4096 + (w*32 + 16)*32]); \
        gA0 += 32; gA1 += 32; gB0 += 32; gB1 += 32; } while (0)

#define COMP_Q(BUF) do { \
        const unsigned short* s_ = smem + (BUF)*8192; \
        bf16x8 af[4], bfr[4]; \
        _Pragma("unroll") \
        for (int mi = 0; mi < 4; mi++) \
            af[mi] = as_bf16x8(*(const uint4*)(s_ + aoff + mi*512)); \
        _Pragma("unroll") \
        for (int ni = 0; ni < 4; ni++) \
            bfr[ni] = as_bf16x8(*(const uint4*)(s_ + boff + ni*512)); \
        _Pragma("unroll") \
        for (int mi = 0; mi < 4; mi++) \
            _Pragma("unroll") \
            for (int ni = 0; ni < 4; ni++) \
                acc[mi][ni] = __builtin_amdgcn_mfma_f32_16x16x32_bf16(af[mi], bfr[ni], acc[mi][ni], 0, 0, 0); \
    } while (0)

#define QITER(B) do { \
        asm volatile("s_waitcnt vmcnt(4)" ::: "memory"); \
        __builtin_amdgcn_s_barrier(); \
        __builtin_amdgcn_sched_barrier(0); \
        STAGE_Q(((B) + 2) % 3); \
        COMP_Q(B); \
        __builtin_amdgcn_sched_barrier(0); \
    } while (0)

    STAGE_Q(0);
    STAGE_Q(1);
    for (int base = 0; base < 30; base += 3) {
        QITER(0); QITER(1); QITER(2);
    }
    asm volatile("s_waitcnt vmcnt(4)" ::: "memory");
    __builtin_amdgcn_s_barrier();
    __builtin_amdgcn_sched_barrier(0);
    COMP_Q(0);
    __builtin_amdgcn_sched_barrier(0);
    asm volatile("s_waitcnt vmcnt(0)" ::: "memory");
    __builtin_amdgcn_s_barrier();
    __builtin_amdgcn_sched_barrier(0);
    COMP_Q(1);
#undef QITER
#undef COMP_Q
#undef STAGE_Q

    const float* bias = (mode == 0) ? bq : (mode == 1) ? bk : bv;
    unsigned short* dst = (mode == 0) ? Qh : (mode == 1) ? Kh : Vt;
    if (mode < 2) {
        const float sc = (mode == 0) ? 0.125f * 1.4426950408889634f : 1.0f;
        #pragma unroll
        for (int mi = 0; mi < 4; mi++) {
            #pragma unroll
            for (int r = 0; r < 4; r++) {
                int grow = bm*128 + wm*64 + mi*16 + quad*4 + r;
                int b_ = grow >> 11, n = grow & (NN - 1);
                #pragma unroll
                for (int ni = 0; ni < 4; ni++) {
                    int gcol = bn*128 + wn*64 + ni*16 + ln;
                    int hh = gcol >> 6, dd = gcol & 63;
                    float val = (acc[mi][ni][r] + bias[gcol]) * sc;
                    dst[(((size_t)(b_*HEADS + hh))*NN + n)*HD + dd] = f2bf(val);
                }
            }
        }
    } else {
        // V: single-pass transpose through swizzled sT[128 dd][128 nn]
        __syncthreads();
        #pragma unroll
        for (int ni = 0; ni < 4; ni++) {
            int row_s = wn*64 + ni*16 + ln;            // local feature col dd
            float bsv = bias[bn*128 + row_s];
            int sxor = (row_s & 7) << 1;               // 8B-unit XOR swizzle
            #pragma unroll
            for (int mi = 0; mi < 4; mi++) {
                int u = wm*16 + mi*4 + quad;           // 8B unit along nn
                ushort4 pk;
                pk.x = f2bf(acc[mi][ni][0] + bsv);
                pk.y = f2bf(acc[mi][ni][1] + bsv);
                pk.z = f2bf(acc[mi][ni][2] + bsv);
                pk.w = f2bf(acc[mi][ni][3] + bsv);
                *(ushort4*)(&smem[row_s*128 + ((u ^ sxor) << 2)]) = pk;
            }
        }
        __syncthreads();
        const int b_ = bm >> 4;
        #pragma unroll
        for (int i = 0; i < 8; i++) {
            int idx = i*256 + t;                        // 0..2047 16B chunks
            int dd = idx >> 4, jc = idx & 15;
            int u = (jc*2) ^ ((dd & 7) << 1);
            int hh = bn*2 + (dd >> 6), d_ = dd & 63;
            *(uint4*)(dst + (((size_t)(b_*HEADS + hh))*HD + d_)*NN
                          + (size_t)(bm & 15)*128 + jc*8)
                = *(const uint4*)(&smem[dd*128 + (u << 2)]);
        }
    }
}

// ---------------------------------------------------------------------------
// Out projection: out[4096,1024] = attp @ Wo^T + bo (f32). 64x128 tile,
// grid (64, 8). T4 counted-vmcnt pipeline (3 loads/stage -> vmcnt(3)).
// ---------------------------------------------------------------------------
__global__ __launch_bounds__(256) void gemm_out(
    const unsigned short* __restrict__ attp,
    const unsigned short* __restrict__ Wt_all,
    const float* __restrict__ bo, float* __restrict__ out)
{
    const int bm = blockIdx.x, bn = blockIdx.y;
    __shared__ __align__(16) unsigned short smem[3*6144];   // 36 KB
    const int t = threadIdx.x;
    const int w = t >> 6, lane = t & 63, ln = lane & 15, quad = lane >> 4;
    const int wm = w >> 1, wn = w & 1;
    const unsigned short* Wt = Wt_all + (size_t)3 * (DIM*DIM);

    const int srow = lane >> 2;
    const int scol = (lane & 3) * 8;

    const unsigned short* gA = attp + (size_t)(bm*64 + w*16 + srow)*DIM + scol;
    const unsigned short* gB0 = Wt + (size_t)(bn*128 + w*32 + srow)*DIM + scol;
    const unsigned short* gB1 = gB0 + (size_t)16*DIM;

    const int aoff = (wm*32 + ln)*32 + quad*8;          // + mi*512
    const int boff = 2048 + (wn*64 + ln)*32 + quad*8;   // + ni*512

    f32x4 acc[2][4];
    #pragma unroll
    for (int mi = 0; mi < 2; mi++)
        #pragma unroll
        for (int ni = 0; ni < 4; ni++)
            acc[mi][ni] = (f32x4){0.f, 0.f, 0.f, 0.f};

#define STAGE_T(BUF) do { \
        unsigned short* s_ = smem + (BUF)*6144; \
        gl_lds16(gA, &s_[(w*16)*32]); \
        gl_lds16(gB0, &s_[2048 + (w*32)*32]); \
        gl_lds16(gB1, &s_[2048 + (w*32 + 16)*32]); \
        gA += 32; gB0 += 32; gB1 += 32; } while (0)

#define COMP_T(BUF) do { \
        const unsigned short* s_ = smem + (BUF)*6144; \
        bf16x8 af[2], bfr[4]; \
        _Pragma("unroll") \
        for (int mi = 0; mi < 2; mi++) \
            af[mi] = as_bf16x8(*(const uint4*)(s_ + aoff + mi*512)); \
        _Pragma("unroll") \
        for (int ni = 0; ni < 4; ni++) \
            bfr[ni] = as_bf16x8(*(const uint4*)(s_ + boff + ni*512)); \
        _Pragma("unroll") \
        for (int mi = 0; mi < 2; mi++) \
            _Pragma("unroll") \
            for (int ni = 0; ni < 4; ni++) \
                acc[mi][ni] = __builtin_amdgcn_mfma_f32_16x16x32_bf16(af[mi], bfr[ni], acc[mi][ni], 0, 0, 0); \
    } while (0)

#define TITER(B) do { \
        asm volatile("s_waitcnt vmcnt(3)" ::: "memory"); \
        __builtin_amdgcn_s_barrier(); \
        __builtin_amdgcn_sched_barrier(0); \
        STAGE_T(((B) + 2) % 3); \
        COMP_T(B); \
        __builtin_amdgcn_sched_barrier(0); \
    } while (0)

    STAGE_T(0);
    STAGE_T(1);
    for (int base = 0; base < 30; base += 3) {
        TITER(0); TITER(1); TITER(2);
    }
    asm volatile("s_waitcnt vmcnt(3)" ::: "memory");
    __builtin_amdgcn_s_barrier();
    __builtin_amdgcn_sched_barrier(0);
    COMP_T(0);
    __builtin_amdgcn_sched_barrier(0);
    asm volatile("s_waitcnt vmcnt(0)" ::: "memory");
    __builtin_amdgcn_s_barrier();
    __builtin_amdgcn_sched_barrier(0);
    COMP_T(1);
#undef TITER
#undef COMP_T
#undef STAGE_T

    #pragma unroll
    for (int mi = 0; mi < 2; mi++) {
        #pragma unroll
        for (int r = 0; r < 4; r++) {
            int grow = bm*64 + wm*32 + mi*16 + quad*4 + r;
            #pragma unroll
            for (int ni = 0; ni < 4; ni++) {
                int gcol = bn*128 + wn*64 + ni*16 + ln;
                out[(size_t)grow*DIM + gcol] = acc[mi][ni][r] + bo[gcol];
            }
        }
    }
}

// ---------------------------------------------------------------------------
// Flash attention v8: QBLK=128 (2 q-row m-tiles per wave). RATIONALE: the
// kernel is LDS-pipe-bound (R3 analysis: ~256 LDS cyc/wave-jt x 512 wave-jts
// = 131k cyc/CU vs 156k wall; all K/V fragment addresses are wave-invariant
// so every LDS read fed exactly 1 MFMA). Each K/V fragment read now feeds 2
// MFMAs (one per m-tile) -> LDS cycles per FLOP halved. Grid (32 bh, 16 qt)
// = 512 blocks (2/CU). Sync structure = R2's proven 2-buffer form:
// STAGE(next) -> compute(cur) -> vmcnt(0)+raw barrier (R3's pointer-hoist
// variant regressed; reverted to compiler-addressed form).
// ---------------------------------------------------------------------------
__global__ __launch_bounds__(256) void attn_kernel(
    const unsigned short* __restrict__ Qh, const unsigned short* __restrict__ Kh,
    const unsigned short* __restrict__ Vt, const unsigned short* __restrict__ As,
    unsigned short* __restrict__ attp)
{
    const int bh = blockIdx.x;      // b*16 + h
    const int qt = blockIdx.y;      // 0..15 (128-row q tiles)
    const int b = bh >> 4, h = bh & 15;
    const int t = threadIdx.x;
    const int w = t >> 6, lane = t & 63, ln = lane & 15, quad = lane >> 4;
    const int sw = ln & 7;          // fragment rows are == ln (mod 8)
    const float EBIAS = 17.312340490667562f;   // 12 * log2(e)

    __shared__ __align__(16) unsigned short sK[2][64*64];    // 16 KB [n][k]
    __shared__ __align__(16) unsigned short sVt[2][64*64];   // 16 KB [d][n]

    const unsigned short* Qb  = Qh + (size_t)bh * NN * HD + (size_t)qt * 128 * HD;
    const unsigned short* Kb  = Kh + (size_t)bh * NN * HD;
    const unsigned short* Vtb = Vt + (size_t)bh * HD * NN;   // [d][n]

    const int rl = lane >> 3, cb = lane & 7;

    // ---- Q fragments straight from global: 2 m-tiles x 2 k-frags ----
    bf16x8 aq[2][2];
    #pragma unroll
    for (int m = 0; m < 2; m++)
        #pragma unroll
        for (int k = 0; k < 2; k++)
            aq[m][k] = as_bf16x8(*(const uint4*)(
                Qb + (size_t)(m*64 + w*16 + ln)*HD + (k*4 + quad)*8));

    // stage tile jt into buffer bb (4 gl_lds16 per wave; XOR-swizzled cols)
#define STAGE_KV(JT, BBUF) do { \
        _Pragma("unroll") \
        for (int j = 0; j < 2; j++) { \
            int row = w*16 + j*8 + rl; \
            gl_lds16(Kb + (size_t)((JT)*64 + row)*HD + ((cb ^ (row & 7))*8), \
                     &sK[BBUF][(w*16 + j*8)*64]); \
            gl_lds16(Vtb + (size_t)row*NN + (JT)*64 + ((cb ^ (row & 7))*8), \
                     &sVt[BBUF][(w*16 + j*8)*64]); \
        } } while (0)

    const s16x4 ones = { (short)0x3F80, (short)0x3F80, (short)0x3F80, (short)0x3F80 };
    f32x4 accO[2][4], accL[2];
    #pragma unroll
    for (int m = 0; m < 2; m++) {
        accL[m] = (f32x4){0.f, 0.f, 0.f, 0.f};
        #pragma unroll
        for (int di = 0; di < 4; di++) accO[m][di] = (f32x4){0.f, 0.f, 0.f, 0.f};
    }

    STAGE_KV(0, 0);                       // prologue: tile 0 -> buf 0
    asm volatile("s_waitcnt vmcnt(0)" ::: "memory");
    __builtin_amdgcn_s_barrier();
    __builtin_amdgcn_sched_barrier(0);

    #pragma unroll 2
    for (int jt = 0; jt < 32; jt++) {
        const int cur = jt & 1;
        if (jt < 31) STAGE_KV(jt + 1, cur ^ 1);   // issue next tile first

        const unsigned short* sKc = sK[cur];
        const unsigned short* sVc = sVt[cur];

        // S^T: accS[m][ni] — lane: q-col = m*64+w*16+ln, kv = ni*16+quad*4+r.
        // One K-frag read feeds both m-tiles.
        f32x4 accS[2][4];
        #pragma unroll
        for (int m = 0; m < 2; m++)
            #pragma unroll
            for (int ni = 0; ni < 4; ni++)
                accS[m][ni] = (f32x4){-EBIAS, -EBIAS, -EBIAS, -EBIAS};
        __builtin_amdgcn_s_setprio(1);
        #pragma unroll
        for (int ni = 0; ni < 4; ni++) {
            bf16x8 b0 = as_bf16x8(*(const uint4*)(
                &sKc[(ni*16 + ln)*64 + (((0 + quad) ^ sw)*8)]));
            accS[0][ni] = __builtin_amdgcn_mfma_f32_16x16x32_bf16(b0, aq[0][0], accS[0][ni], 0, 0, 0);
            accS[1][ni] = __builtin_amdgcn_mfma_f32_16x16x32_bf16(b0, aq[1][0], accS[1][ni], 0, 0, 0);
            bf16x8 b1 = as_bf16x8(*(const uint4*)(
                &sKc[(ni*16 + ln)*64 + (((4 + quad) ^ sw)*8)]));
            accS[0][ni] = __builtin_amdgcn_mfma_f32_16x16x32_bf16(b1, aq[0][1], accS[0][ni], 0, 0, 0);
            accS[1][ni] = __builtin_amdgcn_mfma_f32_16x16x32_bf16(b1, aq[1][1], accS[1][ni], 0, 0, 0);
        }
        __builtin_amdgcn_s_setprio(0);

        // p = exp2(s-EBIAS); pack via v_perm (trunc); L via ones-MFMA
        s16x4 pf[2][4];
        #pragma unroll
        for (int m = 0; m < 2; m++)
            #pragma unroll
            for (int ni = 0; ni < 4; ni++) {
                unsigned int e0 = __builtin_bit_cast(unsigned int, __builtin_amdgcn_exp2f(accS[m][ni][0]));
                unsigned int e1 = __builtin_bit_cast(unsigned int, __builtin_amdgcn_exp2f(accS[m][ni][1]));
                unsigned int e2 = __builtin_bit_cast(unsigned int, __builtin_amdgcn_exp2f(accS[m][ni][2]));
                unsigned int e3 = __builtin_bit_cast(unsigned int, __builtin_amdgcn_exp2f(accS[m][ni][3]));
                unsigned int lo = __builtin_amdgcn_perm(e1, e0, 0x07060302u);
                unsigned int hi = __builtin_amdgcn_perm(e3, e2, 0x07060302u);
                pf[m][ni] = __builtin_bit_cast(s16x4, uint2{lo, hi});
                accL[m] = mfma16x16x16bf16(pf[m][ni], ones, accL[m]);
            }

        // O += P V: one V-frag read feeds both m-tiles.
        __builtin_amdgcn_s_setprio(1);
        #pragma unroll
        for (int ni = 0; ni < 4; ni++) {
            int blkv = 2*ni + (quad >> 1);
            int off = (quad & 1) * 4;
            #pragma unroll
            for (int di = 0; di < 4; di++) {
                s16x4 bv = __builtin_bit_cast(s16x4,
                    *(const uint2*)(&sVc[(di*16 + ln)*64 + ((blkv ^ sw)*8) + off]));
                accO[0][di] = mfma16x16x16bf16(pf[0][ni], bv, accO[0][di]);
                accO[1][di] = mfma16x16x16bf16(pf[1][ni], bv, accO[1][di]);
            }
        }
        __builtin_amdgcn_s_setprio(0);

        __builtin_amdgcn_sched_barrier(0);
        if (jt < 31) {
            asm volatile("s_waitcnt vmcnt(0)" ::: "memory");  // next tile landed
            __builtin_amdgcn_s_barrier();                     // cur fully read
            __builtin_amdgcn_sched_barrier(0);
        }
    }
#undef STAGE_KV

    // accL[m][r] = row-sum L for q-row m*64 + w*16 + quad*4 + r
    #pragma unroll
    for (int m = 0; m < 2; m++) {
        #pragma unroll
        for (int r = 0; r < 4; r++) {
            float inv = 1.f / accL[m][r];
            int n = qt*128 + m*64 + w*16 + quad*4 + r;
            #pragma unroll
            for (int di = 0; di < 4; di++) {
                int c = h*64 + di*16 + ln;
                size_t gi = ((size_t)b*NN + n)*DIM + c;
                float o = accO[m][di][r]*inv + bf2f(As[gi]);
                attp[gi] = f2bf(o);
            }
        }
    }
}

// ---------------------------------------------------------------------------
extern "C" void kernel_launch(void* const* d_in, const int* in_sizes, int n_in,
                              void* d_out, int out_size, void* d_ws, size_t ws_size,
                              hipStream_t stream) {
    const float* y2f = (const float*)d_in[0];
    const float* y2b = (const float*)d_in[1];
    const float* Wq  = (const float*)d_in[2];
    const float* bq  = (const float*)d_in[3];
    const float* Wk  = (const float*)d_in[4];
    const float* bk  = (const float*)d_in[5];
    const float* Wv  = (const float*)d_in[6];
    const float* bv  = (const float*)d_in[7];
    const float* Wo  = (const float*)d_in[8];
    const float* bo  = (const float*)d_in[9];
    float* out = (float*)d_out;

    const size_t NACT = (size_t)M_ROWS * DIM;  // 4,194,304 (8 MB as ushort)
    unsigned short* ws   = (unsigned short*)d_ws;
    unsigned short* Af   = ws;
    unsigned short* Ab   = ws + NACT;
    unsigned short* As   = ws + 2*NACT;
    unsigned short* Qh   = ws + 3*NACT;
    unsigned short* Kh   = ws + 4*NACT;
    unsigned short* Vt   = ws + 5*NACT;   // V written pre-transposed [b,h,d,n]
    unsigned short* Wt   = ws + 6*NACT;   // 4 x 1024 x 1024 bf16
    unsigned short* attp = Ab;            // overlay (Ab dead after QKV gemm)

    prep_all<<<dim3(6144), 256, 0, stream>>>(y2f, y2b, Wq, Wk, Wv, Wo,
                                             Af, Ab, As, Wt);
    gemm_qkv<<<dim3(32, 24), 256, 0, stream>>>(
        Af, Ab, As, Wt, bq, bk, bv, Qh, Kh, Vt);
    attn_kernel<<<dim3(32, 16), 256, 0, stream>>>(Qh, Kh, Vt, As, attp);
    gemm_out<<<dim3(64, 8), 256, 0, stream>>>(attp, Wt, bo, out);
}

// Round 5
// 217.704 us; speedup vs baseline: 1.1153x; 1.0046x over previous
//
#include <hip/hip_runtime.h>

#define DIM 1024
#define HEADS 16
#define BB 2
#define NN 2048
#define HD 64
#define M_ROWS (BB*NN)  // 4096

typedef __bf16 bf16x8 __attribute__((ext_vector_type(8)));
typedef float f32x4 __attribute__((ext_vector_type(4)));
typedef short s16x4 __attribute__((ext_vector_type(4)));

__device__ inline unsigned short f2bf(float f) {
    unsigned int u = __builtin_bit_cast(unsigned int, f);
    u += 0x7fffu + ((u >> 16) & 1u);
    return (unsigned short)(u >> 16);
}
__device__ inline float bf2f(unsigned short u) {
    return __builtin_bit_cast(float, (unsigned int)u << 16);
}
__device__ inline bf16x8 as_bf16x8(uint4 v) {
    return __builtin_bit_cast(bf16x8, v);
}
// async global->LDS, 16B per lane: LDS dest = base + lane*16 (wave-uniform
// base); global source address is per-lane (gather allowed).
__device__ __forceinline__ void gl_lds16(const unsigned short* g, unsigned short* l) {
    __builtin_amdgcn_global_load_lds(
        (const __attribute__((address_space(1))) unsigned int*)g,
        (__attribute__((address_space(3))) unsigned int*)l, 16, 0, 0);
}

// 16x16x16 bf16 MFMA (K=16): A/B = 4 bf16 (2 VGPRs), C/D = 4 f32.
__device__ __forceinline__ f32x4 mfma16x16x16bf16(s16x4 a, s16x4 b, f32x4 c) {
#if __has_builtin(__builtin_amdgcn_mfma_f32_16x16x16bf16_1k)
    return __builtin_amdgcn_mfma_f32_16x16x16bf16_1k(a, b, c, 0, 0, 0);
#else
    asm volatile("v_mfma_f32_16x16x16_bf16 %0, %1, %2, %0"
                 : "+v"(c) : "v"(a), "v"(b));
    return c;
#endif
}

// ---------------------------------------------------------------------------
// Merged prep: blocks 0..4095 = weight transpose (Wt[m][n][k] = W_m[k][n]),
// blocks 4096..6143 = activation bf16 prep.
// ---------------------------------------------------------------------------
__global__ __launch_bounds__(256) void prep_all(
    const float* __restrict__ y2f, const float* __restrict__ y2b,
    const float* __restrict__ Wq, const float* __restrict__ Wk,
    const float* __restrict__ Wv, const float* __restrict__ Wo,
    unsigned short* __restrict__ Af, unsigned short* __restrict__ Ab,
    unsigned short* __restrict__ As, unsigned short* __restrict__ Wt_all)
{
    __shared__ float tile[32][33];
    const int blk = blockIdx.x;
    if (blk < 4096) {
        const int m = blk >> 10, r = blk & 1023, bk = r & 31, bn = r >> 5;
        const float* W = (m == 0) ? Wq : (m == 1) ? Wk : (m == 2) ? Wv : Wo;
        const int tx = threadIdx.x & 31, ty = threadIdx.x >> 5;  // 32 x 8
        #pragma unroll
        for (int i = 0; i < 32; i += 8)
            tile[ty + i][tx] = W[(size_t)(bk*32 + ty + i)*DIM + bn*32 + tx];
        __syncthreads();
        unsigned short* dst = Wt_all + (size_t)m * DIM * DIM;
        #pragma unroll
        for (int i = 0; i < 32; i += 8)
            dst[(size_t)(bn*32 + ty + i)*DIM + bk*32 + tx] = f2bf(tile[tx][ty + i]);
    } else {
        const size_t idx = ((size_t)(blk - 4096)*256 + threadIdx.x) * 8;
        #pragma unroll
        for (int half = 0; half < 2; half++) {
            float4 f = *(const float4*)(y2f + idx + half*4);
            float4 b = *(const float4*)(y2b + idx + half*4);
            ushort4 of, ob, os;
            of.x = f2bf(f.x); of.y = f2bf(f.y); of.z = f2bf(f.z); of.w = f2bf(f.w);
            ob.x = f2bf(b.x); ob.y = f2bf(b.y); ob.z = f2bf(b.z); ob.w = f2bf(b.w);
            os.x = f2bf(f.x + b.x); os.y = f2bf(f.y + b.y);
            os.z = f2bf(f.z + b.z); os.w = f2bf(f.w + b.w);
            *(ushort4*)(Af + idx + half*4) = of;
            *(ushort4*)(Ab + idx + half*4) = ob;
            *(ushort4*)(As + idx + half*4) = os;
        }
    }
}

// ---------------------------------------------------------------------------
// Uniform QKV GEMM: grid (32, 24). mode = bn>>3 (0=Q,1=K,2=V); 128x128 tile,
// 32 K-iters. T4 counted-vmcnt pipeline: 3 staging buffers (48 KB),
// per iter: vmcnt(4) -> barrier -> STAGE(kt+2) -> compute(kt).
// ---------------------------------------------------------------------------
__global__ __launch_bounds__(256) void gemm_qkv(
    const unsigned short* __restrict__ Af, const unsigned short* __restrict__ Ab,
    const unsigned short* __restrict__ As,
    const unsigned short* __restrict__ Wt_all,
    const float* __restrict__ bq, const float* __restrict__ bk,
    const float* __restrict__ bv,
    unsigned short* __restrict__ Qh, unsigned short* __restrict__ Kh,
    unsigned short* __restrict__ Vt)
{
    const int bm = blockIdx.x;
    const int mode = blockIdx.y >> 3;       // 0=Q, 1=K, 2=V
    const int bn = blockIdx.y & 7;
    __shared__ __align__(16) unsigned short smem[3*8192];   // 48 KB
    const int t = threadIdx.x;
    const int w = t >> 6, lane = t & 63, ln = lane & 15, quad = lane >> 4;
    const int wm = w >> 1, wn = w & 1;
    const unsigned short* Wt = Wt_all + (size_t)mode * (DIM*DIM);
    const unsigned short* A0 = (mode == 0) ? Af : (mode == 1) ? Ab : As;

    const int srow = lane >> 2;
    const int scol = (lane & 3) * 8;

    const unsigned short* gA0 = A0 + (size_t)(bm*128 + w*32 + srow)*DIM + scol;
    const unsigned short* gA1 = gA0 + (size_t)16*DIM;
    const unsigned short* gB0 = Wt + (size_t)(bn*128 + w*32 + srow)*DIM + scol;
    const unsigned short* gB1 = gB0 + (size_t)16*DIM;

    const int aoff = (wm*64 + ln)*32 + quad*8;          // + mi*512
    const int boff = 4096 + (wn*64 + ln)*32 + quad*8;   // + ni*512

    f32x4 acc[4][4];
    #pragma unroll
    for (int mi = 0; mi < 4; mi++)
        #pragma unroll
        for (int ni = 0; ni < 4; ni++)
            acc[mi][ni] = (f32x4){0.f, 0.f, 0.f, 0.f};

#define STAGE_Q(BUF) do { \
        unsigned short* s_ = smem + (BUF)*8192; \
        gl_lds16(gA0, &s_[(w*32)*32]); \
        gl_lds16(gA1, &s_[(w*32 + 16)*32]); \
        gl_lds16(gB0, &s_[4096 + (w*32)*32]); \
        gl_lds16(gB1, &s_[4096 + (w*32 + 16)*32]); \
        gA0 += 32; gA1 += 32; gB0 += 32; gB1 += 32; } while (0)

#define COMP_Q(BUF) do { \
        const unsigned short* s_ = smem + (BUF)*8192; \
        bf16x8 af[4], bfr[4]; \
        _Pragma("unroll") \
        for (int mi = 0; mi < 4; mi++) \
            af[mi] = as_bf16x8(*(const uint4*)(s_ + aoff + mi*512)); \
        _Pragma("unroll") \
        for (int ni = 0; ni < 4; ni++) \
            bfr[ni] = as_bf16x8(*(const uint4*)(s_ + boff + ni*512)); \
        _Pragma("unroll") \
        for (int mi = 0; mi < 4; mi++) \
            _Pragma("unroll") \
            for (int ni = 0; ni < 4; ni++) \
                acc[mi][ni] = __builtin_amdgcn_mfma_f32_16x16x32_bf16(af[mi], bfr[ni], acc[mi][ni], 0, 0, 0); \
    } while (0)

#define QITER(B) do { \
        asm volatile("s_waitcnt vmcnt(4)" ::: "memory"); \
        __builtin_amdgcn_s_barrier(); \
        __builtin_amdgcn_sched_barrier(0); \
        STAGE_Q(((B) + 2) % 3); \
        COMP_Q(B); \
        __builtin_amdgcn_sched_barrier(0); \
    } while (0)

    STAGE_Q(0);
    STAGE_Q(1);
    for (int base = 0; base < 30; base += 3) {
        QITER(0); QITER(1); QITER(2);
    }
    asm volatile("s_waitcnt vmcnt(4)" ::: "memory");
    __builtin_amdgcn_s_barrier();
    __builtin_amdgcn_sched_barrier(0);
    COMP_Q(0);
    __builtin_amdgcn_sched_barrier(0);
    asm volatile("s_waitcnt vmcnt(0)" ::: "memory");
    __builtin_amdgcn_s_barrier();
    __builtin_amdgcn_sched_barrier(0);
    COMP_Q(1);
#undef QITER
#undef COMP_Q
#undef STAGE_Q

    const float* bias = (mode == 0) ? bq : (mode == 1) ? bk : bv;
    unsigned short* dst = (mode == 0) ? Qh : (mode == 1) ? Kh : Vt;
    if (mode < 2) {
        const float sc = (mode == 0) ? 0.125f * 1.4426950408889634f : 1.0f;
        #pragma unroll
        for (int mi = 0; mi < 4; mi++) {
            #pragma unroll
            for (int r = 0; r < 4; r++) {
                int grow = bm*128 + wm*64 + mi*16 + quad*4 + r;
                int b_ = grow >> 11, n = grow & (NN - 1);
                #pragma unroll
                for (int ni = 0; ni < 4; ni++) {
                    int gcol = bn*128 + wn*64 + ni*16 + ln;
                    int hh = gcol >> 6, dd = gcol & 63;
                    float val = (acc[mi][ni][r] + bias[gcol]) * sc;
                    dst[(((size_t)(b_*HEADS + hh))*NN + n)*HD + dd] = f2bf(val);
                }
            }
        }
    } else {
        // V: single-pass transpose through swizzled sT[128 dd][128 nn]
        __syncthreads();
        #pragma unroll
        for (int ni = 0; ni < 4; ni++) {
            int row_s = wn*64 + ni*16 + ln;            // local feature col dd
            float bsv = bias[bn*128 + row_s];
            int sxor = (row_s & 7) << 1;               // 8B-unit XOR swizzle
            #pragma unroll
            for (int mi = 0; mi < 4; mi++) {
                int u = wm*16 + mi*4 + quad;           // 8B unit along nn
                ushort4 pk;
                pk.x = f2bf(acc[mi][ni][0] + bsv);
                pk.y = f2bf(acc[mi][ni][1] + bsv);
                pk.z = f2bf(acc[mi][ni][2] + bsv);
                pk.w = f2bf(acc[mi][ni][3] + bsv);
                *(ushort4*)(&smem[row_s*128 + ((u ^ sxor) << 2)]) = pk;
            }
        }
        __syncthreads();
        const int b_ = bm >> 4;
        #pragma unroll
        for (int i = 0; i < 8; i++) {
            int idx = i*256 + t;                        // 0..2047 16B chunks
            int dd = idx >> 4, jc = idx & 15;
            int u = (jc*2) ^ ((dd & 7) << 1);
            int hh = bn*2 + (dd >> 6), d_ = dd & 63;
            *(uint4*)(dst + (((size_t)(b_*HEADS + hh))*HD + d_)*NN
                          + (size_t)(bm & 15)*128 + jc*8)
                = *(const uint4*)(&smem[dd*128 + (u << 2)]);
        }
    }
}

// ---------------------------------------------------------------------------
// Out projection: out[4096,1024] = attp @ Wo^T + bo (f32). 64x128 tile,
// grid (64, 8). T4 counted-vmcnt pipeline (3 loads/stage -> vmcnt(3)).
// ---------------------------------------------------------------------------
__global__ __launch_bounds__(256) void gemm_out(
    const unsigned short* __restrict__ attp,
    const unsigned short* __restrict__ Wt_all,
    const float* __restrict__ bo, float* __restrict__ out)
{
    const int bm = blockIdx.x, bn = blockIdx.y;
    __shared__ __align__(16) unsigned short smem[3*6144];   // 36 KB
    const int t = threadIdx.x;
    const int w = t >> 6, lane = t & 63, ln = lane & 15, quad = lane >> 4;
    const int wm = w >> 1, wn = w & 1;
    const unsigned short* Wt = Wt_all + (size_t)3 * (DIM*DIM);

    const int srow = lane >> 2;
    const int scol = (lane & 3) * 8;

    const unsigned short* gA = attp + (size_t)(bm*64 + w*16 + srow)*DIM + scol;
    const unsigned short* gB0 = Wt + (size_t)(bn*128 + w*32 + srow)*DIM + scol;
    const unsigned short* gB1 = gB0 + (size_t)16*DIM;

    const int aoff = (wm*32 + ln)*32 + quad*8;          // + mi*512
    const int boff = 2048 + (wn*64 + ln)*32 + quad*8;   // + ni*512

    f32x4 acc[2][4];
    #pragma unroll
    for (int mi = 0; mi < 2; mi++)
        #pragma unroll
        for (int ni = 0; ni < 4; ni++)
            acc[mi][ni] = (f32x4){0.f, 0.f, 0.f, 0.f};

#define STAGE_T(BUF) do { \
        unsigned short* s_ = smem + (BUF)*6144; \
        gl_lds16(gA, &s_[(w*16)*32]); \
        gl_lds16(gB0, &s_[2048 + (w*32)*32]); \
        gl_lds16(gB1, &s_[2048 + (w*32 + 16)*32]); \
        gA += 32; gB0 += 32; gB1 += 32; } while (0)

#define COMP_T(BUF) do { \
        const unsigned short* s_ = smem + (BUF)*6144; \
        bf16x8 af[2], bfr[4]; \
        _Pragma("unroll") \
        for (int mi = 0; mi < 2; mi++) \
            af[mi] = as_bf16x8(*(const uint4*)(s_ + aoff + mi*512)); \
        _Pragma("unroll") \
        for (int ni = 0; ni < 4; ni++) \
            bfr[ni] = as_bf16x8(*(const uint4*)(s_ + boff + ni*512)); \
        _Pragma("unroll") \
        for (int mi = 0; mi < 2; mi++) \
            _Pragma("unroll") \
            for (int ni = 0; ni < 4; ni++) \
                acc[mi][ni] = __builtin_amdgcn_mfma_f32_16x16x32_bf16(af[mi], bfr[ni], acc[mi][ni], 0, 0, 0); \
    } while (0)

#define TITER(B) do { \
        asm volatile("s_waitcnt vmcnt(3)" ::: "memory"); \
        __builtin_amdgcn_s_barrier(); \
        __builtin_amdgcn_sched_barrier(0); \
        STAGE_T(((B) + 2) % 3); \
        COMP_T(B); \
        __builtin_amdgcn_sched_barrier(0); \
    } while (0)

    STAGE_T(0);
    STAGE_T(1);
    for (int base = 0; base < 30; base += 3) {
        TITER(0); TITER(1); TITER(2);
    }
    asm volatile("s_waitcnt vmcnt(3)" ::: "memory");
    __builtin_amdgcn_s_barrier();
    __builtin_amdgcn_sched_barrier(0);
    COMP_T(0);
    __builtin_amdgcn_sched_barrier(0);
    asm volatile("s_waitcnt vmcnt(0)" ::: "memory");
    __builtin_amdgcn_s_barrier();
    __builtin_amdgcn_sched_barrier(0);
    COMP_T(1);
#undef TITER
#undef COMP_T
#undef STAGE_T

    #pragma unroll
    for (int mi = 0; mi < 2; mi++) {
        #pragma unroll
        for (int r = 0; r < 4; r++) {
            int grow = bm*64 + wm*32 + mi*16 + quad*4 + r;
            #pragma unroll
            for (int ni = 0; ni < 4; ni++) {
                int gcol = bn*128 + wn*64 + ni*16 + ln;
                out[(size_t)grow*DIM + gcol] = acc[mi][ni][r] + bo[gcol];
            }
        }
    }
}

// ---------------------------------------------------------------------------
// Flash attention v9 = v8 + cross-jt software pipeline (T15):
// R4 counters: MfmaUtil 41%, VALUBusy 42% with 2 waves/SIMD phase-locked by
// the per-jt barrier -> MFMA pipe idles during exp2 phase and vice versa.
// Now each barrier-to-barrier region holds QK^T(jt) [MFMA] + softmax/PV(jt-1)
// [VALU+MFMA], with NO register deps between exp2(jt-1) and QK(jt) -> the
// scheduler issues exp2 in the MFMA shadow. Needs: 2 accS sets (static
// names, rule #20), 4-buffer K/V rotation (stage target (jt+2)%4 never
// collides with PV's (jt-1)%4 read), counted vmcnt(4) (GEMM-proven).
// LDS 64 KB (exactly the static limit), 2 blocks/CU; VGPR rise is free
// (LDS-capped occupancy). g-loop kept rolled: 8 code bodies, not 32.
// ---------------------------------------------------------------------------
__global__ __launch_bounds__(256) void attn_kernel(
    const unsigned short* __restrict__ Qh, const unsigned short* __restrict__ Kh,
    const unsigned short* __restrict__ Vt, const unsigned short* __restrict__ As,
    unsigned short* __restrict__ attp)
{
    const int bh = blockIdx.x;      // b*16 + h
    const int qt = blockIdx.y;      // 0..15 (128-row q tiles)
    const int b = bh >> 4, h = bh & 15;
    const int t = threadIdx.x;
    const int w = t >> 6, lane = t & 63, ln = lane & 15, quad = lane >> 4;
    const int sw = ln & 7;          // fragment rows are == ln (mod 8)
    const float EBIAS = 17.312340490667562f;   // 12 * log2(e)

    __shared__ __align__(16) unsigned short sK[4][64*64];    // 32 KB [n][k]
    __shared__ __align__(16) unsigned short sVt[4][64*64];   // 32 KB [d][n]

    const unsigned short* Qb  = Qh + (size_t)bh * NN * HD + (size_t)qt * 128 * HD;
    const unsigned short* Kb  = Kh + (size_t)bh * NN * HD;
    const unsigned short* Vtb = Vt + (size_t)bh * HD * NN;   // [d][n]

    const int rl = lane >> 3, cb = lane & 7;

    // ---- Q fragments straight from global: 2 m-tiles x 2 k-frags ----
    bf16x8 aq[2][2];
    #pragma unroll
    for (int m = 0; m < 2; m++)
        #pragma unroll
        for (int k = 0; k < 2; k++)
            aq[m][k] = as_bf16x8(*(const uint4*)(
                Qb + (size_t)(m*64 + w*16 + ln)*HD + (k*4 + quad)*8));

    // ---- staging pointers (advance by constants per STAGE; GEMM pattern) ----
    const int r0 = w*16 + rl, r1 = r0 + 8;
    const unsigned short* gK0 = Kb + (size_t)r0*HD + (cb ^ (r0 & 7))*8;
    const unsigned short* gK1 = Kb + (size_t)r1*HD + (cb ^ (r1 & 7))*8;
    const unsigned short* gV0 = Vtb + (size_t)r0*NN + (cb ^ (r0 & 7))*8;
    const unsigned short* gV1 = Vtb + (size_t)r1*NN + (cb ^ (r1 & 7))*8;

#define STAGE_KV(BUF) do { \
        gl_lds16(gK0, &sK[BUF][(w*16)*64]); \
        gl_lds16(gK1, &sK[BUF][(w*16 + 8)*64]); \
        gl_lds16(gV0, &sVt[BUF][(w*16)*64]); \
        gl_lds16(gV1, &sVt[BUF][(w*16 + 8)*64]); \
        gK0 += 64*HD; gK1 += 64*HD; gV0 += 64; gV1 += 64; } while (0)

    const s16x4 ones = { (short)0x3F80, (short)0x3F80, (short)0x3F80, (short)0x3F80 };
    f32x4 accO[2][4], accL[2];
    #pragma unroll
    for (int m = 0; m < 2; m++) {
        accL[m] = (f32x4){0.f, 0.f, 0.f, 0.f};
        #pragma unroll
        for (int di = 0; di < 4; di++) accO[m][di] = (f32x4){0.f, 0.f, 0.f, 0.f};
    }
    f32x4 accSA[2][4], accSB[2][4];

    // QK^T of tile jt from sK[BUF] into ACCS (pre-biased with -EBIAS)
#define QK_TILE(BUF, ACCS) do { \
        _Pragma("unroll") \
        for (int m = 0; m < 2; m++) \
            _Pragma("unroll") \
            for (int ni = 0; ni < 4; ni++) \
                ACCS[m][ni] = (f32x4){-EBIAS, -EBIAS, -EBIAS, -EBIAS}; \
        _Pragma("unroll") \
        for (int ni = 0; ni < 4; ni++) { \
            bf16x8 b0_ = as_bf16x8(*(const uint4*)( \
                &sK[BUF][(ni*16 + ln)*64 + ((quad ^ sw)*8)])); \
            ACCS[0][ni] = __builtin_amdgcn_mfma_f32_16x16x32_bf16(b0_, aq[0][0], ACCS[0][ni], 0, 0, 0); \
            ACCS[1][ni] = __builtin_amdgcn_mfma_f32_16x16x32_bf16(b0_, aq[1][0], ACCS[1][ni], 0, 0, 0); \
            bf16x8 b1_ = as_bf16x8(*(const uint4*)( \
                &sK[BUF][(ni*16 + ln)*64 + (((4 + quad) ^ sw)*8)])); \
            ACCS[0][ni] = __builtin_amdgcn_mfma_f32_16x16x32_bf16(b1_, aq[0][1], ACCS[0][ni], 0, 0, 0); \
            ACCS[1][ni] = __builtin_amdgcn_mfma_f32_16x16x32_bf16(b1_, aq[1][1], ACCS[1][ni], 0, 0, 0); \
        } } while (0)

    // softmax (exp2, pack, L) + PV for the tile whose scores are in ACCS,
    // V in sVt[BUF]
#define SOFTPV_TILE(BUF, ACCS) do { \
        s16x4 pf[2][4]; \
        _Pragma("unroll") \
        for (int m = 0; m < 2; m++) \
            _Pragma("unroll") \
            for (int ni = 0; ni < 4; ni++) { \
                unsigned int e0 = __builtin_bit_cast(unsigned int, __builtin_amdgcn_exp2f(ACCS[m][ni][0])); \
                unsigned int e1 = __builtin_bit_cast(unsigned int, __builtin_amdgcn_exp2f(ACCS[m][ni][1])); \
                unsigned int e2 = __builtin_bit_cast(unsigned int, __builtin_amdgcn_exp2f(ACCS[m][ni][2])); \
                unsigned int e3 = __builtin_bit_cast(unsigned int, __builtin_amdgcn_exp2f(ACCS[m][ni][3])); \
                unsigned int lo = __builtin_amdgcn_perm(e1, e0, 0x07060302u); \
                unsigned int hi = __builtin_amdgcn_perm(e3, e2, 0x07060302u); \
                pf[m][ni] = __builtin_bit_cast(s16x4, uint2{lo, hi}); \
                accL[m] = mfma16x16x16bf16(pf[m][ni], ones, accL[m]); \
            } \
        _Pragma("unroll") \
        for (int ni = 0; ni < 4; ni++) { \
            int blkv = 2*ni + (quad >> 1); \
            int off = (quad & 1) * 4; \
            _Pragma("unroll") \
            for (int di = 0; di < 4; di++) { \
                s16x4 bv = __builtin_bit_cast(s16x4, \
                    *(const uint2*)(&sVt[BUF][(di*16 + ln)*64 + ((blkv ^ sw)*8) + off])); \
                accO[0][di] = mfma16x16x16bf16(pf[0][ni], bv, accO[0][di]); \
                accO[1][di] = mfma16x16x16bf16(pf[1][ni], bv, accO[1][di]); \
            } \
        } } while (0)

#define KV_SYNC(VM) do { \
        asm volatile("s_waitcnt vmcnt(" #VM ")" ::: "memory"); \
        __builtin_amdgcn_s_barrier(); \
        __builtin_amdgcn_sched_barrier(0); } while (0)

    // ---- pipeline: region(jt) = { STAGE(jt+2); QK(jt); SOFTPV(jt-1) } ----
    STAGE_KV(0);
    STAGE_KV(1);
    KV_SYNC(4);                   // buf0 staged (stage(1) in flight)
    STAGE_KV(2);
    QK_TILE(0, accSA);            // jt=0 (no softmax yet)
    #pragma unroll 1
    for (int g = 0; g < 7; ++g) { // jt = 1..28
        KV_SYNC(4); STAGE_KV(3); QK_TILE(1, accSB); SOFTPV_TILE(0, accSA);
        KV_SYNC(4); STAGE_KV(0); QK_TILE(2, accSA); SOFTPV_TILE(1, accSB);
        KV_SYNC(4); STAGE_KV(1); QK_TILE(3, accSB); SOFTPV_TILE(2, accSA);
        KV_SYNC(4); STAGE_KV(2); QK_TILE(0, accSA); SOFTPV_TILE(3, accSB);
    }
    KV_SYNC(4); STAGE_KV(3); QK_TILE(1, accSB); SOFTPV_TILE(0, accSA);  // jt=29
    KV_SYNC(4);              QK_TILE(2, accSA); SOFTPV_TILE(1, accSB);  // jt=30
    KV_SYNC(0);              QK_TILE(3, accSB); SOFTPV_TILE(2, accSA);  // jt=31
    SOFTPV_TILE(3, accSB);                                               // epi
#undef KV_SYNC
#undef SOFTPV_TILE
#undef QK_TILE
#undef STAGE_KV

    // accL[m][r] = row-sum L for q-row m*64 + w*16 + quad*4 + r
    #pragma unroll
    for (int m = 0; m < 2; m++) {
        #pragma unroll
        for (int r = 0; r < 4; r++) {
            float inv = 1.f / accL[m][r];
            int n = qt*128 + m*64 + w*16 + quad*4 + r;
            #pragma unroll
            for (int di = 0; di < 4; di++) {
                int c = h*64 + di*16 + ln;
                size_t gi = ((size_t)b*NN + n)*DIM + c;
                float o = accO[m][di][r]*inv + bf2f(As[gi]);
                attp[gi] = f2bf(o);
            }
        }
    }
}

// ---------------------------------------------------------------------------
extern "C" void kernel_launch(void* const* d_in, const int* in_sizes, int n_in,
                              void* d_out, int out_size, void* d_ws, size_t ws_size,
                              hipStream_t stream) {
    const float* y2f = (const float*)d_in[0];
    const float* y2b = (const float*)d_in[1];
    const float* Wq  = (const float*)d_in[2];
    const float* bq  = (const float*)d_in[3];
    const float* Wk  = (const float*)d_in[4];
    const float* bk  = (const float*)d_in[5];
    const float* Wv  = (const float*)d_in[6];
    const float* bv  = (const float*)d_in[7];
    const float* Wo  = (const float*)d_in[8];
    const float* bo  = (const float*)d_in[9];
    float* out = (float*)d_out;

    const size_t NACT = (size_t)M_ROWS * DIM;  // 4,194,304 (8 MB as ushort)
    unsigned short* ws   = (unsigned short*)d_ws;
    unsigned short* Af   = ws;
    unsigned short* Ab   = ws + NACT;
    unsigned short* As   = ws + 2*NACT;
    unsigned short* Qh   = ws + 3*NACT;
    unsigned short* Kh   = ws + 4*NACT;
    unsigned short* Vt   = ws + 5*NACT;   // V written pre-transposed [b,h,d,n]
    unsigned short* Wt   = ws + 6*NACT;   // 4 x 1024 x 1024 bf16
    unsigned short* attp = Ab;            // overlay (Ab dead after QKV gemm)

    prep_all<<<dim3(6144), 256, 0, stream>>>(y2f, y2b, Wq, Wk, Wv, Wo,
                                             Af, Ab, As, Wt);
    gemm_qkv<<<dim3(32, 24), 256, 0, stream>>>(
        Af, Ab, As, Wt, bq, bk, bv, Qh, Kh, Vt);
    attn_kernel<<<dim3(32, 16), 256, 0, stream>>>(Qh, Kh, Vt, As, attp);
    gemm_out<<<dim3(64, 8), 256, 0, stream>>>(attp, Wt, bo, out);
}

// Round 6
// 209.361 us; speedup vs baseline: 1.1597x; 1.0398x over previous
//
#include <hip/hip_runtime.h>

#define DIM 1024
#define HEADS 16
#define BB 2
#define NN 2048
#define HD 64
#define M_ROWS (BB*NN)  // 4096

typedef __bf16 bf16x8 __attribute__((ext_vector_type(8)));
typedef float f32x4 __attribute__((ext_vector_type(4)));
typedef short s16x4 __attribute__((ext_vector_type(4)));

__device__ inline unsigned short f2bf(float f) {
    unsigned int u = __builtin_bit_cast(unsigned int, f);
    u += 0x7fffu + ((u >> 16) & 1u);
    return (unsigned short)(u >> 16);
}
__device__ inline float bf2f(unsigned short u) {
    return __builtin_bit_cast(float, (unsigned int)u << 16);
}
__device__ inline bf16x8 as_bf16x8(uint4 v) {
    return __builtin_bit_cast(bf16x8, v);
}
// async global->LDS, 16B per lane: LDS dest = base + lane*16 (wave-uniform
// base); global source address is per-lane (gather allowed).
__device__ __forceinline__ void gl_lds16(const unsigned short* g, unsigned short* l) {
    __builtin_amdgcn_global_load_lds(
        (const __attribute__((address_space(1))) unsigned int*)g,
        (__attribute__((address_space(3))) unsigned int*)l, 16, 0, 0);
}

// 16x16x16 bf16 MFMA (K=16): A/B = 4 bf16 (2 VGPRs), C/D = 4 f32.
__device__ __forceinline__ f32x4 mfma16x16x16bf16(s16x4 a, s16x4 b, f32x4 c) {
#if __has_builtin(__builtin_amdgcn_mfma_f32_16x16x16bf16_1k)
    return __builtin_amdgcn_mfma_f32_16x16x16bf16_1k(a, b, c, 0, 0, 0);
#else
    asm volatile("v_mfma_f32_16x16x16_bf16 %0, %1, %2, %0"
                 : "+v"(c) : "v"(a), "v"(b));
    return c;
#endif
}

// ---------------------------------------------------------------------------
// Merged prep: blocks 0..4095 = weight transpose (Wt[m][n][k] = W_m[k][n]),
// blocks 4096..6143 = activation bf16 prep.
// ---------------------------------------------------------------------------
__global__ __launch_bounds__(256) void prep_all(
    const float* __restrict__ y2f, const float* __restrict__ y2b,
    const float* __restrict__ Wq, const float* __restrict__ Wk,
    const float* __restrict__ Wv, const float* __restrict__ Wo,
    unsigned short* __restrict__ Af, unsigned short* __restrict__ Ab,
    unsigned short* __restrict__ As, unsigned short* __restrict__ Wt_all)
{
    __shared__ float tile[32][33];
    const int blk = blockIdx.x;
    if (blk < 4096) {
        const int m = blk >> 10, r = blk & 1023, bk = r & 31, bn = r >> 5;
        const float* W = (m == 0) ? Wq : (m == 1) ? Wk : (m == 2) ? Wv : Wo;
        const int tx = threadIdx.x & 31, ty = threadIdx.x >> 5;  // 32 x 8
        #pragma unroll
        for (int i = 0; i < 32; i += 8)
            tile[ty + i][tx] = W[(size_t)(bk*32 + ty + i)*DIM + bn*32 + tx];
        __syncthreads();
        unsigned short* dst = Wt_all + (size_t)m * DIM * DIM;
        #pragma unroll
        for (int i = 0; i < 32; i += 8)
            dst[(size_t)(bn*32 + ty + i)*DIM + bk*32 + tx] = f2bf(tile[tx][ty + i]);
    } else {
        const size_t idx = ((size_t)(blk - 4096)*256 + threadIdx.x) * 8;
        #pragma unroll
        for (int half = 0; half < 2; half++) {
            float4 f = *(const float4*)(y2f + idx + half*4);
            float4 b = *(const float4*)(y2b + idx + half*4);
            ushort4 of, ob, os;
            of.x = f2bf(f.x); of.y = f2bf(f.y); of.z = f2bf(f.z); of.w = f2bf(f.w);
            ob.x = f2bf(b.x); ob.y = f2bf(b.y); ob.z = f2bf(b.z); ob.w = f2bf(b.w);
            os.x = f2bf(f.x + b.x); os.y = f2bf(f.y + b.y);
            os.z = f2bf(f.z + b.z); os.w = f2bf(f.w + b.w);
            *(ushort4*)(Af + idx + half*4) = of;
            *(ushort4*)(Ab + idx + half*4) = ob;
            *(ushort4*)(As + idx + half*4) = os;
        }
    }
}

// ---------------------------------------------------------------------------
// Uniform QKV GEMM, v2: 512 threads / 8 waves per block (TLP: 3 blocks/CU x
// 8 waves = 24 waves/CU = 6/SIMD, double R3's 3/SIMD — the kernel was
// latency-bound at 14% MfmaUtil pre-pipeline). 128x128 tile, 32 K-iters,
// T4 counted-vmcnt 3-buffer pipeline (2 loads/wave/stage -> vmcnt(2)).
// XCD-swizzled block id (768 = 8 x 96): each XCD sweeps bm with bn fixed
// -> weight panel stays hot in that XCD's L2.
// ---------------------------------------------------------------------------
__global__ __launch_bounds__(512) void gemm_qkv(
    const unsigned short* __restrict__ Af, const unsigned short* __restrict__ Ab,
    const unsigned short* __restrict__ As,
    const unsigned short* __restrict__ Wt_all,
    const float* __restrict__ bq, const float* __restrict__ bk,
    const float* __restrict__ bv,
    unsigned short* __restrict__ Qh, unsigned short* __restrict__ Kh,
    unsigned short* __restrict__ Vt)
{
    // XCD swizzle: lin 0..767 -> swz; bm fastest within an XCD chunk.
    const int lin = blockIdx.x + 32*blockIdx.y;
    const int swz = (lin & 7)*96 + (lin >> 3);
    const int bm = swz & 31;
    const int rest = swz >> 5;              // 0..23
    const int mode = rest >> 3;             // 0=Q, 1=K, 2=V
    const int bn = rest & 7;
    __shared__ __align__(16) unsigned short smem[3*8192];   // 48 KB
    const int t = threadIdx.x;
    const int w = t >> 6, lane = t & 63, ln = lane & 15, quad = lane >> 4;
    const int wm = w >> 1, wn = w & 1;      // 4 x 2 wave grid (32r x 64c each)
    const unsigned short* Wt = Wt_all + (size_t)mode * (DIM*DIM);
    const unsigned short* A0 = (mode == 0) ? Af : (mode == 1) ? Ab : As;

    const int srow = lane >> 2;             // 16 rows per wave-load
    const int scol = (lane & 3) * 8;

    const unsigned short* gA0 = A0 + (size_t)(bm*128 + w*16 + srow)*DIM + scol;
    const unsigned short* gB0 = Wt + (size_t)(bn*128 + w*16 + srow)*DIM + scol;

    const int aoff = (wm*32 + ln)*32 + quad*8;          // + mi*512
    const int boff = 4096 + (wn*64 + ln)*32 + quad*8;   // + ni*512

    f32x4 acc[2][4];
    #pragma unroll
    for (int mi = 0; mi < 2; mi++)
        #pragma unroll
        for (int ni = 0; ni < 4; ni++)
            acc[mi][ni] = (f32x4){0.f, 0.f, 0.f, 0.f};

#define STAGE_Q(BUF) do { \
        unsigned short* s_ = smem + (BUF)*8192; \
        gl_lds16(gA0, &s_[(w*16)*32]); \
        gl_lds16(gB0, &s_[4096 + (w*16)*32]); \
        gA0 += 32; gB0 += 32; } while (0)

#define COMP_Q(BUF) do { \
        const unsigned short* s_ = smem + (BUF)*8192; \
        bf16x8 af[2], bfr[4]; \
        _Pragma("unroll") \
        for (int mi = 0; mi < 2; mi++) \
            af[mi] = as_bf16x8(*(const uint4*)(s_ + aoff + mi*512)); \
        _Pragma("unroll") \
        for (int ni = 0; ni < 4; ni++) \
            bfr[ni] = as_bf16x8(*(const uint4*)(s_ + boff + ni*512)); \
        _Pragma("unroll") \
        for (int mi = 0; mi < 2; mi++) \
            _Pragma("unroll") \
            for (int ni = 0; ni < 4; ni++) \
                acc[mi][ni] = __builtin_amdgcn_mfma_f32_16x16x32_bf16(af[mi], bfr[ni], acc[mi][ni], 0, 0, 0); \
    } while (0)

#define QITER(B) do { \
        asm volatile("s_waitcnt vmcnt(2)" ::: "memory"); \
        __builtin_amdgcn_s_barrier(); \
        __builtin_amdgcn_sched_barrier(0); \
        STAGE_Q(((B) + 2) % 3); \
        COMP_Q(B); \
        __builtin_amdgcn_sched_barrier(0); \
    } while (0)

    STAGE_Q(0);
    STAGE_Q(1);
    for (int base = 0; base < 30; base += 3) {
        QITER(0); QITER(1); QITER(2);
    }
    asm volatile("s_waitcnt vmcnt(2)" ::: "memory");
    __builtin_amdgcn_s_barrier();
    __builtin_amdgcn_sched_barrier(0);
    COMP_Q(0);
    __builtin_amdgcn_sched_barrier(0);
    asm volatile("s_waitcnt vmcnt(0)" ::: "memory");
    __builtin_amdgcn_s_barrier();
    __builtin_amdgcn_sched_barrier(0);
    COMP_Q(1);
#undef QITER
#undef COMP_Q
#undef STAGE_Q

    const float* bias = (mode == 0) ? bq : (mode == 1) ? bk : bv;
    unsigned short* dst = (mode == 0) ? Qh : (mode == 1) ? Kh : Vt;
    if (mode < 2) {
        const float sc = (mode == 0) ? 0.125f * 1.4426950408889634f : 1.0f;
        #pragma unroll
        for (int mi = 0; mi < 2; mi++) {
            #pragma unroll
            for (int r = 0; r < 4; r++) {
                int grow = bm*128 + wm*32 + mi*16 + quad*4 + r;
                int b_ = grow >> 11, n = grow & (NN - 1);
                #pragma unroll
                for (int ni = 0; ni < 4; ni++) {
                    int gcol = bn*128 + wn*64 + ni*16 + ln;
                    int hh = gcol >> 6, dd = gcol & 63;
                    float val = (acc[mi][ni][r] + bias[gcol]) * sc;
                    dst[(((size_t)(b_*HEADS + hh))*NN + n)*HD + dd] = f2bf(val);
                }
            }
        }
    } else {
        // V: single-pass transpose through swizzled sT[128 dd][128 nn]
        __syncthreads();
        #pragma unroll
        for (int ni = 0; ni < 4; ni++) {
            int row_s = wn*64 + ni*16 + ln;            // local feature col dd
            float bsv = bias[bn*128 + row_s];
            int sxor = (row_s & 7) << 1;               // 8B-unit XOR swizzle
            #pragma unroll
            for (int mi = 0; mi < 2; mi++) {
                int u = wm*8 + mi*4 + quad;            // 8B unit along nn (0..31)
                ushort4 pk;
                pk.x = f2bf(acc[mi][ni][0] + bsv);
                pk.y = f2bf(acc[mi][ni][1] + bsv);
                pk.z = f2bf(acc[mi][ni][2] + bsv);
                pk.w = f2bf(acc[mi][ni][3] + bsv);
                *(ushort4*)(&smem[row_s*128 + ((u ^ sxor) << 2)]) = pk;
            }
        }
        __syncthreads();
        const int b_ = bm >> 4;
        #pragma unroll
        for (int i = 0; i < 4; i++) {
            int idx = i*512 + t;                        // 0..2047 16B chunks
            int dd = idx >> 4, jc = idx & 15;
            int u = (jc*2) ^ ((dd & 7) << 1);
            int hh = bn*2 + (dd >> 6), d_ = dd & 63;
            *(uint4*)(dst + (((size_t)(b_*HEADS + hh))*HD + d_)*NN
                          + (size_t)(bm & 15)*128 + jc*8)
                = *(const uint4*)(&smem[dd*128 + (u << 2)]);
        }
    }
}

// ---------------------------------------------------------------------------
// Out projection: out[4096,1024] = attp @ Wo^T + bo (f32). 64x128 tile,
// grid (64, 8). T4 counted-vmcnt pipeline (3 loads/stage -> vmcnt(3)).
// XCD-swizzled (512 = 8 x 64): each XCD sweeps bm with bn fixed.
// ---------------------------------------------------------------------------
__global__ __launch_bounds__(256) void gemm_out(
    const unsigned short* __restrict__ attp,
    const unsigned short* __restrict__ Wt_all,
    const float* __restrict__ bo, float* __restrict__ out)
{
    const int lin = blockIdx.x + 64*blockIdx.y;
    const int swz = (lin & 7)*64 + (lin >> 3);
    const int bm = swz & 63, bn = swz >> 6;
    __shared__ __align__(16) unsigned short smem[3*6144];   // 36 KB
    const int t = threadIdx.x;
    const int w = t >> 6, lane = t & 63, ln = lane & 15, quad = lane >> 4;
    const int wm = w >> 1, wn = w & 1;
    const unsigned short* Wt = Wt_all + (size_t)3 * (DIM*DIM);

    const int srow = lane >> 2;
    const int scol = (lane & 3) * 8;

    const unsigned short* gA = attp + (size_t)(bm*64 + w*16 + srow)*DIM + scol;
    const unsigned short* gB0 = Wt + (size_t)(bn*128 + w*32 + srow)*DIM + scol;
    const unsigned short* gB1 = gB0 + (size_t)16*DIM;

    const int aoff = (wm*32 + ln)*32 + quad*8;          // + mi*512
    const int boff = 2048 + (wn*64 + ln)*32 + quad*8;   // + ni*512

    f32x4 acc[2][4];
    #pragma unroll
    for (int mi = 0; mi < 2; mi++)
        #pragma unroll
        for (int ni = 0; ni < 4; ni++)
            acc[mi][ni] = (f32x4){0.f, 0.f, 0.f, 0.f};

#define STAGE_T(BUF) do { \
        unsigned short* s_ = smem + (BUF)*6144; \
        gl_lds16(gA, &s_[(w*16)*32]); \
        gl_lds16(gB0, &s_[2048 + (w*32)*32]); \
        gl_lds16(gB1, &s_[2048 + (w*32 + 16)*32]); \
        gA += 32; gB0 += 32; gB1 += 32; } while (0)

#define COMP_T(BUF) do { \
        const unsigned short* s_ = smem + (BUF)*6144; \
        bf16x8 af[2], bfr[4]; \
        _Pragma("unroll") \
        for (int mi = 0; mi < 2; mi++) \
            af[mi] = as_bf16x8(*(const uint4*)(s_ + aoff + mi*512)); \
        _Pragma("unroll") \
        for (int ni = 0; ni < 4; ni++) \
            bfr[ni] = as_bf16x8(*(const uint4*)(s_ + boff + ni*512)); \
        _Pragma("unroll") \
        for (int mi = 0; mi < 2; mi++) \
            _Pragma("unroll") \
            for (int ni = 0; ni < 4; ni++) \
                acc[mi][ni] = __builtin_amdgcn_mfma_f32_16x16x32_bf16(af[mi], bfr[ni], acc[mi][ni], 0, 0, 0); \
    } while (0)

#define TITER(B) do { \
        asm volatile("s_waitcnt vmcnt(3)" ::: "memory"); \
        __builtin_amdgcn_s_barrier(); \
        __builtin_amdgcn_sched_barrier(0); \
        STAGE_T(((B) + 2) % 3); \
        COMP_T(B); \
        __builtin_amdgcn_sched_barrier(0); \
    } while (0)

    STAGE_T(0);
    STAGE_T(1);
    for (int base = 0; base < 30; base += 3) {
        TITER(0); TITER(1); TITER(2);
    }
    asm volatile("s_waitcnt vmcnt(3)" ::: "memory");
    __builtin_amdgcn_s_barrier();
    __builtin_amdgcn_sched_barrier(0);
    COMP_T(0);
    __builtin_amdgcn_sched_barrier(0);
    asm volatile("s_waitcnt vmcnt(0)" ::: "memory");
    __builtin_amdgcn_s_barrier();
    __builtin_amdgcn_sched_barrier(0);
    COMP_T(1);
#undef TITER
#undef COMP_T
#undef STAGE_T

    #pragma unroll
    for (int mi = 0; mi < 2; mi++) {
        #pragma unroll
        for (int r = 0; r < 4; r++) {
            int grow = bm*64 + wm*32 + mi*16 + quad*4 + r;
            #pragma unroll
            for (int ni = 0; ni < 4; ni++) {
                int gcol = bn*128 + wn*64 + ni*16 + ln;
                out[(size_t)grow*DIM + gcol] = acc[mi][ni][r] + bo[gcol];
            }
        }
    }
}

// ---------------------------------------------------------------------------
// Flash attention v10 = R4's proven structure (57.2us profiled; QBLK=128,
// 2 m-tiles/wave, 2-buffer STAGE(next)->compute->vmcnt(0)+barrier, setprio)
// + one micro-opt: accS init via MFMA C-operand (persistent CB register
// holding -EBIAS) instead of 32 v_mov per region. R5's cross-jt pipeline
// REVERTED (regressed 57->72: region fences reduced overlap).
// ---------------------------------------------------------------------------
__global__ __launch_bounds__(256) void attn_kernel(
    const unsigned short* __restrict__ Qh, const unsigned short* __restrict__ Kh,
    const unsigned short* __restrict__ Vt, const unsigned short* __restrict__ As,
    unsigned short* __restrict__ attp)
{
    const int bh = blockIdx.x;      // b*16 + h
    const int qt = blockIdx.y;      // 0..15 (128-row q tiles)
    const int b = bh >> 4, h = bh & 15;
    const int t = threadIdx.x;
    const int w = t >> 6, lane = t & 63, ln = lane & 15, quad = lane >> 4;
    const int sw = ln & 7;          // fragment rows are == ln (mod 8)
    const float EBIAS = 17.312340490667562f;   // 12 * log2(e)

    __shared__ __align__(16) unsigned short sK[2][64*64];    // 16 KB [n][k]
    __shared__ __align__(16) unsigned short sVt[2][64*64];   // 16 KB [d][n]

    const unsigned short* Qb  = Qh + (size_t)bh * NN * HD + (size_t)qt * 128 * HD;
    const unsigned short* Kb  = Kh + (size_t)bh * NN * HD;
    const unsigned short* Vtb = Vt + (size_t)bh * HD * NN;   // [d][n]

    const int rl = lane >> 3, cb = lane & 7;

    // ---- Q fragments straight from global: 2 m-tiles x 2 k-frags ----
    bf16x8 aq[2][2];
    #pragma unroll
    for (int m = 0; m < 2; m++)
        #pragma unroll
        for (int k = 0; k < 2; k++)
            aq[m][k] = as_bf16x8(*(const uint4*)(
                Qb + (size_t)(m*64 + w*16 + ln)*HD + (k*4 + quad)*8));

    // stage tile jt into buffer bb (4 gl_lds16 per wave; XOR-swizzled cols)
#define STAGE_KV(JT, BBUF) do { \
        _Pragma("unroll") \
        for (int j = 0; j < 2; j++) { \
            int row = w*16 + j*8 + rl; \
            gl_lds16(Kb + (size_t)((JT)*64 + row)*HD + ((cb ^ (row & 7))*8), \
                     &sK[BBUF][(w*16 + j*8)*64]); \
            gl_lds16(Vtb + (size_t)row*NN + (JT)*64 + ((cb ^ (row & 7))*8), \
                     &sVt[BBUF][(w*16 + j*8)*64]); \
        } } while (0)

    const s16x4 ones = { (short)0x3F80, (short)0x3F80, (short)0x3F80, (short)0x3F80 };
    const f32x4 CB = (f32x4){-EBIAS, -EBIAS, -EBIAS, -EBIAS};  // persistent C-init
    f32x4 accO[2][4], accL[2];
    #pragma unroll
    for (int m = 0; m < 2; m++) {
        accL[m] = (f32x4){0.f, 0.f, 0.f, 0.f};
        #pragma unroll
        for (int di = 0; di < 4; di++) accO[m][di] = (f32x4){0.f, 0.f, 0.f, 0.f};
    }

    STAGE_KV(0, 0);                       // prologue: tile 0 -> buf 0
    asm volatile("s_waitcnt vmcnt(0)" ::: "memory");
    __builtin_amdgcn_s_barrier();
    __builtin_amdgcn_sched_barrier(0);

    #pragma unroll 2
    for (int jt = 0; jt < 32; jt++) {
        const int cur = jt & 1;
        if (jt < 31) STAGE_KV(jt + 1, cur ^ 1);   // issue next tile first

        const unsigned short* sKc = sK[cur];
        const unsigned short* sVc = sVt[cur];

        // S^T: accS[m][ni] — lane: q-col = m*64+w*16+ln, kv = ni*16+quad*4+r.
        // First MFMA of each chain takes CB (-EBIAS) as C: no init movs.
        f32x4 accS[2][4];
        __builtin_amdgcn_s_setprio(1);
        #pragma unroll
        for (int ni = 0; ni < 4; ni++) {
            bf16x8 b0 = as_bf16x8(*(const uint4*)(
                &sKc[(ni*16 + ln)*64 + (((0 + quad) ^ sw)*8)]));
            accS[0][ni] = __builtin_amdgcn_mfma_f32_16x16x32_bf16(b0, aq[0][0], CB, 0, 0, 0);
            accS[1][ni] = __builtin_amdgcn_mfma_f32_16x16x32_bf16(b0, aq[1][0], CB, 0, 0, 0);
            bf16x8 b1 = as_bf16x8(*(const uint4*)(
                &sKc[(ni*16 + ln)*64 + (((4 + quad) ^ sw)*8)]));
            accS[0][ni] = __builtin_amdgcn_mfma_f32_16x16x32_bf16(b1, aq[0][1], accS[0][ni], 0, 0, 0);
            accS[1][ni] = __builtin_amdgcn_mfma_f32_16x16x32_bf16(b1, aq[1][1], accS[1][ni], 0, 0, 0);
        }
        __builtin_amdgcn_s_setprio(0);

        // p = exp2(s-EBIAS); pack via v_perm (trunc); L via ones-MFMA
        s16x4 pf[2][4];
        #pragma unroll
        for (int m = 0; m < 2; m++)
            #pragma unroll
            for (int ni = 0; ni < 4; ni++) {
                unsigned int e0 = __builtin_bit_cast(unsigned int, __builtin_amdgcn_exp2f(accS[m][ni][0]));
                unsigned int e1 = __builtin_bit_cast(unsigned int, __builtin_amdgcn_exp2f(accS[m][ni][1]));
                unsigned int e2 = __builtin_bit_cast(unsigned int, __builtin_amdgcn_exp2f(accS[m][ni][2]));
                unsigned int e3 = __builtin_bit_cast(unsigned int, __builtin_amdgcn_exp2f(accS[m][ni][3]));
                unsigned int lo = __builtin_amdgcn_perm(e1, e0, 0x07060302u);
                unsigned int hi = __builtin_amdgcn_perm(e3, e2, 0x07060302u);
                pf[m][ni] = __builtin_bit_cast(s16x4, uint2{lo, hi});
                accL[m] = mfma16x16x16bf16(pf[m][ni], ones, accL[m]);
            }

        // O += P V: one V-frag read feeds both m-tiles.
        __builtin_amdgcn_s_setprio(1);
        #pragma unroll
        for (int ni = 0; ni < 4; ni++) {
            int blkv = 2*ni + (quad >> 1);
            int off = (quad & 1) * 4;
            #pragma unroll
            for (int di = 0; di < 4; di++) {
                s16x4 bv = __builtin_bit_cast(s16x4,
                    *(const uint2*)(&sVc[(di*16 + ln)*64 + ((blkv ^ sw)*8) + off]));
                accO[0][di] = mfma16x16x16bf16(pf[0][ni], bv, accO[0][di]);
                accO[1][di] = mfma16x16x16bf16(pf[1][ni], bv, accO[1][di]);
            }
        }
        __builtin_amdgcn_s_setprio(0);

        __builtin_amdgcn_sched_barrier(0);
        if (jt < 31) {
            asm volatile("s_waitcnt vmcnt(0)" ::: "memory");  // next tile landed
            __builtin_amdgcn_s_barrier();                     // cur fully read
            __builtin_amdgcn_sched_barrier(0);
        }
    }
#undef STAGE_KV

    // accL[m][r] = row-sum L for q-row m*64 + w*16 + quad*4 + r
    #pragma unroll
    for (int m = 0; m < 2; m++) {
        #pragma unroll
        for (int r = 0; r < 4; r++) {
            float inv = 1.f / accL[m][r];
            int n = qt*128 + m*64 + w*16 + quad*4 + r;
            #pragma unroll
            for (int di = 0; di < 4; di++) {
                int c = h*64 + di*16 + ln;
                size_t gi = ((size_t)b*NN + n)*DIM + c;
                float o = accO[m][di][r]*inv + bf2f(As[gi]);
                attp[gi] = f2bf(o);
            }
        }
    }
}

// ---------------------------------------------------------------------------
extern "C" void kernel_launch(void* const* d_in, const int* in_sizes, int n_in,
                              void* d_out, int out_size, void* d_ws, size_t ws_size,
                              hipStream_t stream) {
    const float* y2f = (const float*)d_in[0];
    const float* y2b = (const float*)d_in[1];
    const float* Wq  = (const float*)d_in[2];
    const float* bq  = (const float*)d_in[3];
    const float* Wk  = (const float*)d_in[4];
    const float* bk  = (const float*)d_in[5];
    const float* Wv  = (const float*)d_in[6];
    const float* bv  = (const float*)d_in[7];
    const float* Wo  = (const float*)d_in[8];
    const float* bo  = (const float*)d_in[9];
    float* out = (float*)d_out;

    const size_t NACT = (size_t)M_ROWS * DIM;  // 4,194,304 (8 MB as ushort)
    unsigned short* ws   = (unsigned short*)d_ws;
    unsigned short* Af   = ws;
    unsigned short* Ab   = ws + NACT;
    unsigned short* As   = ws + 2*NACT;
    unsigned short* Qh   = ws + 3*NACT;
    unsigned short* Kh   = ws + 4*NACT;
    unsigned short* Vt   = ws + 5*NACT;   // V written pre-transposed [b,h,d,n]
    unsigned short* Wt   = ws + 6*NACT;   // 4 x 1024 x 1024 bf16
    unsigned short* attp = Ab;            // overlay (Ab dead after QKV gemm)

    prep_all<<<dim3(6144), 256, 0, stream>>>(y2f, y2b, Wq, Wk, Wv, Wo,
                                             Af, Ab, As, Wt);
    gemm_qkv<<<dim3(32, 24), 512, 0, stream>>>(
        Af, Ab, As, Wt, bq, bk, bv, Qh, Kh, Vt);
    attn_kernel<<<dim3(32, 16), 256, 0, stream>>>(Qh, Kh, Vt, As, attp);
    gemm_out<<<dim3(64, 8), 256, 0, stream>>>(attp, Wt, bo, out);
}

// Round 7
// 208.057 us; speedup vs baseline: 1.1670x; 1.0063x over previous
//
#include <hip/hip_runtime.h>

#define DIM 1024
#define HEADS 16
#define BB 2
#define NN 2048
#define HD 64
#define M_ROWS (BB*NN)  // 4096

typedef __bf16 bf16x8 __attribute__((ext_vector_type(8)));
typedef float f32x4 __attribute__((ext_vector_type(4)));
typedef short s16x4 __attribute__((ext_vector_type(4)));

__device__ inline unsigned short f2bf(float f) {
    unsigned int u = __builtin_bit_cast(unsigned int, f);
    u += 0x7fffu + ((u >> 16) & 1u);
    return (unsigned short)(u >> 16);
}
__device__ inline float bf2f(unsigned short u) {
    return __builtin_bit_cast(float, (unsigned int)u << 16);
}
__device__ inline bf16x8 as_bf16x8(uint4 v) {
    return __builtin_bit_cast(bf16x8, v);
}
// async global->LDS, 16B per lane: LDS dest = base + lane*16 (wave-uniform
// base); global source address is per-lane (gather allowed).
__device__ __forceinline__ void gl_lds16(const unsigned short* g, unsigned short* l) {
    __builtin_amdgcn_global_load_lds(
        (const __attribute__((address_space(1))) unsigned int*)g,
        (__attribute__((address_space(3))) unsigned int*)l, 16, 0, 0);
}

// 16x16x16 bf16 MFMA (K=16): A/B = 4 bf16 (2 VGPRs), C/D = 4 f32.
__device__ __forceinline__ f32x4 mfma16x16x16bf16(s16x4 a, s16x4 b, f32x4 c) {
#if __has_builtin(__builtin_amdgcn_mfma_f32_16x16x16bf16_1k)
    return __builtin_amdgcn_mfma_f32_16x16x16bf16_1k(a, b, c, 0, 0, 0);
#else
    asm volatile("v_mfma_f32_16x16x16_bf16 %0, %1, %2, %0"
                 : "+v"(c) : "v"(a), "v"(b));
    return c;
#endif
}

// ---------------------------------------------------------------------------
// Merged prep v2: blocks 0..1023 = weight transpose in 64x64 f32 tiles
// (float4 loads 16B/lane, uint4 = 8xbf16 stores 16B/lane; was 32x32 tiles
// with 4B loads + 64B store segments). blocks 1024..3071 = activation prep.
// ---------------------------------------------------------------------------
__global__ __launch_bounds__(256) void prep_all(
    const float* __restrict__ y2f, const float* __restrict__ y2b,
    const float* __restrict__ Wq, const float* __restrict__ Wk,
    const float* __restrict__ Wv, const float* __restrict__ Wo,
    unsigned short* __restrict__ Af, unsigned short* __restrict__ Ab,
    unsigned short* __restrict__ As, unsigned short* __restrict__ Wt_all)
{
    __shared__ float tile[64][68];    // 17.4 KB; rows 272B (16B-aligned)
    const int blk = blockIdx.x;
    if (blk < 1024) {
        const int m = blk >> 8, r = blk & 255, bk = r & 15, bn = r >> 4;
        const float* W = (m == 0) ? Wq : (m == 1) ? Wk : (m == 2) ? Wv : Wo;
        const int tx = threadIdx.x & 15, ty = threadIdx.x >> 4;  // 16 x 16
        #pragma unroll
        for (int i = 0; i < 64; i += 16)
            *(float4*)(&tile[ty + i][tx*4]) =
                *(const float4*)(&W[(size_t)(bk*64 + ty + i)*DIM + bn*64 + tx*4]);
        __syncthreads();
        unsigned short* dst = Wt_all + (size_t)m * DIM * DIM;
        #pragma unroll
        for (int i = 0; i < 2; i++) {
            int chunk = i*256 + threadIdx.x;        // 0..511
            int n = chunk >> 3, kc = (chunk & 7)*8; // Wt row = n, col kc..kc+7
            unsigned int p0 = (unsigned)f2bf(tile[kc+0][n]) | ((unsigned)f2bf(tile[kc+1][n]) << 16);
            unsigned int p1 = (unsigned)f2bf(tile[kc+2][n]) | ((unsigned)f2bf(tile[kc+3][n]) << 16);
            unsigned int p2 = (unsigned)f2bf(tile[kc+4][n]) | ((unsigned)f2bf(tile[kc+5][n]) << 16);
            unsigned int p3 = (unsigned)f2bf(tile[kc+6][n]) | ((unsigned)f2bf(tile[kc+7][n]) << 16);
            *(uint4*)(&dst[(size_t)(bn*64 + n)*DIM + bk*64 + kc]) = uint4{p0, p1, p2, p3};
        }
    } else {
        const size_t idx = ((size_t)(blk - 1024)*256 + threadIdx.x) * 8;
        #pragma unroll
        for (int half = 0; half < 2; half++) {
            float4 f = *(const float4*)(y2f + idx + half*4);
            float4 b = *(const float4*)(y2b + idx + half*4);
            ushort4 of, ob, os;
            of.x = f2bf(f.x); of.y = f2bf(f.y); of.z = f2bf(f.z); of.w = f2bf(f.w);
            ob.x = f2bf(b.x); ob.y = f2bf(b.y); ob.z = f2bf(b.z); ob.w = f2bf(b.w);
            os.x = f2bf(f.x + b.x); os.y = f2bf(f.y + b.y);
            os.z = f2bf(f.z + b.z); os.w = f2bf(f.w + b.w);
            *(ushort4*)(Af + idx + half*4) = of;
            *(ushort4*)(Ab + idx + half*4) = ob;
            *(ushort4*)(As + idx + half*4) = os;
        }
    }
}

// ---------------------------------------------------------------------------
// Uniform QKV GEMM (unchanged from R6): 512 threads / 8 waves, 128x128 tile,
// T4 counted-vmcnt 3-buffer pipeline, XCD-swizzled block id.
// ---------------------------------------------------------------------------
__global__ __launch_bounds__(512) void gemm_qkv(
    const unsigned short* __restrict__ Af, const unsigned short* __restrict__ Ab,
    const unsigned short* __restrict__ As,
    const unsigned short* __restrict__ Wt_all,
    const float* __restrict__ bq, const float* __restrict__ bk,
    const float* __restrict__ bv,
    unsigned short* __restrict__ Qh, unsigned short* __restrict__ Kh,
    unsigned short* __restrict__ Vt)
{
    const int lin = blockIdx.x + 32*blockIdx.y;
    const int swz = (lin & 7)*96 + (lin >> 3);
    const int bm = swz & 31;
    const int rest = swz >> 5;              // 0..23
    const int mode = rest >> 3;             // 0=Q, 1=K, 2=V
    const int bn = rest & 7;
    __shared__ __align__(16) unsigned short smem[3*8192];   // 48 KB
    const int t = threadIdx.x;
    const int w = t >> 6, lane = t & 63, ln = lane & 15, quad = lane >> 4;
    const int wm = w >> 1, wn = w & 1;      // 4 x 2 wave grid (32r x 64c each)
    const unsigned short* Wt = Wt_all + (size_t)mode * (DIM*DIM);
    const unsigned short* A0 = (mode == 0) ? Af : (mode == 1) ? Ab : As;

    const int srow = lane >> 2;             // 16 rows per wave-load
    const int scol = (lane & 3) * 8;

    const unsigned short* gA0 = A0 + (size_t)(bm*128 + w*16 + srow)*DIM + scol;
    const unsigned short* gB0 = Wt + (size_t)(bn*128 + w*16 + srow)*DIM + scol;

    const int aoff = (wm*32 + ln)*32 + quad*8;          // + mi*512
    const int boff = 4096 + (wn*64 + ln)*32 + quad*8;   // + ni*512

    f32x4 acc[2][4];
    #pragma unroll
    for (int mi = 0; mi < 2; mi++)
        #pragma unroll
        for (int ni = 0; ni < 4; ni++)
            acc[mi][ni] = (f32x4){0.f, 0.f, 0.f, 0.f};

#define STAGE_Q(BUF) do { \
        unsigned short* s_ = smem + (BUF)*8192; \
        gl_lds16(gA0, &s_[(w*16)*32]); \
        gl_lds16(gB0, &s_[4096 + (w*16)*32]); \
        gA0 += 32; gB0 += 32; } while (0)

#define COMP_Q(BUF) do { \
        const unsigned short* s_ = smem + (BUF)*8192; \
        bf16x8 af[2], bfr[4]; \
        _Pragma("unroll") \
        for (int mi = 0; mi < 2; mi++) \
            af[mi] = as_bf16x8(*(const uint4*)(s_ + aoff + mi*512)); \
        _Pragma("unroll") \
        for (int ni = 0; ni < 4; ni++) \
            bfr[ni] = as_bf16x8(*(const uint4*)(s_ + boff + ni*512)); \
        _Pragma("unroll") \
        for (int mi = 0; mi < 2; mi++) \
            _Pragma("unroll") \
            for (int ni = 0; ni < 4; ni++) \
                acc[mi][ni] = __builtin_amdgcn_mfma_f32_16x16x32_bf16(af[mi], bfr[ni], acc[mi][ni], 0, 0, 0); \
    } while (0)

#define QITER(B) do { \
        asm volatile("s_waitcnt vmcnt(2)" ::: "memory"); \
        __builtin_amdgcn_s_barrier(); \
        __builtin_amdgcn_sched_barrier(0); \
        STAGE_Q(((B) + 2) % 3); \
        COMP_Q(B); \
        __builtin_amdgcn_sched_barrier(0); \
    } while (0)

    STAGE_Q(0);
    STAGE_Q(1);
    for (int base = 0; base < 30; base += 3) {
        QITER(0); QITER(1); QITER(2);
    }
    asm volatile("s_waitcnt vmcnt(2)" ::: "memory");
    __builtin_amdgcn_s_barrier();
    __builtin_amdgcn_sched_barrier(0);
    COMP_Q(0);
    __builtin_amdgcn_sched_barrier(0);
    asm volatile("s_waitcnt vmcnt(0)" ::: "memory");
    __builtin_amdgcn_s_barrier();
    __builtin_amdgcn_sched_barrier(0);
    COMP_Q(1);
#undef QITER
#undef COMP_Q
#undef STAGE_Q

    const float* bias = (mode == 0) ? bq : (mode == 1) ? bk : bv;
    unsigned short* dst = (mode == 0) ? Qh : (mode == 1) ? Kh : Vt;
    if (mode < 2) {
        const float sc = (mode == 0) ? 0.125f * 1.4426950408889634f : 1.0f;
        #pragma unroll
        for (int mi = 0; mi < 2; mi++) {
            #pragma unroll
            for (int r = 0; r < 4; r++) {
                int grow = bm*128 + wm*32 + mi*16 + quad*4 + r;
                int b_ = grow >> 11, n = grow & (NN - 1);
                #pragma unroll
                for (int ni = 0; ni < 4; ni++) {
                    int gcol = bn*128 + wn*64 + ni*16 + ln;
                    int hh = gcol >> 6, dd = gcol & 63;
                    float val = (acc[mi][ni][r] + bias[gcol]) * sc;
                    dst[(((size_t)(b_*HEADS + hh))*NN + n)*HD + dd] = f2bf(val);
                }
            }
        }
    } else {
        // V: single-pass transpose through swizzled sT[128 dd][128 nn]
        __syncthreads();
        #pragma unroll
        for (int ni = 0; ni < 4; ni++) {
            int row_s = wn*64 + ni*16 + ln;            // local feature col dd
            float bsv = bias[bn*128 + row_s];
            int sxor = (row_s & 7) << 1;               // 8B-unit XOR swizzle
            #pragma unroll
            for (int mi = 0; mi < 2; mi++) {
                int u = wm*8 + mi*4 + quad;            // 8B unit along nn (0..31)
                ushort4 pk;
                pk.x = f2bf(acc[mi][ni][0] + bsv);
                pk.y = f2bf(acc[mi][ni][1] + bsv);
                pk.z = f2bf(acc[mi][ni][2] + bsv);
                pk.w = f2bf(acc[mi][ni][3] + bsv);
                *(ushort4*)(&smem[row_s*128 + ((u ^ sxor) << 2)]) = pk;
            }
        }
        __syncthreads();
        const int b_ = bm >> 4;
        #pragma unroll
        for (int i = 0; i < 4; i++) {
            int idx = i*512 + t;                        // 0..2047 16B chunks
            int dd = idx >> 4, jc = idx & 15;
            int u = (jc*2) ^ ((dd & 7) << 1);
            int hh = bn*2 + (dd >> 6), d_ = dd & 63;
            *(uint4*)(dst + (((size_t)(b_*HEADS + hh))*HD + d_)*NN
                          + (size_t)(bm & 15)*128 + jc*8)
                = *(const uint4*)(&smem[dd*128 + (u << 2)]);
        }
    }
}

// ---------------------------------------------------------------------------
// Out projection v2: exact clone of the proven 8-wave gemm_qkv structure.
// 128x128 tile, 512 threads, T4 counted-vmcnt(2) 3-buffer pipeline.
// Grid (32, 8) = 256 blocks = 1/CU; XCD swizzle: bn = lin&7 — each XCD owns
// one Wo panel (256 KB, L2-resident) and sweeps all bm. f32 epilogue.
// ---------------------------------------------------------------------------
__global__ __launch_bounds__(512) void gemm_out(
    const unsigned short* __restrict__ attp,
    const unsigned short* __restrict__ Wt_all,
    const float* __restrict__ bo, float* __restrict__ out)
{
    const int lin = blockIdx.x + 32*blockIdx.y;   // 0..255
    const int bn = lin & 7;                       // XCD id == Wo panel
    const int bm = lin >> 3;                      // 0..31
    __shared__ __align__(16) unsigned short smem[3*8192];   // 48 KB
    const int t = threadIdx.x;
    const int w = t >> 6, lane = t & 63, ln = lane & 15, quad = lane >> 4;
    const int wm = w >> 1, wn = w & 1;
    const unsigned short* Wt = Wt_all + (size_t)3 * (DIM*DIM);

    const int srow = lane >> 2;
    const int scol = (lane & 3) * 8;

    const unsigned short* gA0 = attp + (size_t)(bm*128 + w*16 + srow)*DIM + scol;
    const unsigned short* gB0 = Wt + (size_t)(bn*128 + w*16 + srow)*DIM + scol;

    const int aoff = (wm*32 + ln)*32 + quad*8;          // + mi*512
    const int boff = 4096 + (wn*64 + ln)*32 + quad*8;   // + ni*512

    f32x4 acc[2][4];
    #pragma unroll
    for (int mi = 0; mi < 2; mi++)
        #pragma unroll
        for (int ni = 0; ni < 4; ni++)
            acc[mi][ni] = (f32x4){0.f, 0.f, 0.f, 0.f};

#define STAGE_T(BUF) do { \
        unsigned short* s_ = smem + (BUF)*8192; \
        gl_lds16(gA0, &s_[(w*16)*32]); \
        gl_lds16(gB0, &s_[4096 + (w*16)*32]); \
        gA0 += 32; gB0 += 32; } while (0)

#define COMP_T(BUF) do { \
        const unsigned short* s_ = smem + (BUF)*8192; \
        bf16x8 af[2], bfr[4]; \
        _Pragma("unroll") \
        for (int mi = 0; mi < 2; mi++) \
            af[mi] = as_bf16x8(*(const uint4*)(s_ + aoff + mi*512)); \
        _Pragma("unroll") \
        for (int ni = 0; ni < 4; ni++) \
            bfr[ni] = as_bf16x8(*(const uint4*)(s_ + boff + ni*512)); \
        _Pragma("unroll") \
        for (int mi = 0; mi < 2; mi++) \
            _Pragma("unroll") \
            for (int ni = 0; ni < 4; ni++) \
                acc[mi][ni] = __builtin_amdgcn_mfma_f32_16x16x32_bf16(af[mi], bfr[ni], acc[mi][ni], 0, 0, 0); \
    } while (0)

#define TITER(B) do { \
        asm volatile("s_waitcnt vmcnt(2)" ::: "memory"); \
        __builtin_amdgcn_s_barrier(); \
        __builtin_amdgcn_sched_barrier(0); \
        STAGE_T(((B) + 2) % 3); \
        COMP_T(B); \
        __builtin_amdgcn_sched_barrier(0); \
    } while (0)

    STAGE_T(0);
    STAGE_T(1);
    for (int base = 0; base < 30; base += 3) {
        TITER(0); TITER(1); TITER(2);
    }
    asm volatile("s_waitcnt vmcnt(2)" ::: "memory");
    __builtin_amdgcn_s_barrier();
    __builtin_amdgcn_sched_barrier(0);
    COMP_T(0);
    __builtin_amdgcn_sched_barrier(0);
    asm volatile("s_waitcnt vmcnt(0)" ::: "memory");
    __builtin_amdgcn_s_barrier();
    __builtin_amdgcn_sched_barrier(0);
    COMP_T(1);
#undef TITER
#undef COMP_T
#undef STAGE_T

    #pragma unroll
    for (int mi = 0; mi < 2; mi++) {
        #pragma unroll
        for (int r = 0; r < 4; r++) {
            int grow = bm*128 + wm*32 + mi*16 + quad*4 + r;
            #pragma unroll
            for (int ni = 0; ni < 4; ni++) {
                int gcol = bn*128 + wn*64 + ni*16 + ln;
                out[(size_t)grow*DIM + gcol] = acc[mi][ni][r] + bo[gcol];
            }
        }
    }
}

// ---------------------------------------------------------------------------
// Flash attention (unchanged from R6 — best-known; bench-insensitive to
// attn variants across R3-R6, so frozen).
// ---------------------------------------------------------------------------
__global__ __launch_bounds__(256) void attn_kernel(
    const unsigned short* __restrict__ Qh, const unsigned short* __restrict__ Kh,
    const unsigned short* __restrict__ Vt, const unsigned short* __restrict__ As,
    unsigned short* __restrict__ attp)
{
    const int bh = blockIdx.x;      // b*16 + h
    const int qt = blockIdx.y;      // 0..15 (128-row q tiles)
    const int b = bh >> 4, h = bh & 15;
    const int t = threadIdx.x;
    const int w = t >> 6, lane = t & 63, ln = lane & 15, quad = lane >> 4;
    const int sw = ln & 7;          // fragment rows are == ln (mod 8)
    const float EBIAS = 17.312340490667562f;   // 12 * log2(e)

    __shared__ __align__(16) unsigned short sK[2][64*64];    // 16 KB [n][k]
    __shared__ __align__(16) unsigned short sVt[2][64*64];   // 16 KB [d][n]

    const unsigned short* Qb  = Qh + (size_t)bh * NN * HD + (size_t)qt * 128 * HD;
    const unsigned short* Kb  = Kh + (size_t)bh * NN * HD;
    const unsigned short* Vtb = Vt + (size_t)bh * HD * NN;   // [d][n]

    const int rl = lane >> 3, cb = lane & 7;

    // ---- Q fragments straight from global: 2 m-tiles x 2 k-frags ----
    bf16x8 aq[2][2];
    #pragma unroll
    for (int m = 0; m < 2; m++)
        #pragma unroll
        for (int k = 0; k < 2; k++)
            aq[m][k] = as_bf16x8(*(const uint4*)(
                Qb + (size_t)(m*64 + w*16 + ln)*HD + (k*4 + quad)*8));

    // stage tile jt into buffer bb (4 gl_lds16 per wave; XOR-swizzled cols)
#define STAGE_KV(JT, BBUF) do { \
        _Pragma("unroll") \
        for (int j = 0; j < 2; j++) { \
            int row = w*16 + j*8 + rl; \
            gl_lds16(Kb + (size_t)((JT)*64 + row)*HD + ((cb ^ (row & 7))*8), \
                     &sK[BBUF][(w*16 + j*8)*64]); \
            gl_lds16(Vtb + (size_t)row*NN + (JT)*64 + ((cb ^ (row & 7))*8), \
                     &sVt[BBUF][(w*16 + j*8)*64]); \
        } } while (0)

    const s16x4 ones = { (short)0x3F80, (short)0x3F80, (short)0x3F80, (short)0x3F80 };
    const f32x4 CB = (f32x4){-EBIAS, -EBIAS, -EBIAS, -EBIAS};  // persistent C-init
    f32x4 accO[2][4], accL[2];
    #pragma unroll
    for (int m = 0; m < 2; m++) {
        accL[m] = (f32x4){0.f, 0.f, 0.f, 0.f};
        #pragma unroll
        for (int di = 0; di < 4; di++) accO[m][di] = (f32x4){0.f, 0.f, 0.f, 0.f};
    }

    STAGE_KV(0, 0);                       // prologue: tile 0 -> buf 0
    asm volatile("s_waitcnt vmcnt(0)" ::: "memory");
    __builtin_amdgcn_s_barrier();
    __builtin_amdgcn_sched_barrier(0);

    #pragma unroll 2
    for (int jt = 0; jt < 32; jt++) {
        const int cur = jt & 1;
        if (jt < 31) STAGE_KV(jt + 1, cur ^ 1);   // issue next tile first

        const unsigned short* sKc = sK[cur];
        const unsigned short* sVc = sVt[cur];

        // S^T: accS[m][ni] — lane: q-col = m*64+w*16+ln, kv = ni*16+quad*4+r.
        // First MFMA of each chain takes CB (-EBIAS) as C: no init movs.
        f32x4 accS[2][4];
        __builtin_amdgcn_s_setprio(1);
        #pragma unroll
        for (int ni = 0; ni < 4; ni++) {
            bf16x8 b0 = as_bf16x8(*(const uint4*)(
                &sKc[(ni*16 + ln)*64 + (((0 + quad) ^ sw)*8)]));
            accS[0][ni] = __builtin_amdgcn_mfma_f32_16x16x32_bf16(b0, aq[0][0], CB, 0, 0, 0);
            accS[1][ni] = __builtin_amdgcn_mfma_f32_16x16x32_bf16(b0, aq[1][0], CB, 0, 0, 0);
            bf16x8 b1 = as_bf16x8(*(const uint4*)(
                &sKc[(ni*16 + ln)*64 + (((4 + quad) ^ sw)*8)]));
            accS[0][ni] = __builtin_amdgcn_mfma_f32_16x16x32_bf16(b1, aq[0][1], accS[0][ni], 0, 0, 0);
            accS[1][ni] = __builtin_amdgcn_mfma_f32_16x16x32_bf16(b1, aq[1][1], accS[1][ni], 0, 0, 0);
        }
        __builtin_amdgcn_s_setprio(0);

        // p = exp2(s-EBIAS); pack via v_perm (trunc); L via ones-MFMA
        s16x4 pf[2][4];
        #pragma unroll
        for (int m = 0; m < 2; m++)
            #pragma unroll
            for (int ni = 0; ni < 4; ni++) {
                unsigned int e0 = __builtin_bit_cast(unsigned int, __builtin_amdgcn_exp2f(accS[m][ni][0]));
                unsigned int e1 = __builtin_bit_cast(unsigned int, __builtin_amdgcn_exp2f(accS[m][ni][1]));
                unsigned int e2 = __builtin_bit_cast(unsigned int, __builtin_amdgcn_exp2f(accS[m][ni][2]));
                unsigned int e3 = __builtin_bit_cast(unsigned int, __builtin_amdgcn_exp2f(accS[m][ni][3]));
                unsigned int lo = __builtin_amdgcn_perm(e1, e0, 0x07060302u);
                unsigned int hi = __builtin_amdgcn_perm(e3, e2, 0x07060302u);
                pf[m][ni] = __builtin_bit_cast(s16x4, uint2{lo, hi});
                accL[m] = mfma16x16x16bf16(pf[m][ni], ones, accL[m]);
            }

        // O += P V: one V-frag read feeds both m-tiles.
        __builtin_amdgcn_s_setprio(1);
        #pragma unroll
        for (int ni = 0; ni < 4; ni++) {
            int blkv = 2*ni + (quad >> 1);
            int off = (quad & 1) * 4;
            #pragma unroll
            for (int di = 0; di < 4; di++) {
                s16x4 bv = __builtin_bit_cast(s16x4,
                    *(const uint2*)(&sVc[(di*16 + ln)*64 + ((blkv ^ sw)*8) + off]));
                accO[0][di] = mfma16x16x16bf16(pf[0][ni], bv, accO[0][di]);
                accO[1][di] = mfma16x16x16bf16(pf[1][ni], bv, accO[1][di]);
            }
        }
        __builtin_amdgcn_s_setprio(0);

        __builtin_amdgcn_sched_barrier(0);
        if (jt < 31) {
            asm volatile("s_waitcnt vmcnt(0)" ::: "memory");  // next tile landed
            __builtin_amdgcn_s_barrier();                     // cur fully read
            __builtin_amdgcn_sched_barrier(0);
        }
    }
#undef STAGE_KV

    // accL[m][r] = row-sum L for q-row m*64 + w*16 + quad*4 + r
    #pragma unroll
    for (int m = 0; m < 2; m++) {
        #pragma unroll
        for (int r = 0; r < 4; r++) {
            float inv = 1.f / accL[m][r];
            int n = qt*128 + m*64 + w*16 + quad*4 + r;
            #pragma unroll
            for (int di = 0; di < 4; di++) {
                int c = h*64 + di*16 + ln;
                size_t gi = ((size_t)b*NN + n)*DIM + c;
                float o = accO[m][di][r]*inv + bf2f(As[gi]);
                attp[gi] = f2bf(o);
            }
        }
    }
}

// ---------------------------------------------------------------------------
extern "C" void kernel_launch(void* const* d_in, const int* in_sizes, int n_in,
                              void* d_out, int out_size, void* d_ws, size_t ws_size,
                              hipStream_t stream) {
    const float* y2f = (const float*)d_in[0];
    const float* y2b = (const float*)d_in[1];
    const float* Wq  = (const float*)d_in[2];
    const float* bq  = (const float*)d_in[3];
    const float* Wk  = (const float*)d_in[4];
    const float* bk  = (const float*)d_in[5];
    const float* Wv  = (const float*)d_in[6];
    const float* bv  = (const float*)d_in[7];
    const float* Wo  = (const float*)d_in[8];
    const float* bo  = (const float*)d_in[9];
    float* out = (float*)d_out;

    const size_t NACT = (size_t)M_ROWS * DIM;  // 4,194,304 (8 MB as ushort)
    unsigned short* ws   = (unsigned short*)d_ws;
    unsigned short* Af   = ws;
    unsigned short* Ab   = ws + NACT;
    unsigned short* As   = ws + 2*NACT;
    unsigned short* Qh   = ws + 3*NACT;
    unsigned short* Kh   = ws + 4*NACT;
    unsigned short* Vt   = ws + 5*NACT;   // V written pre-transposed [b,h,d,n]
    unsigned short* Wt   = ws + 6*NACT;   // 4 x 1024 x 1024 bf16
    unsigned short* attp = Ab;            // overlay (Ab dead after QKV gemm)

    prep_all<<<dim3(3072), 256, 0, stream>>>(y2f, y2b, Wq, Wk, Wv, Wo,
                                             Af, Ab, As, Wt);
    gemm_qkv<<<dim3(32, 24), 512, 0, stream>>>(
        Af, Ab, As, Wt, bq, bk, bv, Qh, Kh, Vt);
    attn_kernel<<<dim3(32, 16), 256, 0, stream>>>(Qh, Kh, Vt, As, attp);
    gemm_out<<<dim3(32, 8), 512, 0, stream>>>(attp, Wt, bo, out);
}

// Round 8
// 207.355 us; speedup vs baseline: 1.1709x; 1.0034x over previous
//
#include <hip/hip_runtime.h>

#define DIM 1024
#define HEADS 16
#define BB 2
#define NN 2048
#define HD 64
#define M_ROWS (BB*NN)  // 4096

typedef __bf16 bf16x8 __attribute__((ext_vector_type(8)));
typedef float f32x4 __attribute__((ext_vector_type(4)));
typedef short s16x4 __attribute__((ext_vector_type(4)));

__device__ inline unsigned short f2bf(float f) {
    unsigned int u = __builtin_bit_cast(unsigned int, f);
    u += 0x7fffu + ((u >> 16) & 1u);
    return (unsigned short)(u >> 16);
}
__device__ inline float bf2f(unsigned short u) {
    return __builtin_bit_cast(float, (unsigned int)u << 16);
}
__device__ inline bf16x8 as_bf16x8(uint4 v) {
    return __builtin_bit_cast(bf16x8, v);
}
// async global->LDS, 16B per lane: LDS dest = base + lane*16 (wave-uniform
// base); global source address is per-lane (gather allowed).
__device__ __forceinline__ void gl_lds16(const unsigned short* g, unsigned short* l) {
    __builtin_amdgcn_global_load_lds(
        (const __attribute__((address_space(1))) unsigned int*)g,
        (__attribute__((address_space(3))) unsigned int*)l, 16, 0, 0);
}

// 16x16x16 bf16 MFMA (K=16): A/B = 4 bf16 (2 VGPRs), C/D = 4 f32.
__device__ __forceinline__ f32x4 mfma16x16x16bf16(s16x4 a, s16x4 b, f32x4 c) {
#if __has_builtin(__builtin_amdgcn_mfma_f32_16x16x16bf16_1k)
    return __builtin_amdgcn_mfma_f32_16x16x16bf16_1k(a, b, c, 0, 0, 0);
#else
    asm volatile("v_mfma_f32_16x16x16_bf16 %0, %1, %2, %0"
                 : "+v"(c) : "v"(a), "v"(b));
    return c;
#endif
}

// ---------------------------------------------------------------------------
// Merged prep (unchanged from R7): blocks 0..1023 = weight transpose in
// 64x64 f32 tiles; blocks 1024..3071 = activation bf16 prep.
// ---------------------------------------------------------------------------
__global__ __launch_bounds__(256) void prep_all(
    const float* __restrict__ y2f, const float* __restrict__ y2b,
    const float* __restrict__ Wq, const float* __restrict__ Wk,
    const float* __restrict__ Wv, const float* __restrict__ Wo,
    unsigned short* __restrict__ Af, unsigned short* __restrict__ Ab,
    unsigned short* __restrict__ As, unsigned short* __restrict__ Wt_all)
{
    __shared__ float tile[64][68];    // 17.4 KB; rows 272B (16B-aligned)
    const int blk = blockIdx.x;
    if (blk < 1024) {
        const int m = blk >> 8, r = blk & 255, bk = r & 15, bn = r >> 4;
        const float* W = (m == 0) ? Wq : (m == 1) ? Wk : (m == 2) ? Wv : Wo;
        const int tx = threadIdx.x & 15, ty = threadIdx.x >> 4;  // 16 x 16
        #pragma unroll
        for (int i = 0; i < 64; i += 16)
            *(float4*)(&tile[ty + i][tx*4]) =
                *(const float4*)(&W[(size_t)(bk*64 + ty + i)*DIM + bn*64 + tx*4]);
        __syncthreads();
        unsigned short* dst = Wt_all + (size_t)m * DIM * DIM;
        #pragma unroll
        for (int i = 0; i < 2; i++) {
            int chunk = i*256 + threadIdx.x;        // 0..511
            int n = chunk >> 3, kc = (chunk & 7)*8; // Wt row = n, col kc..kc+7
            unsigned int p0 = (unsigned)f2bf(tile[kc+0][n]) | ((unsigned)f2bf(tile[kc+1][n]) << 16);
            unsigned int p1 = (unsigned)f2bf(tile[kc+2][n]) | ((unsigned)f2bf(tile[kc+3][n]) << 16);
            unsigned int p2 = (unsigned)f2bf(tile[kc+4][n]) | ((unsigned)f2bf(tile[kc+5][n]) << 16);
            unsigned int p3 = (unsigned)f2bf(tile[kc+6][n]) | ((unsigned)f2bf(tile[kc+7][n]) << 16);
            *(uint4*)(&dst[(size_t)(bn*64 + n)*DIM + bk*64 + kc]) = uint4{p0, p1, p2, p3};
        }
    } else {
        const size_t idx = ((size_t)(blk - 1024)*256 + threadIdx.x) * 8;
        #pragma unroll
        for (int half = 0; half < 2; half++) {
            float4 f = *(const float4*)(y2f + idx + half*4);
            float4 b = *(const float4*)(y2b + idx + half*4);
            ushort4 of, ob, os;
            of.x = f2bf(f.x); of.y = f2bf(f.y); of.z = f2bf(f.z); of.w = f2bf(f.w);
            ob.x = f2bf(b.x); ob.y = f2bf(b.y); ob.z = f2bf(b.z); ob.w = f2bf(b.w);
            os.x = f2bf(f.x + b.x); os.y = f2bf(f.y + b.y);
            os.z = f2bf(f.z + b.z); os.w = f2bf(f.w + b.w);
            *(ushort4*)(Af + idx + half*4) = of;
            *(ushort4*)(Ab + idx + half*4) = ob;
            *(ushort4*)(As + idx + half*4) = os;
        }
    }
}

// ---------------------------------------------------------------------------
// Uniform QKV GEMM v3 = R6 structure + T2 LDS swizzle at zero VALU cost.
// Bank math: 64B LDS rows put fragment ds_read_b128 at bank (ln*16+quad*4)%32
// -> 8-way conflict (R1 PMC: 4.1M cycles, ~5.3/read). Fix (rule #21): LDS
// dest stays linear (gl_lds16 requirement); GLOBAL source col pre-swizzled
// scol ^= ((lane>>3)&3)*8 (stays in same 64B segment -> coalescing intact);
// fragment reads XOR col8 with (ln>>1)&3 (invariant over mi/wm: their row
// contribution == 0 mod 4) -> per-phase banks spread 2-way = free (m136).
// ---------------------------------------------------------------------------
__global__ __launch_bounds__(512) void gemm_qkv(
    const unsigned short* __restrict__ Af, const unsigned short* __restrict__ Ab,
    const unsigned short* __restrict__ As,
    const unsigned short* __restrict__ Wt_all,
    const float* __restrict__ bq, const float* __restrict__ bk,
    const float* __restrict__ bv,
    unsigned short* __restrict__ Qh, unsigned short* __restrict__ Kh,
    unsigned short* __restrict__ Vt)
{
    const int lin = blockIdx.x + 32*blockIdx.y;
    const int swz = (lin & 7)*96 + (lin >> 3);
    const int bm = swz & 31;
    const int rest = swz >> 5;              // 0..23
    const int mode = rest >> 3;             // 0=Q, 1=K, 2=V
    const int bn = rest & 7;
    __shared__ __align__(16) unsigned short smem[3*8192];   // 48 KB
    const int t = threadIdx.x;
    const int w = t >> 6, lane = t & 63, ln = lane & 15, quad = lane >> 4;
    const int wm = w >> 1, wn = w & 1;      // 4 x 2 wave grid (32r x 64c each)
    const unsigned short* Wt = Wt_all + (size_t)mode * (DIM*DIM);
    const unsigned short* A0 = (mode == 0) ? Af : (mode == 1) ? Ab : As;

    const int srow = lane >> 2;             // 16 rows per wave-load
    // source col pre-swizzle: LDS pos (row, c) holds element c ^ ((row>>1)&3)
    const int scol = (((lane & 3) ^ ((lane >> 3) & 3)) * 8);

    const unsigned short* gA0 = A0 + (size_t)(bm*128 + w*16 + srow)*DIM + scol;
    const unsigned short* gB0 = Wt + (size_t)(bn*128 + w*16 + srow)*DIM + scol;

    // fragment read: element quad lives at col8 = quad ^ ((ln>>1)&3)
    const int cswz = (quad ^ ((ln >> 1) & 3)) * 8;
    const int aoff = (wm*32 + ln)*32 + cswz;            // + mi*512
    const int boff = 4096 + (wn*64 + ln)*32 + cswz;     // + ni*512

    f32x4 acc[2][4];
    #pragma unroll
    for (int mi = 0; mi < 2; mi++)
        #pragma unroll
        for (int ni = 0; ni < 4; ni++)
            acc[mi][ni] = (f32x4){0.f, 0.f, 0.f, 0.f};

#define STAGE_Q(BUF) do { \
        unsigned short* s_ = smem + (BUF)*8192; \
        gl_lds16(gA0, &s_[(w*16)*32]); \
        gl_lds16(gB0, &s_[4096 + (w*16)*32]); \
        gA0 += 32; gB0 += 32; } while (0)

#define COMP_Q(BUF) do { \
        const unsigned short* s_ = smem + (BUF)*8192; \
        bf16x8 af[2], bfr[4]; \
        _Pragma("unroll") \
        for (int mi = 0; mi < 2; mi++) \
            af[mi] = as_bf16x8(*(const uint4*)(s_ + aoff + mi*512)); \
        _Pragma("unroll") \
        for (int ni = 0; ni < 4; ni++) \
            bfr[ni] = as_bf16x8(*(const uint4*)(s_ + boff + ni*512)); \
        _Pragma("unroll") \
        for (int mi = 0; mi < 2; mi++) \
            _Pragma("unroll") \
            for (int ni = 0; ni < 4; ni++) \
                acc[mi][ni] = __builtin_amdgcn_mfma_f32_16x16x32_bf16(af[mi], bfr[ni], acc[mi][ni], 0, 0, 0); \
    } while (0)

#define QITER(B) do { \
        asm volatile("s_waitcnt vmcnt(2)" ::: "memory"); \
        __builtin_amdgcn_s_barrier(); \
        __builtin_amdgcn_sched_barrier(0); \
        STAGE_Q(((B) + 2) % 3); \
        COMP_Q(B); \
        __builtin_amdgcn_sched_barrier(0); \
    } while (0)

    STAGE_Q(0);
    STAGE_Q(1);
    for (int base = 0; base < 30; base += 3) {
        QITER(0); QITER(1); QITER(2);
    }
    asm volatile("s_waitcnt vmcnt(2)" ::: "memory");
    __builtin_amdgcn_s_barrier();
    __builtin_amdgcn_sched_barrier(0);
    COMP_Q(0);
    __builtin_amdgcn_sched_barrier(0);
    asm volatile("s_waitcnt vmcnt(0)" ::: "memory");
    __builtin_amdgcn_s_barrier();
    __builtin_amdgcn_sched_barrier(0);
    COMP_Q(1);
#undef QITER
#undef COMP_Q
#undef STAGE_Q

    const float* bias = (mode == 0) ? bq : (mode == 1) ? bk : bv;
    unsigned short* dst = (mode == 0) ? Qh : (mode == 1) ? Kh : Vt;
    if (mode < 2) {
        const float sc = (mode == 0) ? 0.125f * 1.4426950408889634f : 1.0f;
        #pragma unroll
        for (int mi = 0; mi < 2; mi++) {
            #pragma unroll
            for (int r = 0; r < 4; r++) {
                int grow = bm*128 + wm*32 + mi*16 + quad*4 + r;
                int b_ = grow >> 11, n = grow & (NN - 1);
                #pragma unroll
                for (int ni = 0; ni < 4; ni++) {
                    int gcol = bn*128 + wn*64 + ni*16 + ln;
                    int hh = gcol >> 6, dd = gcol & 63;
                    float val = (acc[mi][ni][r] + bias[gcol]) * sc;
                    dst[(((size_t)(b_*HEADS + hh))*NN + n)*HD + dd] = f2bf(val);
                }
            }
        }
    } else {
        // V: single-pass transpose through swizzled sT[128 dd][128 nn]
        __syncthreads();
        #pragma unroll
        for (int ni = 0; ni < 4; ni++) {
            int row_s = wn*64 + ni*16 + ln;            // local feature col dd
            float bsv = bias[bn*128 + row_s];
            int sxor = (row_s & 7) << 1;               // 8B-unit XOR swizzle
            #pragma unroll
            for (int mi = 0; mi < 2; mi++) {
                int u = wm*8 + mi*4 + quad;            // 8B unit along nn (0..31)
                ushort4 pk;
                pk.x = f2bf(acc[mi][ni][0] + bsv);
                pk.y = f2bf(acc[mi][ni][1] + bsv);
                pk.z = f2bf(acc[mi][ni][2] + bsv);
                pk.w = f2bf(acc[mi][ni][3] + bsv);
                *(ushort4*)(&smem[row_s*128 + ((u ^ sxor) << 2)]) = pk;
            }
        }
        __syncthreads();
        const int b_ = bm >> 4;
        #pragma unroll
        for (int i = 0; i < 4; i++) {
            int idx = i*512 + t;                        // 0..2047 16B chunks
            int dd = idx >> 4, jc = idx & 15;
            int u = (jc*2) ^ ((dd & 7) << 1);
            int hh = bn*2 + (dd >> 6), d_ = dd & 63;
            *(uint4*)(dst + (((size_t)(b_*HEADS + hh))*HD + d_)*NN
                          + (size_t)(bm & 15)*128 + jc*8)
                = *(const uint4*)(&smem[dd*128 + (u << 2)]);
        }
    }
}

// ---------------------------------------------------------------------------
// Out projection v3 = R7 structure + same zero-cost T2 LDS swizzle.
// ---------------------------------------------------------------------------
__global__ __launch_bounds__(512) void gemm_out(
    const unsigned short* __restrict__ attp,
    const unsigned short* __restrict__ Wt_all,
    const float* __restrict__ bo, float* __restrict__ out)
{
    const int lin = blockIdx.x + 32*blockIdx.y;   // 0..255
    const int bn = lin & 7;                       // XCD id == Wo panel
    const int bm = lin >> 3;                      // 0..31
    __shared__ __align__(16) unsigned short smem[3*8192];   // 48 KB
    const int t = threadIdx.x;
    const int w = t >> 6, lane = t & 63, ln = lane & 15, quad = lane >> 4;
    const int wm = w >> 1, wn = w & 1;
    const unsigned short* Wt = Wt_all + (size_t)3 * (DIM*DIM);

    const int srow = lane >> 2;
    const int scol = (((lane & 3) ^ ((lane >> 3) & 3)) * 8);

    const unsigned short* gA0 = attp + (size_t)(bm*128 + w*16 + srow)*DIM + scol;
    const unsigned short* gB0 = Wt + (size_t)(bn*128 + w*16 + srow)*DIM + scol;

    const int cswz = (quad ^ ((ln >> 1) & 3)) * 8;
    const int aoff = (wm*32 + ln)*32 + cswz;            // + mi*512
    const int boff = 4096 + (wn*64 + ln)*32 + cswz;     // + ni*512

    f32x4 acc[2][4];
    #pragma unroll
    for (int mi = 0; mi < 2; mi++)
        #pragma unroll
        for (int ni = 0; ni < 4; ni++)
            acc[mi][ni] = (f32x4){0.f, 0.f, 0.f, 0.f};

#define STAGE_T(BUF) do { \
        unsigned short* s_ = smem + (BUF)*8192; \
        gl_lds16(gA0, &s_[(w*16)*32]); \
        gl_lds16(gB0, &s_[4096 + (w*16)*32]); \
        gA0 += 32; gB0 += 32; } while (0)

#define COMP_T(BUF) do { \
        const unsigned short* s_ = smem + (BUF)*8192; \
        bf16x8 af[2], bfr[4]; \
        _Pragma("unroll") \
        for (int mi = 0; mi < 2; mi++) \
            af[mi] = as_bf16x8(*(const uint4*)(s_ + aoff + mi*512)); \
        _Pragma("unroll") \
        for (int ni = 0; ni < 4; ni++) \
            bfr[ni] = as_bf16x8(*(const uint4*)(s_ + boff + ni*512)); \
        _Pragma("unroll") \
        for (int mi = 0; mi < 2; mi++) \
            _Pragma("unroll") \
            for (int ni = 0; ni < 4; ni++) \
                acc[mi][ni] = __builtin_amdgcn_mfma_f32_16x16x32_bf16(af[mi], bfr[ni], acc[mi][ni], 0, 0, 0); \
    } while (0)

#define TITER(B) do { \
        asm volatile("s_waitcnt vmcnt(2)" ::: "memory"); \
        __builtin_amdgcn_s_barrier(); \
        __builtin_amdgcn_sched_barrier(0); \
        STAGE_T(((B) + 2) % 3); \
        COMP_T(B); \
        __builtin_amdgcn_sched_barrier(0); \
    } while (0)

    STAGE_T(0);
    STAGE_T(1);
    for (int base = 0; base < 30; base += 3) {
        TITER(0); TITER(1); TITER(2);
    }
    asm volatile("s_waitcnt vmcnt(2)" ::: "memory");
    __builtin_amdgcn_s_barrier();
    __builtin_amdgcn_sched_barrier(0);
    COMP_T(0);
    __builtin_amdgcn_sched_barrier(0);
    asm volatile("s_waitcnt vmcnt(0)" ::: "memory");
    __builtin_amdgcn_s_barrier();
    __builtin_amdgcn_sched_barrier(0);
    COMP_T(1);
#undef TITER
#undef COMP_T
#undef STAGE_T

    #pragma unroll
    for (int mi = 0; mi < 2; mi++) {
        #pragma unroll
        for (int r = 0; r < 4; r++) {
            int grow = bm*128 + wm*32 + mi*16 + quad*4 + r;
            #pragma unroll
            for (int ni = 0; ni < 4; ni++) {
                int gcol = bn*128 + wn*64 + ni*16 + ln;
                out[(size_t)grow*DIM + gcol] = acc[mi][ni][r] + bo[gcol];
            }
        }
    }
}

// ---------------------------------------------------------------------------
// Flash attention (unchanged from R6 — best-known; bench-insensitive to
// attn variants across R3-R6, so frozen).
// ---------------------------------------------------------------------------
__global__ __launch_bounds__(256) void attn_kernel(
    const unsigned short* __restrict__ Qh, const unsigned short* __restrict__ Kh,
    const unsigned short* __restrict__ Vt, const unsigned short* __restrict__ As,
    unsigned short* __restrict__ attp)
{
    const int bh = blockIdx.x;      // b*16 + h
    const int qt = blockIdx.y;      // 0..15 (128-row q tiles)
    const int b = bh >> 4, h = bh & 15;
    const int t = threadIdx.x;
    const int w = t >> 6, lane = t & 63, ln = lane & 15, quad = lane >> 4;
    const int sw = ln & 7;          // fragment rows are == ln (mod 8)
    const float EBIAS = 17.312340490667562f;   // 12 * log2(e)

    __shared__ __align__(16) unsigned short sK[2][64*64];    // 16 KB [n][k]
    __shared__ __align__(16) unsigned short sVt[2][64*64];   // 16 KB [d][n]

    const unsigned short* Qb  = Qh + (size_t)bh * NN * HD + (size_t)qt * 128 * HD;
    const unsigned short* Kb  = Kh + (size_t)bh * NN * HD;
    const unsigned short* Vtb = Vt + (size_t)bh * HD * NN;   // [d][n]

    const int rl = lane >> 3, cb = lane & 7;

    // ---- Q fragments straight from global: 2 m-tiles x 2 k-frags ----
    bf16x8 aq[2][2];
    #pragma unroll
    for (int m = 0; m < 2; m++)
        #pragma unroll
        for (int k = 0; k < 2; k++)
            aq[m][k] = as_bf16x8(*(const uint4*)(
                Qb + (size_t)(m*64 + w*16 + ln)*HD + (k*4 + quad)*8));

    // stage tile jt into buffer bb (4 gl_lds16 per wave; XOR-swizzled cols)
#define STAGE_KV(JT, BBUF) do { \
        _Pragma("unroll") \
        for (int j = 0; j < 2; j++) { \
            int row = w*16 + j*8 + rl; \
            gl_lds16(Kb + (size_t)((JT)*64 + row)*HD + ((cb ^ (row & 7))*8), \
                     &sK[BBUF][(w*16 + j*8)*64]); \
            gl_lds16(Vtb + (size_t)row*NN + (JT)*64 + ((cb ^ (row & 7))*8), \
                     &sVt[BBUF][(w*16 + j*8)*64]); \
        } } while (0)

    const s16x4 ones = { (short)0x3F80, (short)0x3F80, (short)0x3F80, (short)0x3F80 };
    const f32x4 CB = (f32x4){-EBIAS, -EBIAS, -EBIAS, -EBIAS};  // persistent C-init
    f32x4 accO[2][4], accL[2];
    #pragma unroll
    for (int m = 0; m < 2; m++) {
        accL[m] = (f32x4){0.f, 0.f, 0.f, 0.f};
        #pragma unroll
        for (int di = 0; di < 4; di++) accO[m][di] = (f32x4){0.f, 0.f, 0.f, 0.f};
    }

    STAGE_KV(0, 0);                       // prologue: tile 0 -> buf 0
    asm volatile("s_waitcnt vmcnt(0)" ::: "memory");
    __builtin_amdgcn_s_barrier();
    __builtin_amdgcn_sched_barrier(0);

    #pragma unroll 2
    for (int jt = 0; jt < 32; jt++) {
        const int cur = jt & 1;
        if (jt < 31) STAGE_KV(jt + 1, cur ^ 1);   // issue next tile first

        const unsigned short* sKc = sK[cur];
        const unsigned short* sVc = sVt[cur];

        // S^T: accS[m][ni] — lane: q-col = m*64+w*16+ln, kv = ni*16+quad*4+r.
        // First MFMA of each chain takes CB (-EBIAS) as C: no init movs.
        f32x4 accS[2][4];
        __builtin_amdgcn_s_setprio(1);
        #pragma unroll
        for (int ni = 0; ni < 4; ni++) {
            bf16x8 b0 = as_bf16x8(*(const uint4*)(
                &sKc[(ni*16 + ln)*64 + (((0 + quad) ^ sw)*8)]));
            accS[0][ni] = __builtin_amdgcn_mfma_f32_16x16x32_bf16(b0, aq[0][0], CB, 0, 0, 0);
            accS[1][ni] = __builtin_amdgcn_mfma_f32_16x16x32_bf16(b0, aq[1][0], CB, 0, 0, 0);
            bf16x8 b1 = as_bf16x8(*(const uint4*)(
                &sKc[(ni*16 + ln)*64 + (((4 + quad) ^ sw)*8)]));
            accS[0][ni] = __builtin_amdgcn_mfma_f32_16x16x32_bf16(b1, aq[0][1], accS[0][ni], 0, 0, 0);
            accS[1][ni] = __builtin_amdgcn_mfma_f32_16x16x32_bf16(b1, aq[1][1], accS[1][ni], 0, 0, 0);
        }
        __builtin_amdgcn_s_setprio(0);

        // p = exp2(s-EBIAS); pack via v_perm (trunc); L via ones-MFMA
        s16x4 pf[2][4];
        #pragma unroll
        for (int m = 0; m < 2; m++)
            #pragma unroll
            for (int ni = 0; ni < 4; ni++) {
                unsigned int e0 = __builtin_bit_cast(unsigned int, __builtin_amdgcn_exp2f(accS[m][ni][0]));
                unsigned int e1 = __builtin_bit_cast(unsigned int, __builtin_amdgcn_exp2f(accS[m][ni][1]));
                unsigned int e2 = __builtin_bit_cast(unsigned int, __builtin_amdgcn_exp2f(accS[m][ni][2]));
                unsigned int e3 = __builtin_bit_cast(unsigned int, __builtin_amdgcn_exp2f(accS[m][ni][3]));
                unsigned int lo = __builtin_amdgcn_perm(e1, e0, 0x07060302u);
                unsigned int hi = __builtin_amdgcn_perm(e3, e2, 0x07060302u);
                pf[m][ni] = __builtin_bit_cast(s16x4, uint2{lo, hi});
                accL[m] = mfma16x16x16bf16(pf[m][ni], ones, accL[m]);
            }

        // O += P V: one V-frag read feeds both m-tiles.
        __builtin_amdgcn_s_setprio(1);
        #pragma unroll
        for (int ni = 0; ni < 4; ni++) {
            int blkv = 2*ni + (quad >> 1);
            int off = (quad & 1) * 4;
            #pragma unroll
            for (int di = 0; di < 4; di++) {
                s16x4 bv = __builtin_bit_cast(s16x4,
                    *(const uint2*)(&sVc[(di*16 + ln)*64 + ((blkv ^ sw)*8) + off]));
                accO[0][di] = mfma16x16x16bf16(pf[0][ni], bv, accO[0][di]);
                accO[1][di] = mfma16x16x16bf16(pf[1][ni], bv, accO[1][di]);
            }
        }
        __builtin_amdgcn_s_setprio(0);

        __builtin_amdgcn_sched_barrier(0);
        if (jt < 31) {
            asm volatile("s_waitcnt vmcnt(0)" ::: "memory");  // next tile landed
            __builtin_amdgcn_s_barrier();                     // cur fully read
            __builtin_amdgcn_sched_barrier(0);
        }
    }
#undef STAGE_KV

    // accL[m][r] = row-sum L for q-row m*64 + w*16 + quad*4 + r
    #pragma unroll
    for (int m = 0; m < 2; m++) {
        #pragma unroll
        for (int r = 0; r < 4; r++) {
            float inv = 1.f / accL[m][r];
            int n = qt*128 + m*64 + w*16 + quad*4 + r;
            #pragma unroll
            for (int di = 0; di < 4; di++) {
                int c = h*64 + di*16 + ln;
                size_t gi = ((size_t)b*NN + n)*DIM + c;
                float o = accO[m][di][r]*inv + bf2f(As[gi]);
                attp[gi] = f2bf(o);
            }
        }
    }
}

// ---------------------------------------------------------------------------
extern "C" void kernel_launch(void* const* d_in, const int* in_sizes, int n_in,
                              void* d_out, int out_size, void* d_ws, size_t ws_size,
                              hipStream_t stream) {
    const float* y2f = (const float*)d_in[0];
    const float* y2b = (const float*)d_in[1];
    const float* Wq  = (const float*)d_in[2];
    const float* bq  = (const float*)d_in[3];
    const float* Wk  = (const float*)d_in[4];
    const float* bk  = (const float*)d_in[5];
    const float* Wv  = (const float*)d_in[6];
    const float* bv  = (const float*)d_in[7];
    const float* Wo  = (const float*)d_in[8];
    const float* bo  = (const float*)d_in[9];
    float* out = (float*)d_out;

    const size_t NACT = (size_t)M_ROWS * DIM;  // 4,194,304 (8 MB as ushort)
    unsigned short* ws   = (unsigned short*)d_ws;
    unsigned short* Af   = ws;
    unsigned short* Ab   = ws + NACT;
    unsigned short* As   = ws + 2*NACT;
    unsigned short* Qh   = ws + 3*NACT;
    unsigned short* Kh   = ws + 4*NACT;
    unsigned short* Vt   = ws + 5*NACT;   // V written pre-transposed [b,h,d,n]
    unsigned short* Wt   = ws + 6*NACT;   // 4 x 1024 x 1024 bf16
    unsigned short* attp = Ab;            // overlay (Ab dead after QKV gemm)

    prep_all<<<dim3(3072), 256, 0, stream>>>(y2f, y2b, Wq, Wk, Wv, Wo,
                                             Af, Ab, As, Wt);
    gemm_qkv<<<dim3(32, 24), 512, 0, stream>>>(
        Af, Ab, As, Wt, bq, bk, bv, Qh, Kh, Vt);
    attn_kernel<<<dim3(32, 16), 256, 0, stream>>>(Qh, Kh, Vt, As, attp);
    gemm_out<<<dim3(32, 8), 512, 0, stream>>>(attp, Wt, bo, out);
}

// Round 9
// 205.259 us; speedup vs baseline: 1.1829x; 1.0102x over previous
//
#include <hip/hip_runtime.h>

#define DIM 1024
#define HEADS 16
#define BB 2
#define NN 2048
#define HD 64
#define M_ROWS (BB*NN)  // 4096

typedef __bf16 bf16x8 __attribute__((ext_vector_type(8)));
typedef float f32x4 __attribute__((ext_vector_type(4)));
typedef short s16x4 __attribute__((ext_vector_type(4)));

__device__ inline unsigned short f2bf(float f) {
    unsigned int u = __builtin_bit_cast(unsigned int, f);
    u += 0x7fffu + ((u >> 16) & 1u);
    return (unsigned short)(u >> 16);
}
__device__ inline float bf2f(unsigned short u) {
    return __builtin_bit_cast(float, (unsigned int)u << 16);
}
__device__ inline bf16x8 as_bf16x8(uint4 v) {
    return __builtin_bit_cast(bf16x8, v);
}
// async global->LDS, 16B per lane: LDS dest = base + lane*16 (wave-uniform
// base); global source address is per-lane (gather allowed).
__device__ __forceinline__ void gl_lds16(const unsigned short* g, unsigned short* l) {
    __builtin_amdgcn_global_load_lds(
        (const __attribute__((address_space(1))) unsigned int*)g,
        (__attribute__((address_space(3))) unsigned int*)l, 16, 0, 0);
}

// 16x16x16 bf16 MFMA (K=16): A/B = 4 bf16 (2 VGPRs), C/D = 4 f32.
__device__ __forceinline__ f32x4 mfma16x16x16bf16(s16x4 a, s16x4 b, f32x4 c) {
#if __has_builtin(__builtin_amdgcn_mfma_f32_16x16x16bf16_1k)
    return __builtin_amdgcn_mfma_f32_16x16x16bf16_1k(a, b, c, 0, 0, 0);
#else
    asm volatile("v_mfma_f32_16x16x16_bf16 %0, %1, %2, %0"
                 : "+v"(c) : "v"(a), "v"(b));
    return c;
#endif
}

// ---------------------------------------------------------------------------
// Merged prep (unchanged from R7): blocks 0..1023 = weight transpose in
// 64x64 f32 tiles; blocks 1024..3071 = activation bf16 prep.
// ---------------------------------------------------------------------------
__global__ __launch_bounds__(256) void prep_all(
    const float* __restrict__ y2f, const float* __restrict__ y2b,
    const float* __restrict__ Wq, const float* __restrict__ Wk,
    const float* __restrict__ Wv, const float* __restrict__ Wo,
    unsigned short* __restrict__ Af, unsigned short* __restrict__ Ab,
    unsigned short* __restrict__ As, unsigned short* __restrict__ Wt_all)
{
    __shared__ float tile[64][68];    // 17.4 KB; rows 272B (16B-aligned)
    const int blk = blockIdx.x;
    if (blk < 1024) {
        const int m = blk >> 8, r = blk & 255, bk = r & 15, bn = r >> 4;
        const float* W = (m == 0) ? Wq : (m == 1) ? Wk : (m == 2) ? Wv : Wo;
        const int tx = threadIdx.x & 15, ty = threadIdx.x >> 4;  // 16 x 16
        #pragma unroll
        for (int i = 0; i < 64; i += 16)
            *(float4*)(&tile[ty + i][tx*4]) =
                *(const float4*)(&W[(size_t)(bk*64 + ty + i)*DIM + bn*64 + tx*4]);
        __syncthreads();
        unsigned short* dst = Wt_all + (size_t)m * DIM * DIM;
        #pragma unroll
        for (int i = 0; i < 2; i++) {
            int chunk = i*256 + threadIdx.x;        // 0..511
            int n = chunk >> 3, kc = (chunk & 7)*8; // Wt row = n, col kc..kc+7
            unsigned int p0 = (unsigned)f2bf(tile[kc+0][n]) | ((unsigned)f2bf(tile[kc+1][n]) << 16);
            unsigned int p1 = (unsigned)f2bf(tile[kc+2][n]) | ((unsigned)f2bf(tile[kc+3][n]) << 16);
            unsigned int p2 = (unsigned)f2bf(tile[kc+4][n]) | ((unsigned)f2bf(tile[kc+5][n]) << 16);
            unsigned int p3 = (unsigned)f2bf(tile[kc+6][n]) | ((unsigned)f2bf(tile[kc+7][n]) << 16);
            *(uint4*)(&dst[(size_t)(bn*64 + n)*DIM + bk*64 + kc]) = uint4{p0, p1, p2, p3};
        }
    } else {
        const size_t idx = ((size_t)(blk - 1024)*256 + threadIdx.x) * 8;
        #pragma unroll
        for (int half = 0; half < 2; half++) {
            float4 f = *(const float4*)(y2f + idx + half*4);
            float4 b = *(const float4*)(y2b + idx + half*4);
            ushort4 of, ob, os;
            of.x = f2bf(f.x); of.y = f2bf(f.y); of.z = f2bf(f.z); of.w = f2bf(f.w);
            ob.x = f2bf(b.x); ob.y = f2bf(b.y); ob.z = f2bf(b.z); ob.w = f2bf(b.w);
            os.x = f2bf(f.x + b.x); os.y = f2bf(f.y + b.y);
            os.z = f2bf(f.z + b.z); os.w = f2bf(f.w + b.w);
            *(ushort4*)(Af + idx + half*4) = of;
            *(ushort4*)(Ab + idx + half*4) = ob;
            *(ushort4*)(As + idx + half*4) = os;
        }
    }
}

// ---------------------------------------------------------------------------
// Uniform QKV GEMM v4 = R8 + bm-major intra-XCD order. OLD swizzle ran one
// (mode,bn) combo across all 32 bm per XCD -> the 8MB A-matrix streamed
// through the 4MB XCD-L2 three times (zero cross-combo reuse; loads land at
// L3 latency). NEW: j = lin>>3; bm = j/3, combo = j%3 -> the ~32 resident
// blocks per XCD cover 3 combos x ~11 shared bm panels, so each staged A
// panel is L2-hot for its 2 sibling-combo blocks. B-panel set per XCD
// unchanged (rest = 3*xcd + combo).
// ---------------------------------------------------------------------------
__global__ __launch_bounds__(512) void gemm_qkv(
    const unsigned short* __restrict__ Af, const unsigned short* __restrict__ Ab,
    const unsigned short* __restrict__ As,
    const unsigned short* __restrict__ Wt_all,
    const float* __restrict__ bq, const float* __restrict__ bk,
    const float* __restrict__ bv,
    unsigned short* __restrict__ Qh, unsigned short* __restrict__ Kh,
    unsigned short* __restrict__ Vt)
{
    const int lin = blockIdx.x + 32*blockIdx.y;
    const int xcd = lin & 7, j = lin >> 3;  // XCD id, intra-XCD index 0..95
    const int bm = j / 3;                   // bm-major: A panel shared across
    const int rest = 3*xcd + (j % 3);       //  the 3 in-flight combos
    const int mode = rest >> 3;             // 0=Q, 1=K, 2=V
    const int bn = rest & 7;
    __shared__ __align__(16) unsigned short smem[3*8192];   // 48 KB
    const int t = threadIdx.x;
    const int w = t >> 6, lane = t & 63, ln = lane & 15, quad = lane >> 4;
    const int wm = w >> 1, wn = w & 1;      // 4 x 2 wave grid (32r x 64c each)
    const unsigned short* Wt = Wt_all + (size_t)mode * (DIM*DIM);
    const unsigned short* A0 = (mode == 0) ? Af : (mode == 1) ? Ab : As;

    const int srow = lane >> 2;             // 16 rows per wave-load
    // source col pre-swizzle: LDS pos (row, c) holds element c ^ ((row>>1)&3)
    const int scol = (((lane & 3) ^ ((lane >> 3) & 3)) * 8);

    const unsigned short* gA0 = A0 + (size_t)(bm*128 + w*16 + srow)*DIM + scol;
    const unsigned short* gB0 = Wt + (size_t)(bn*128 + w*16 + srow)*DIM + scol;

    // fragment read: element quad lives at col8 = quad ^ ((ln>>1)&3)
    const int cswz = (quad ^ ((ln >> 1) & 3)) * 8;
    const int aoff = (wm*32 + ln)*32 + cswz;            // + mi*512
    const int boff = 4096 + (wn*64 + ln)*32 + cswz;     // + ni*512

    f32x4 acc[2][4];
    #pragma unroll
    for (int mi = 0; mi < 2; mi++)
        #pragma unroll
        for (int ni = 0; ni < 4; ni++)
            acc[mi][ni] = (f32x4){0.f, 0.f, 0.f, 0.f};

#define STAGE_Q(BUF) do { \
        unsigned short* s_ = smem + (BUF)*8192; \
        gl_lds16(gA0, &s_[(w*16)*32]); \
        gl_lds16(gB0, &s_[4096 + (w*16)*32]); \
        gA0 += 32; gB0 += 32; } while (0)

#define COMP_Q(BUF) do { \
        const unsigned short* s_ = smem + (BUF)*8192; \
        bf16x8 af[2], bfr[4]; \
        _Pragma("unroll") \
        for (int mi = 0; mi < 2; mi++) \
            af[mi] = as_bf16x8(*(const uint4*)(s_ + aoff + mi*512)); \
        _Pragma("unroll") \
        for (int ni = 0; ni < 4; ni++) \
            bfr[ni] = as_bf16x8(*(const uint4*)(s_ + boff + ni*512)); \
        _Pragma("unroll") \
        for (int mi = 0; mi < 2; mi++) \
            _Pragma("unroll") \
            for (int ni = 0; ni < 4; ni++) \
                acc[mi][ni] = __builtin_amdgcn_mfma_f32_16x16x32_bf16(af[mi], bfr[ni], acc[mi][ni], 0, 0, 0); \
    } while (0)

#define QITER(B) do { \
        asm volatile("s_waitcnt vmcnt(2)" ::: "memory"); \
        __builtin_amdgcn_s_barrier(); \
        __builtin_amdgcn_sched_barrier(0); \
        STAGE_Q(((B) + 2) % 3); \
        COMP_Q(B); \
        __builtin_amdgcn_sched_barrier(0); \
    } while (0)

    STAGE_Q(0);
    STAGE_Q(1);
    for (int base = 0; base < 30; base += 3) {
        QITER(0); QITER(1); QITER(2);
    }
    asm volatile("s_waitcnt vmcnt(2)" ::: "memory");
    __builtin_amdgcn_s_barrier();
    __builtin_amdgcn_sched_barrier(0);
    COMP_Q(0);
    __builtin_amdgcn_sched_barrier(0);
    asm volatile("s_waitcnt vmcnt(0)" ::: "memory");
    __builtin_amdgcn_s_barrier();
    __builtin_amdgcn_sched_barrier(0);
    COMP_Q(1);
#undef QITER
#undef COMP_Q
#undef STAGE_Q

    const float* bias = (mode == 0) ? bq : (mode == 1) ? bk : bv;
    unsigned short* dst = (mode == 0) ? Qh : (mode == 1) ? Kh : Vt;
    if (mode < 2) {
        const float sc = (mode == 0) ? 0.125f * 1.4426950408889634f : 1.0f;
        #pragma unroll
        for (int mi = 0; mi < 2; mi++) {
            #pragma unroll
            for (int r = 0; r < 4; r++) {
                int grow = bm*128 + wm*32 + mi*16 + quad*4 + r;
                int b_ = grow >> 11, n = grow & (NN - 1);
                #pragma unroll
                for (int ni = 0; ni < 4; ni++) {
                    int gcol = bn*128 + wn*64 + ni*16 + ln;
                    int hh = gcol >> 6, dd = gcol & 63;
                    float val = (acc[mi][ni][r] + bias[gcol]) * sc;
                    dst[(((size_t)(b_*HEADS + hh))*NN + n)*HD + dd] = f2bf(val);
                }
            }
        }
    } else {
        // V: single-pass transpose through swizzled sT[128 dd][128 nn]
        __syncthreads();
        #pragma unroll
        for (int ni = 0; ni < 4; ni++) {
            int row_s = wn*64 + ni*16 + ln;            // local feature col dd
            float bsv = bias[bn*128 + row_s];
            int sxor = (row_s & 7) << 1;               // 8B-unit XOR swizzle
            #pragma unroll
            for (int mi = 0; mi < 2; mi++) {
                int u = wm*8 + mi*4 + quad;            // 8B unit along nn (0..31)
                ushort4 pk;
                pk.x = f2bf(acc[mi][ni][0] + bsv);
                pk.y = f2bf(acc[mi][ni][1] + bsv);
                pk.z = f2bf(acc[mi][ni][2] + bsv);
                pk.w = f2bf(acc[mi][ni][3] + bsv);
                *(ushort4*)(&smem[row_s*128 + ((u ^ sxor) << 2)]) = pk;
            }
        }
        __syncthreads();
        const int b_ = bm >> 4;
        #pragma unroll
        for (int i = 0; i < 4; i++) {
            int idx = i*512 + t;                        // 0..2047 16B chunks
            int dd = idx >> 4, jc = idx & 15;
            int u = (jc*2) ^ ((dd & 7) << 1);
            int hh = bn*2 + (dd >> 6), d_ = dd & 63;
            *(uint4*)(dst + (((size_t)(b_*HEADS + hh))*HD + d_)*NN
                          + (size_t)(bm & 15)*128 + jc*8)
                = *(const uint4*)(&smem[dd*128 + (u << 2)]);
        }
    }
}

// ---------------------------------------------------------------------------
// Out projection v4 = R8 + 4th buffer (64 KB, validated static limit; 1
// block/CU so occupancy unaffected) staged 3 tiles ahead with vmcnt(4):
// only 16 waves/CU here, so latency hiding must come from pipeline depth,
// not TLP. Same barrier count, +1 region of load-latency cover.
// ---------------------------------------------------------------------------
__global__ __launch_bounds__(512) void gemm_out(
    const unsigned short* __restrict__ attp,
    const unsigned short* __restrict__ Wt_all,
    const float* __restrict__ bo, float* __restrict__ out)
{
    const int lin = blockIdx.x + 32*blockIdx.y;   // 0..255
    const int bn = lin & 7;                       // XCD id == Wo panel
    const int bm = lin >> 3;                      // 0..31
    __shared__ __align__(16) unsigned short smem[4*8192];   // 64 KB
    const int t = threadIdx.x;
    const int w = t >> 6, lane = t & 63, ln = lane & 15, quad = lane >> 4;
    const int wm = w >> 1, wn = w & 1;
    const unsigned short* Wt = Wt_all + (size_t)3 * (DIM*DIM);

    const int srow = lane >> 2;
    const int scol = (((lane & 3) ^ ((lane >> 3) & 3)) * 8);

    const unsigned short* gA0 = attp + (size_t)(bm*128 + w*16 + srow)*DIM + scol;
    const unsigned short* gB0 = Wt + (size_t)(bn*128 + w*16 + srow)*DIM + scol;

    const int cswz = (quad ^ ((ln >> 1) & 3)) * 8;
    const int aoff = (wm*32 + ln)*32 + cswz;            // + mi*512
    const int boff = 4096 + (wn*64 + ln)*32 + cswz;     // + ni*512

    f32x4 acc[2][4];
    #pragma unroll
    for (int mi = 0; mi < 2; mi++)
        #pragma unroll
        for (int ni = 0; ni < 4; ni++)
            acc[mi][ni] = (f32x4){0.f, 0.f, 0.f, 0.f};

#define STAGE_T(BUF) do { \
        unsigned short* s_ = smem + (BUF)*8192; \
        gl_lds16(gA0, &s_[(w*16)*32]); \
        gl_lds16(gB0, &s_[4096 + (w*16)*32]); \
        gA0 += 32; gB0 += 32; } while (0)

#define COMP_T(BUF) do { \
        const unsigned short* s_ = smem + (BUF)*8192; \
        bf16x8 af[2], bfr[4]; \
        _Pragma("unroll") \
        for (int mi = 0; mi < 2; mi++) \
            af[mi] = as_bf16x8(*(const uint4*)(s_ + aoff + mi*512)); \
        _Pragma("unroll") \
        for (int ni = 0; ni < 4; ni++) \
            bfr[ni] = as_bf16x8(*(const uint4*)(s_ + boff + ni*512)); \
        _Pragma("unroll") \
        for (int mi = 0; mi < 2; mi++) \
            _Pragma("unroll") \
            for (int ni = 0; ni < 4; ni++) \
                acc[mi][ni] = __builtin_amdgcn_mfma_f32_16x16x32_bf16(af[mi], bfr[ni], acc[mi][ni], 0, 0, 0); \
    } while (0)

// region k: tiles k,k+1,k+2 in flight (6 loads); vmcnt(4) -> tile k landed.
// stage tile k+3 into buf (k+3)%4 = (k-1)%4 (freed by last region's barrier).
#define TITER(B, S) do { \
        asm volatile("s_waitcnt vmcnt(4)" ::: "memory"); \
        __builtin_amdgcn_s_barrier(); \
        __builtin_amdgcn_sched_barrier(0); \
        STAGE_T(S); \
        COMP_T(B); \
        __builtin_amdgcn_sched_barrier(0); \
    } while (0)

    STAGE_T(0);
    STAGE_T(1);
    STAGE_T(2);
    for (int g = 0; g < 7; ++g) {           // regions 0..27 (tiles 0..27)
        TITER(0, 3); TITER(1, 0); TITER(2, 1); TITER(3, 2);
    }
    TITER(0, 3);                            // region 28 (stage tile 31)
    asm volatile("s_waitcnt vmcnt(4)" ::: "memory");   // tile 29 landed
    __builtin_amdgcn_s_barrier();
    __builtin_amdgcn_sched_barrier(0);
    COMP_T(1);
    __builtin_amdgcn_sched_barrier(0);
    asm volatile("s_waitcnt vmcnt(2)" ::: "memory");   // tile 30 landed
    __builtin_amdgcn_s_barrier();
    __builtin_amdgcn_sched_barrier(0);
    COMP_T(2);
    __builtin_amdgcn_sched_barrier(0);
    asm volatile("s_waitcnt vmcnt(0)" ::: "memory");   // tile 31 landed
    __builtin_amdgcn_s_barrier();
    __builtin_amdgcn_sched_barrier(0);
    COMP_T(3);
#undef TITER
#undef COMP_T
#undef STAGE_T

    #pragma unroll
    for (int mi = 0; mi < 2; mi++) {
        #pragma unroll
        for (int r = 0; r < 4; r++) {
            int grow = bm*128 + wm*32 + mi*16 + quad*4 + r;
            #pragma unroll
            for (int ni = 0; ni < 4; ni++) {
                int gcol = bn*128 + wn*64 + ni*16 + ln;
                out[(size_t)grow*DIM + gcol] = acc[mi][ni][r] + bo[gcol];
            }
        }
    }
}

// ---------------------------------------------------------------------------
// Flash attention (unchanged from R6 — best-known; bench-insensitive to
// attn variants across R3-R6, so frozen).
// ---------------------------------------------------------------------------
__global__ __launch_bounds__(256) void attn_kernel(
    const unsigned short* __restrict__ Qh, const unsigned short* __restrict__ Kh,
    const unsigned short* __restrict__ Vt, const unsigned short* __restrict__ As,
    unsigned short* __restrict__ attp)
{
    const int bh = blockIdx.x;      // b*16 + h
    const int qt = blockIdx.y;      // 0..15 (128-row q tiles)
    const int b = bh >> 4, h = bh & 15;
    const int t = threadIdx.x;
    const int w = t >> 6, lane = t & 63, ln = lane & 15, quad = lane >> 4;
    const int sw = ln & 7;          // fragment rows are == ln (mod 8)
    const float EBIAS = 17.312340490667562f;   // 12 * log2(e)

    __shared__ __align__(16) unsigned short sK[2][64*64];    // 16 KB [n][k]
    __shared__ __align__(16) unsigned short sVt[2][64*64];   // 16 KB [d][n]

    const unsigned short* Qb  = Qh + (size_t)bh * NN * HD + (size_t)qt * 128 * HD;
    const unsigned short* Kb  = Kh + (size_t)bh * NN * HD;
    const unsigned short* Vtb = Vt + (size_t)bh * HD * NN;   // [d][n]

    const int rl = lane >> 3, cb = lane & 7;

    // ---- Q fragments straight from global: 2 m-tiles x 2 k-frags ----
    bf16x8 aq[2][2];
    #pragma unroll
    for (int m = 0; m < 2; m++)
        #pragma unroll
        for (int k = 0; k < 2; k++)
            aq[m][k] = as_bf16x8(*(const uint4*)(
                Qb + (size_t)(m*64 + w*16 + ln)*HD + (k*4 + quad)*8));

    // stage tile jt into buffer bb (4 gl_lds16 per wave; XOR-swizzled cols)
#define STAGE_KV(JT, BBUF) do { \
        _Pragma("unroll") \
        for (int j = 0; j < 2; j++) { \
            int row = w*16 + j*8 + rl; \
            gl_lds16(Kb + (size_t)((JT)*64 + row)*HD + ((cb ^ (row & 7))*8), \
                     &sK[BBUF][(w*16 + j*8)*64]); \
            gl_lds16(Vtb + (size_t)row*NN + (JT)*64 + ((cb ^ (row & 7))*8), \
                     &sVt[BBUF][(w*16 + j*8)*64]); \
        } } while (0)

    const s16x4 ones = { (short)0x3F80, (short)0x3F80, (short)0x3F80, (short)0x3F80 };
    const f32x4 CB = (f32x4){-EBIAS, -EBIAS, -EBIAS, -EBIAS};  // persistent C-init
    f32x4 accO[2][4], accL[2];
    #pragma unroll
    for (int m = 0; m < 2; m++) {
        accL[m] = (f32x4){0.f, 0.f, 0.f, 0.f};
        #pragma unroll
        for (int di = 0; di < 4; di++) accO[m][di] = (f32x4){0.f, 0.f, 0.f, 0.f};
    }

    STAGE_KV(0, 0);                       // prologue: tile 0 -> buf 0
    asm volatile("s_waitcnt vmcnt(0)" ::: "memory");
    __builtin_amdgcn_s_barrier();
    __builtin_amdgcn_sched_barrier(0);

    #pragma unroll 2
    for (int jt = 0; jt < 32; jt++) {
        const int cur = jt & 1;
        if (jt < 31) STAGE_KV(jt + 1, cur ^ 1);   // issue next tile first

        const unsigned short* sKc = sK[cur];
        const unsigned short* sVc = sVt[cur];

        // S^T: accS[m][ni] — lane: q-col = m*64+w*16+ln, kv = ni*16+quad*4+r.
        // First MFMA of each chain takes CB (-EBIAS) as C: no init movs.
        f32x4 accS[2][4];
        __builtin_amdgcn_s_setprio(1);
        #pragma unroll
        for (int ni = 0; ni < 4; ni++) {
            bf16x8 b0 = as_bf16x8(*(const uint4*)(
                &sKc[(ni*16 + ln)*64 + (((0 + quad) ^ sw)*8)]));
            accS[0][ni] = __builtin_amdgcn_mfma_f32_16x16x32_bf16(b0, aq[0][0], CB, 0, 0, 0);
            accS[1][ni] = __builtin_amdgcn_mfma_f32_16x16x32_bf16(b0, aq[1][0], CB, 0, 0, 0);
            bf16x8 b1 = as_bf16x8(*(const uint4*)(
                &sKc[(ni*16 + ln)*64 + (((4 + quad) ^ sw)*8)]));
            accS[0][ni] = __builtin_amdgcn_mfma_f32_16x16x32_bf16(b1, aq[0][1], accS[0][ni], 0, 0, 0);
            accS[1][ni] = __builtin_amdgcn_mfma_f32_16x16x32_bf16(b1, aq[1][1], accS[1][ni], 0, 0, 0);
        }
        __builtin_amdgcn_s_setprio(0);

        // p = exp2(s-EBIAS); pack via v_perm (trunc); L via ones-MFMA
        s16x4 pf[2][4];
        #pragma unroll
        for (int m = 0; m < 2; m++)
            #pragma unroll
            for (int ni = 0; ni < 4; ni++) {
                unsigned int e0 = __builtin_bit_cast(unsigned int, __builtin_amdgcn_exp2f(accS[m][ni][0]));
                unsigned int e1 = __builtin_bit_cast(unsigned int, __builtin_amdgcn_exp2f(accS[m][ni][1]));
                unsigned int e2 = __builtin_bit_cast(unsigned int, __builtin_amdgcn_exp2f(accS[m][ni][2]));
                unsigned int e3 = __builtin_bit_cast(unsigned int, __builtin_amdgcn_exp2f(accS[m][ni][3]));
                unsigned int lo = __builtin_amdgcn_perm(e1, e0, 0x07060302u);
                unsigned int hi = __builtin_amdgcn_perm(e3, e2, 0x07060302u);
                pf[m][ni] = __builtin_bit_cast(s16x4, uint2{lo, hi});
                accL[m] = mfma16x16x16bf16(pf[m][ni], ones, accL[m]);
            }

        // O += P V: one V-frag read feeds both m-tiles.
        __builtin_amdgcn_s_setprio(1);
        #pragma unroll
        for (int ni = 0; ni < 4; ni++) {
            int blkv = 2*ni + (quad >> 1);
            int off = (quad & 1) * 4;
            #pragma unroll
            for (int di = 0; di < 4; di++) {
                s16x4 bv = __builtin_bit_cast(s16x4,
                    *(const uint2*)(&sVc[(di*16 + ln)*64 + ((blkv ^ sw)*8) + off]));
                accO[0][di] = mfma16x16x16bf16(pf[0][ni], bv, accO[0][di]);
                accO[1][di] = mfma16x16x16bf16(pf[1][ni], bv, accO[1][di]);
            }
        }
        __builtin_amdgcn_s_setprio(0);

        __builtin_amdgcn_sched_barrier(0);
        if (jt < 31) {
            asm volatile("s_waitcnt vmcnt(0)" ::: "memory");  // next tile landed
            __builtin_amdgcn_s_barrier();                     // cur fully read
            __builtin_amdgcn_sched_barrier(0);
        }
    }
#undef STAGE_KV

    // accL[m][r] = row-sum L for q-row m*64 + w*16 + quad*4 + r
    #pragma unroll
    for (int m = 0; m < 2; m++) {
        #pragma unroll
        for (int r = 0; r < 4; r++) {
            float inv = 1.f / accL[m][r];
            int n = qt*128 + m*64 + w*16 + quad*4 + r;
            #pragma unroll
            for (int di = 0; di < 4; di++) {
                int c = h*64 + di*16 + ln;
                size_t gi = ((size_t)b*NN + n)*DIM + c;
                float o = accO[m][di][r]*inv + bf2f(As[gi]);
                attp[gi] = f2bf(o);
            }
        }
    }
}

// ---------------------------------------------------------------------------
extern "C" void kernel_launch(void* const* d_in, const int* in_sizes, int n_in,
                              void* d_out, int out_size, void* d_ws, size_t ws_size,
                              hipStream_t stream) {
    const float* y2f = (const float*)d_in[0];
    const float* y2b = (const float*)d_in[1];
    const float* Wq  = (const float*)d_in[2];
    const float* bq  = (const float*)d_in[3];
    const float* Wk  = (const float*)d_in[4];
    const float* bk  = (const float*)d_in[5];
    const float* Wv  = (const float*)d_in[6];
    const float* bv  = (const float*)d_in[7];
    const float* Wo  = (const float*)d_in[8];
    const float* bo  = (const float*)d_in[9];
    float* out = (float*)d_out;

    const size_t NACT = (size_t)M_ROWS * DIM;  // 4,194,304 (8 MB as ushort)
    unsigned short* ws   = (unsigned short*)d_ws;
    unsigned short* Af   = ws;
    unsigned short* Ab   = ws + NACT;
    unsigned short* As   = ws + 2*NACT;
    unsigned short* Qh   = ws + 3*NACT;
    unsigned short* Kh   = ws + 4*NACT;
    unsigned short* Vt   = ws + 5*NACT;   // V written pre-transposed [b,h,d,n]
    unsigned short* Wt   = ws + 6*NACT;   // 4 x 1024 x 1024 bf16
    unsigned short* attp = Ab;            // overlay (Ab dead after QKV gemm)

    prep_all<<<dim3(3072), 256, 0, stream>>>(y2f, y2b, Wq, Wk, Wv, Wo,
                                             Af, Ab, As, Wt);
    gemm_qkv<<<dim3(32, 24), 512, 0, stream>>>(
        Af, Ab, As, Wt, bq, bk, bv, Qh, Kh, Vt);
    attn_kernel<<<dim3(32, 16), 256, 0, stream>>>(Qh, Kh, Vt, As, attp);
    gemm_out<<<dim3(32, 8), 512, 0, stream>>>(attp, Wt, bo, out);
}